// Round 3
// baseline (386.995 us; speedup 1.0000x reference)
//
#include <hip/hip_runtime.h>
#include <hip/hip_bf16.h>
#include <math.h>

typedef __bf16 bf16x8 __attribute__((ext_vector_type(8)));
typedef float  f32x4  __attribute__((ext_vector_type(4)));

#define GLD16(g, l) __builtin_amdgcn_global_load_lds(                      \
    (const __attribute__((address_space(1))) void*)(g),                    \
    (__attribute__((address_space(3))) void*)(l), 16, 0, 0)

// BK=32 LDS tiles (64 B rows): global k-group g of row r stored at slot
// g ^ ((r>>1)&3) -> all ds_read_b128 fragment reads are 2-way (free).

// ---------------- generic 32x32 transpose tile body -------------------------
__device__ __forceinline__ void tconv_tile(const float* __restrict__ in,
                                           __bf16* __restrict__ out,
                                           int ldin, int ldout,
                                           int r0, int c0, int tid) {
  __shared__ float t[32][33];
  int tx = tid & 31, ty = tid >> 5;
  #pragma unroll
  for (int i = ty; i < 32; i += 8)
    t[i][tx] = in[(size_t)(r0 + i) * ldin + c0 + tx];
  __syncthreads();
  #pragma unroll
  for (int i = ty; i < 32; i += 8)
    out[(size_t)(c0 + i) * ldout + r0 + tx] = (__bf16)t[tx][i];
}

// plain transpose (used for V^T from proj)
__global__ __launch_bounds__(256) void tconv_k(const float* __restrict__ in,
                                               __bf16* __restrict__ out,
                                               int ldin, int ldout) {
  tconv_tile(in, out, ldin, ldout, blockIdx.y * 32, blockIdx.x * 32, threadIdx.x);
}

// W1 transpose with xp/gate 32-col interleave pack:
// packed out row r: group=r>>6, half=(r>>5)&1, idx=r&31
//   -> src output-col = half*4096 + group*32 + idx
__global__ __launch_bounds__(256) void tconvw1p_k(const float* __restrict__ W1,
                                                  __bf16* __restrict__ out) {
  int c0 = blockIdx.x * 32;
  int src_c0 = ((c0 >> 5) & 1) * 4096 + (c0 >> 6) * 32;
  __shared__ float t[32][33];
  int r0 = blockIdx.y * 32;
  int tid = threadIdx.x, tx = tid & 31, ty = tid >> 5;
  #pragma unroll
  for (int i = ty; i < 32; i += 8)
    t[i][tx] = W1[(size_t)(r0 + i) * 8192 + src_c0 + tx];
  __syncthreads();
  #pragma unroll
  for (int i = ty; i < 32; i += 8)
    out[(size_t)(c0 + i) * 1024 + r0 + tx] = (__bf16)t[tx][i];
}

// batched: 5 QKV-family weights (1024x1024 each) -> Wt5 (5 blocks of 1024x1024)
__global__ __launch_bounds__(256) void tconv5_k(const float* __restrict__ w0,
    const float* __restrict__ w1, const float* __restrict__ w2,
    const float* __restrict__ w3, const float* __restrict__ w4,
    __bf16* __restrict__ out) {
  const float* src[5] = {w0, w1, w2, w3, w4};
  int z = blockIdx.z;
  tconv_tile(src[z], out + (size_t)z * 1048576, 1024, 1024,
             blockIdx.y * 32, blockIdx.x * 32, threadIdx.x);
}

// batched: Wo (1024x1024) -> WoW2t cols 0..1023 ; W2 (4096x1024) -> cols 1024..
__global__ __launch_bounds__(256) void tconvwow2_k(const float* __restrict__ Wo,
    const float* __restrict__ W2, __bf16* __restrict__ WoW2t) {
  int tid = threadIdx.x;
  if (blockIdx.z == 0) {
    if (blockIdx.y >= 32) return;
    __shared__ float t[32][33];
    int r0 = blockIdx.y * 32, c0 = blockIdx.x * 32;
    int tx = tid & 31, ty = tid >> 5;
    #pragma unroll
    for (int i = ty; i < 32; i += 8)
      t[i][tx] = Wo[(size_t)(r0 + i) * 1024 + c0 + tx];
    __syncthreads();
    #pragma unroll
    for (int i = ty; i < 32; i += 8)
      WoW2t[(size_t)(c0 + i) * 5120 + r0 + tx] = (__bf16)t[tx][i];
  } else {
    __shared__ float t[32][33];
    int r0 = blockIdx.y * 32, c0 = blockIdx.x * 32;
    int tx = tid & 31, ty = tid >> 5;
    #pragma unroll
    for (int i = ty; i < 32; i += 8)
      t[i][tx] = W2[(size_t)(r0 + i) * 1024 + c0 + tx];
    __syncthreads();
    #pragma unroll
    for (int i = ty; i < 32; i += 8)
      WoW2t[(size_t)(c0 + i) * 5120 + 1024 + r0 + tx] = (__bf16)t[tx][i];
  }
}

// ---------------- RMSNorm ---------------------------------------------------
__global__ __launch_bounds__(256) void rmsnorm_k(const float* __restrict__ hs,
                                                 __bf16* __restrict__ x) {
  int row = blockIdx.x, tid = threadIdx.x;
  const float4 v = ((const float4*)(hs + (size_t)row * 1024))[tid];
  float ss = v.x * v.x + v.y * v.y + v.z * v.z + v.w * v.w;
  #pragma unroll
  for (int o = 32; o > 0; o >>= 1) ss += __shfl_xor(ss, o);
  __shared__ float ps[4];
  if ((tid & 63) == 0) ps[tid >> 6] = ss;
  __syncthreads();
  float tot = ps[0] + ps[1] + ps[2] + ps[3];
  float r = rsqrtf(tot * (1.0f / 1024.0f) + 1.1920929e-7f);
  __bf16* xr = x + (size_t)row * 1024 + tid * 4;
  xr[0] = (__bf16)(v.x * r); xr[1] = (__bf16)(v.y * r);
  xr[2] = (__bf16)(v.z * r); xr[3] = (__bf16)(v.w * r);
}

// ---------------- GEMM 128x128 ring-4, counted vmcnt, swizzled LDS ----------
// Same verified schedule as ffn1silu's ring-4: 4 K-tile buffers, prefetch
// depth 3, s_waitcnt vmcnt(8) (never 0 mid-loop) + raw s_barrier per tile,
// stage t+3 into slot sealed dead by this tile's barrier. 64 KiB LDS ->
// 2 blocks/CU.
__global__ __launch_bounds__(256, 2) void gemm_bt_k(
    const __bf16* __restrict__ A, const __bf16* __restrict__ Bt,
    float* __restrict__ C, int N, int K) {
  __shared__ __bf16 sA[4][128 * 32];
  __shared__ __bf16 sB[4][128 * 32];
  const int tid = threadIdx.x;
  const int lane = tid & 63;
  const int quad = lane >> 4, l16 = lane & 15;
  const int wave = tid >> 6;
  const int waveM = wave >> 1, waveN = wave & 1;
  const int m0 = blockIdx.y * 128, n0 = blockIdx.x * 128;
  const int nk = K >> 5;
  const int rowS = tid >> 2;
  const int kg = ((tid & 3) ^ ((rowS >> 1) & 3)) * 8;
  const __bf16* gA0 = A + (size_t)(m0 + rowS) * K + kg;
  const __bf16* gA1 = gA0 + (size_t)64 * K;
  const __bf16* gB0 = Bt + (size_t)(n0 + rowS) * K + kg;
  const __bf16* gB1 = gB0 + (size_t)64 * K;
  const int lo0 = tid * 8, lo1 = 2048 + tid * 8;

  auto stage = [&](int t) {
    __bf16* dA = sA[t & 3];
    __bf16* dB = sB[t & 3];
    GLD16(gA0 + t * 32, dA + lo0);
    GLD16(gA1 + t * 32, dA + lo1);
    GLD16(gB0 + t * 32, dB + lo0);
    GLD16(gB1 + t * 32, dB + lo1);
  };
  stage(0); stage(1); stage(2);

  f32x4 acc[4][4] = {};
  #pragma unroll 1
  for (int i = 0; i < nk; ++i) {
    if (i < nk - 2)
      asm volatile("s_waitcnt vmcnt(8)" ::: "memory");
    else if (i == nk - 2)
      asm volatile("s_waitcnt vmcnt(4)" ::: "memory");
    else
      asm volatile("s_waitcnt vmcnt(0)" ::: "memory");
    __builtin_amdgcn_s_barrier();
    __builtin_amdgcn_sched_barrier(0);
    const __bf16* cA = sA[i & 3];
    const __bf16* cB = sB[i & 3];
    if (i + 3 < nk) stage(i + 3);
    bf16x8 af[4], bfv[4];
    #pragma unroll
    for (int mt = 0; mt < 4; ++mt) {
      int r = waveM * 64 + mt * 16 + l16;
      af[mt] = *(const bf16x8*)(cA + r * 32 + ((quad ^ ((r >> 1) & 3)) * 8));
    }
    #pragma unroll
    for (int nt = 0; nt < 4; ++nt) {
      int r = waveN * 64 + nt * 16 + l16;
      bfv[nt] = *(const bf16x8*)(cB + r * 32 + ((quad ^ ((r >> 1) & 3)) * 8));
    }
    __builtin_amdgcn_s_setprio(1);
    #pragma unroll
    for (int mt = 0; mt < 4; ++mt)
      #pragma unroll
      for (int nt = 0; nt < 4; ++nt)
        acc[mt][nt] = __builtin_amdgcn_mfma_f32_16x16x32_bf16(af[mt], bfv[nt], acc[mt][nt], 0, 0, 0);
    __builtin_amdgcn_s_setprio(0);
  }
  #pragma unroll
  for (int mt = 0; mt < 4; ++mt) {
    int row = m0 + waveM * 64 + mt * 16 + quad * 4;
    #pragma unroll
    for (int nt = 0; nt < 4; ++nt) {
      int col = n0 + waveN * 64 + nt * 16 + l16;
      #pragma unroll
      for (int r = 0; r < 4; ++r)
        C[(size_t)(row + r) * N + col] = acc[mt][nt][r];
    }
  }
}

// ---------------- GEMM 128x128 ring-4, split-K partial buffers --------------
__global__ __launch_bounds__(256, 2) void gemm_partk_k(
    const __bf16* __restrict__ A, const __bf16* __restrict__ Bt,
    float* __restrict__ P, int N, int K) {
  __shared__ __bf16 sA[4][128 * 32];
  __shared__ __bf16 sB[4][128 * 32];
  const int tid = threadIdx.x;
  const int lane = tid & 63;
  const int quad = lane >> 4, l16 = lane & 15;
  const int wave = tid >> 6;
  const int waveM = wave >> 1, waveN = wave & 1;
  const int m0 = blockIdx.y * 128, n0 = blockIdx.x * 128;
  const int kz = blockIdx.z, nz = gridDim.z;
  const int kper = K / nz, kbeg = kz * kper;
  const int nk = kper >> 5;
  const size_t MN = (size_t)gridDim.y * 128 * N;
  float* C = P + (size_t)kz * MN;
  const int rowS = tid >> 2;
  const int kg = ((tid & 3) ^ ((rowS >> 1) & 3)) * 8;
  const __bf16* gA0 = A + (size_t)(m0 + rowS) * K + kbeg + kg;
  const __bf16* gA1 = gA0 + (size_t)64 * K;
  const __bf16* gB0 = Bt + (size_t)(n0 + rowS) * K + kbeg + kg;
  const __bf16* gB1 = gB0 + (size_t)64 * K;
  const int lo0 = tid * 8, lo1 = 2048 + tid * 8;

  auto stage = [&](int t) {
    __bf16* dA = sA[t & 3];
    __bf16* dB = sB[t & 3];
    GLD16(gA0 + t * 32, dA + lo0);
    GLD16(gA1 + t * 32, dA + lo1);
    GLD16(gB0 + t * 32, dB + lo0);
    GLD16(gB1 + t * 32, dB + lo1);
  };
  stage(0); stage(1); stage(2);

  f32x4 acc[4][4] = {};
  #pragma unroll 1
  for (int i = 0; i < nk; ++i) {
    if (i < nk - 2)
      asm volatile("s_waitcnt vmcnt(8)" ::: "memory");
    else if (i == nk - 2)
      asm volatile("s_waitcnt vmcnt(4)" ::: "memory");
    else
      asm volatile("s_waitcnt vmcnt(0)" ::: "memory");
    __builtin_amdgcn_s_barrier();
    __builtin_amdgcn_sched_barrier(0);
    const __bf16* cA = sA[i & 3];
    const __bf16* cB = sB[i & 3];
    if (i + 3 < nk) stage(i + 3);
    bf16x8 af[4], bfv[4];
    #pragma unroll
    for (int mt = 0; mt < 4; ++mt) {
      int r = waveM * 64 + mt * 16 + l16;
      af[mt] = *(const bf16x8*)(cA + r * 32 + ((quad ^ ((r >> 1) & 3)) * 8));
    }
    #pragma unroll
    for (int nt = 0; nt < 4; ++nt) {
      int r = waveN * 64 + nt * 16 + l16;
      bfv[nt] = *(const bf16x8*)(cB + r * 32 + ((quad ^ ((r >> 1) & 3)) * 8));
    }
    __builtin_amdgcn_s_setprio(1);
    #pragma unroll
    for (int mt = 0; mt < 4; ++mt)
      #pragma unroll
      for (int nt = 0; nt < 4; ++nt)
        acc[mt][nt] = __builtin_amdgcn_mfma_f32_16x16x32_bf16(af[mt], bfv[nt], acc[mt][nt], 0, 0, 0);
    __builtin_amdgcn_s_setprio(0);
  }
  #pragma unroll
  for (int mt = 0; mt < 4; ++mt) {
    int row = m0 + waveM * 64 + mt * 16 + quad * 4;
    #pragma unroll
    for (int nt = 0; nt < 4; ++nt) {
      int col = n0 + waveN * 64 + nt * 16 + l16;
      #pragma unroll
      for (int r = 0; r < 4; ++r)
        C[(size_t)(row + r) * N + col] = acc[mt][nt][r];
    }
  }
}

// ---------------- fused FFN1 + bias + SwiGLU, 256x256 ring-4 pipeline -------
__global__ __launch_bounds__(512, 2) void ffn1silu_k(
    const __bf16* __restrict__ A, const __bf16* __restrict__ W1t,
    const float* __restrict__ b1, __bf16* __restrict__ ffout) {
  __shared__ __bf16 sA[4][256 * 32];
  __shared__ __bf16 sB[4][256 * 32];
  const int tid = threadIdx.x, lane = tid & 63, w = tid >> 6;
  const int quad = lane >> 4, l16 = lane & 15;
  const int wm = w >> 2, wn = w & 3;          // 2 M-waves x 4 N-waves
  const int m0 = blockIdx.y * 256;            // M = 2048 -> 8
  const int n0p = blockIdx.x * 256;           // packed N = 8192 -> 32
  const int K = 1024, NKT = 32;
  const int rowS = tid >> 2;                  // 0..127
  const int kg = ((tid & 3) ^ ((rowS >> 1) & 3)) * 8;
  const __bf16* gA0 = A + (size_t)(m0 + rowS) * K + kg;
  const __bf16* gA1 = gA0 + (size_t)128 * K;
  const __bf16* gB0 = W1t + (size_t)(n0p + rowS) * K + kg;
  const __bf16* gB1 = gB0 + (size_t)128 * K;
  const int lo0 = tid * 8, lo1 = 4096 + tid * 8;

  f32x4 acc[8][4] = {};

  auto stageA = [&](int t) {
    __bf16* d = sA[t & 3];
    GLD16(gA0 + t * 32, d + lo0);
    GLD16(gA1 + t * 32, d + lo1);
  };
  auto stageB = [&](int t) {
    __bf16* d = sB[t & 3];
    GLD16(gB0 + t * 32, d + lo0);
    GLD16(gB1 + t * 32, d + lo1);
  };

  auto compute_half = [&](const __bf16* cA, const __bf16* cB,
                          const bf16x8* bfr, int half) {
    bf16x8 af[4];
    #pragma unroll
    for (int mt = 0; mt < 4; ++mt) {
      int r = wm * 128 + half * 64 + mt * 16 + l16;
      af[mt] = *(const bf16x8*)(cA + r * 32 + ((quad ^ ((r >> 1) & 3)) * 8));
    }
    __builtin_amdgcn_s_setprio(1);
    #pragma unroll
    for (int mt = 0; mt < 4; ++mt)
      #pragma unroll
      for (int nt = 0; nt < 4; ++nt)
        acc[half * 4 + mt][nt] = __builtin_amdgcn_mfma_f32_16x16x32_bf16(
            af[mt], bfr[nt], acc[half * 4 + mt][nt], 0, 0, 0);
    __builtin_amdgcn_s_setprio(0);
  };

  // prologue: prime tiles 0,1,2 (12 loads in flight)
  stageA(0); stageB(0);
  stageA(1); stageB(1);
  stageA(2); stageB(2);

  #pragma unroll 1
  for (int t = 0; t < NKT; ++t) {
    if (t < NKT - 2)
      asm volatile("s_waitcnt vmcnt(8)" ::: "memory");
    else if (t == NKT - 2)
      asm volatile("s_waitcnt vmcnt(4)" ::: "memory");
    else
      asm volatile("s_waitcnt vmcnt(0)" ::: "memory");
    __builtin_amdgcn_s_barrier();
    __builtin_amdgcn_sched_barrier(0);
    const __bf16* cA = sA[t & 3];
    const __bf16* cB = sB[t & 3];
    if (t + 3 < NKT) stageA(t + 3);
    bf16x8 bfr[4];
    #pragma unroll
    for (int nt = 0; nt < 4; ++nt) {
      int r = wn * 64 + nt * 16 + l16;
      bfr[nt] = *(const bf16x8*)(cB + r * 32 + ((quad ^ ((r >> 1) & 3)) * 8));
    }
    compute_half(cA, cB, bfr, 0);
    if (t + 3 < NKT) stageB(t + 3);
    compute_half(cA, cB, bfr, 1);
  }

  // epilogue: bias + SwiGLU, unpack interleaved xp/gate
  const int colbase = (blockIdx.x * 4 + wn) * 32;   // logical col base (0..4095)
  #pragma unroll
  for (int j = 0; j < 8; ++j) {
    int row = m0 + wm * 128 + (j >> 2) * 64 + (j & 3) * 16 + quad * 4;
    #pragma unroll
    for (int p = 0; p < 2; ++p) {
      int col = colbase + p * 16 + l16;
      float bxv = b1[col], bgv = b1[col + 4096];
      #pragma unroll
      for (int r = 0; r < 4; ++r) {
        float xp = acc[j][p][r] + bxv;
        float g  = acc[j][p + 2][r] + bgv;
        float val = xp * g / (1.f + __expf(-g));
        ffout[(size_t)(row + r) * 5120 + 1024 + col] = (__bf16)val;
      }
    }
  }
}

// ---------------- combine: out = Σ4 partials + (bo+b2) + lam*h --------------
__global__ __launch_bounds__(256) void combine_k(
    const float* __restrict__ P, const float* __restrict__ b2,
    const float* __restrict__ bo, const float* __restrict__ hs,
    const float* __restrict__ plam, float* __restrict__ out) {
  const size_t MN = (size_t)2048 * 1024;
  size_t i = ((size_t)blockIdx.x * 256 + threadIdx.x) * 4;
  int col = (int)(i & 1023);
  float4 a0 = *(const float4*)(P + i);
  float4 a1 = *(const float4*)(P + MN + i);
  float4 a2 = *(const float4*)(P + 2 * MN + i);
  float4 a3 = *(const float4*)(P + 3 * MN + i);
  float4 h  = *(const float4*)(hs + i);
  float4 v2 = *(const float4*)(b2 + col);
  float4 vo = *(const float4*)(bo + col);
  float lam = plam[0];
  float4 o;
  o.x = (a0.x + a1.x) + (a2.x + a3.x) + v2.x + vo.x + lam * h.x;
  o.y = (a0.y + a1.y) + (a2.y + a3.y) + v2.y + vo.y + lam * h.y;
  o.z = (a0.z + a1.z) + (a2.z + a3.z) + v2.z + vo.z + lam * h.z;
  o.w = (a0.w + a1.w) + (a2.w + a3.w) + v2.w + vo.w + lam * h.w;
  *(float4*)(out + i) = o;
}

// ---------------- l2norm + RoPE for q,k,qb,kb -------------------------------
__global__ __launch_bounds__(256) void qkprep_k(const float* __restrict__ proj,
    __bf16* __restrict__ qo, __bf16* __restrict__ ko,
    float* __restrict__ qbo, float* __restrict__ kbo) {
  int gw = blockIdx.x * 4 + (threadIdx.x >> 6);
  int lane = threadIdx.x & 63;
  int s = gw >> 4, h = gw & 15;
  int j = lane & 31;
  float inv = powf(1000.0f, -(float)j * (1.0f / 32.0f));
  float ang = (float)s * inv;
  float cb = (float)(__bf16)cosf(ang);
  float sb = (float)(__bf16)sinf(ang);
  size_t ibase = (size_t)s * 5120 + h * 64 + lane;
  size_t obase = (size_t)s * 1024 + h * 64 + lane;
  bool lo = lane < 32;

  auto proc = [&](const float* src) -> float {
    float xv = src[ibase];
    float ss = xv * xv;
    #pragma unroll
    for (int o = 32; o > 0; o >>= 1) ss += __shfl_xor(ss, o);
    float y = xv / fmaxf(sqrtf(ss), 1e-12f);
    float yp = __shfl_xor(y, 32);
    return lo ? (y * cb + yp * sb) : (y * cb - yp * sb);
  };
  qo[obase]  = (__bf16)proc(proj + 0);
  ko[obase]  = (__bf16)proc(proj + 1024);
  qbo[obase] = proc(proj + 3072);
  kbo[obase] = proc(proj + 4096);
}

// ---------------- sb row-sum via two-level cumsum ---------------------------
__global__ __launch_bounds__(64) void kbsum_k(const float* __restrict__ kb,
                                              float* __restrict__ tsum) {
  int t = blockIdx.x, h = blockIdx.y, d = threadIdx.x;
  size_t base = (size_t)h * 64 + d;
  float s = 0.f;
  #pragma unroll 4
  for (int r = 0; r < 32; ++r)
    s += kb[(size_t)(t * 32 + r) * 1024 + base];
  tsum[(t * 16 + h) * 64 + d] = s;
}

__global__ __launch_bounds__(64) void sbrow2_k(const float* __restrict__ qb,
                                               const float* __restrict__ kb,
                                               const float* __restrict__ tsum,
                                               float* __restrict__ sb) {
  int t = blockIdx.x, h = blockIdx.y, d = threadIdx.x;
  size_t base = (size_t)h * 64 + d;
  float run = 0.f;
  for (int tp = 0; tp < t; ++tp) run += tsum[(tp * 16 + h) * 64 + d];
  for (int s0 = 0; s0 < 32; s0 += 4) {
    float p[4];
    #pragma unroll
    for (int u = 0; u < 4; ++u) {
      size_t off = (size_t)(t * 32 + s0 + u) * 1024 + base;
      run += kb[off];
      p[u] = qb[off] * run;
    }
    #pragma unroll
    for (int o = 32; o > 0; o >>= 1) {
      #pragma unroll
      for (int u = 0; u < 4; ++u) p[u] += __shfl_xor(p[u], o);
    }
    if (d == 0) {
      #pragma unroll
      for (int u = 0; u < 4; ++u) sb[(t * 32 + s0 + u) * 16 + h] = 0.125f * p[u];
    }
  }
}

// ---------------- flash attention: split-KV x4, swizzled LDS ----------------
__global__ __launch_bounds__(256) void attn_k(const __bf16* __restrict__ qg,
    const __bf16* __restrict__ kg, const __bf16* __restrict__ vtg,
    float* __restrict__ o_part, float* __restrict__ m_part,
    float* __restrict__ l_part) {
  __shared__ __bf16 sK[64 * 64];
  __shared__ __bf16 sVt[64 * 64];
  __shared__ __bf16 sP[4][16 * 64];
  const int pair = blockIdx.x, j4 = blockIdx.y, hh = blockIdx.z;
  const int tid = threadIdx.x, lane = tid & 63, w = tid >> 6;
  const int quad = lane >> 4, l16 = lane & 15;
  const int srow = tid >> 3;
  const int sg = (tid & 7) ^ (srow & 7);
  __bf16* ldsK = sK + tid * 8;
  __bf16* ldsV = sVt + tid * 8;
  __bf16* sPw = sP[w];

  for (int phase = 0; phase < 2; ++phase) {
    const int qt = phase ? 31 - pair : pair;
    const int q0 = qt * 64;
    const int n = qt + 1;
    const int kb = (j4 * n) >> 2, ke = ((j4 + 1) * n) >> 2;
    bf16x8 qf[2];
    #pragma unroll
    for (int kk = 0; kk < 2; ++kk)
      qf[kk] = *(const bf16x8*)(qg + (size_t)(q0 + w * 16 + l16) * 1024 + hh * 64 + kk * 32 + quad * 8);
    f32x4 accO[4] = {};
    float m_[4], l_[4];
    #pragma unroll
    for (int r = 0; r < 4; ++r) { m_[r] = -INFINITY; l_[r] = 0.f; }

    for (int kt = kb; kt < ke; ++kt) {
      const __bf16* gK = kg + (size_t)(kt * 64 + srow) * 1024 + hh * 64 + sg * 8;
      const __bf16* gV = vtg + (size_t)(hh * 64 + srow) * 2048 + kt * 64 + sg * 8;
      GLD16(gK, ldsK);
      GLD16(gK + (size_t)32 * 1024, ldsK + 2048);
      GLD16(gV, ldsV);
      GLD16(gV + (size_t)32 * 2048, ldsV + 2048);
      __syncthreads();

      f32x4 s4[4];
      #pragma unroll
      for (int nt = 0; nt < 4; ++nt) {
        int r = nt * 16 + l16;
        bf16x8 b0 = *(const bf16x8*)(sK + r * 64 + ((quad ^ (r & 7)) * 8));
        bf16x8 b1 = *(const bf16x8*)(sK + r * 64 + (((4 + quad) ^ (r & 7)) * 8));
        f32x4 sa = {0.f, 0.f, 0.f, 0.f};
        sa = __builtin_amdgcn_mfma_f32_16x16x32_bf16(qf[0], b0, sa, 0, 0, 0);
        sa = __builtin_amdgcn_mfma_f32_16x16x32_bf16(qf[1], b1, sa, 0, 0, 0);
        s4[nt] = sa;
      }
      if (kt == qt) {
        #pragma unroll
        for (int nt = 0; nt < 4; ++nt)
          #pragma unroll
          for (int r = 0; r < 4; ++r)
            if (nt * 16 + l16 > w * 16 + quad * 4 + r) s4[nt][r] = -INFINITY;
      }
      float mx[4], al[4], rs[4];
      #pragma unroll
      for (int r = 0; r < 4; ++r)
        mx[r] = fmaxf(fmaxf(s4[0][r], s4[1][r]), fmaxf(s4[2][r], s4[3][r]));
      #pragma unroll
      for (int o = 1; o < 16; o <<= 1)
        #pragma unroll
        for (int r = 0; r < 4; ++r) mx[r] = fmaxf(mx[r], __shfl_xor(mx[r], o));
      #pragma unroll
      for (int r = 0; r < 4; ++r) {
        float mn = fmaxf(m_[r], mx[r]);
        al[r] = __expf(m_[r] - mn);
        m_[r] = mn;
      }
      float p[4][4];
      #pragma unroll
      for (int nt = 0; nt < 4; ++nt)
        #pragma unroll
        for (int r = 0; r < 4; ++r)
          p[nt][r] = __expf(s4[nt][r] - m_[r]);
      #pragma unroll
      for (int r = 0; r < 4; ++r)
        rs[r] = (p[0][r] + p[1][r]) + (p[2][r] + p[3][r]);
      #pragma unroll
      for (int o = 1; o < 16; o <<= 1)
        #pragma unroll
        for (int r = 0; r < 4; ++r) rs[r] += __shfl_xor(rs[r], o);
      #pragma unroll
      for (int r = 0; r < 4; ++r) l_[r] = l_[r] * al[r] + rs[r];
      #pragma unroll
      for (int nt = 0; nt < 4; ++nt)
        #pragma unroll
        for (int r = 0; r < 4; ++r) accO[nt][r] *= al[r];
      #pragma unroll
      for (int nt = 0; nt < 4; ++nt)
        #pragma unroll
        for (int r = 0; r < 4; ++r) {
          int row = quad * 4 + r, col = nt * 16 + l16;
          sPw[row * 64 + (col ^ ((row & 7) << 3))] = (__bf16)p[nt][r];
        }
      #pragma unroll
      for (int kk = 0; kk < 2; ++kk) {
        bf16x8 a = *(const bf16x8*)(sPw + l16 * 64 + (((kk * 4 + quad) ^ (l16 & 7)) * 8));
        #pragma unroll
        for (int nt = 0; nt < 4; ++nt) {
          int vr = nt * 16 + l16;
          bf16x8 bv = *(const bf16x8*)(sVt + vr * 64 + (((kk * 4 + quad) ^ (vr & 7)) * 8));
          accO[nt] = __builtin_amdgcn_mfma_f32_16x16x32_bf16(a, bv, accO[nt], 0, 0, 0);
        }
      }
      __syncthreads();
    }
    #pragma unroll
    for (int r = 0; r < 4; ++r) {
      int grow = q0 + w * 16 + quad * 4 + r;
      if (l16 == 0) {
        m_part[((size_t)j4 * 2048 + grow) * 16 + hh] = m_[r];
        l_part[((size_t)j4 * 2048 + grow) * 16 + hh] = l_[r];
      }
      #pragma unroll
      for (int nt = 0; nt < 4; ++nt)
        o_part[((size_t)j4 * 2048 + grow) * 1024 + hh * 64 + nt * 16 + l16] = accO[nt][r];
    }
  }
}

// ---------------- merge 4 KV-partials -> y into concat (stride 5120) --------
__global__ __launch_bounds__(256) void attnmerge_k(const float* __restrict__ o_part,
    const float* __restrict__ m_part, const float* __restrict__ l_part,
    const float* __restrict__ sbr, const float* __restrict__ pl2s,
    __bf16* __restrict__ yo) {
  int idx = blockIdx.x * 256 + threadIdx.x;
  int s = idx >> 8, rem = idx & 255;
  int h = rem >> 4, dg = (rem & 15) * 4;
  float m[4], l[4];
  #pragma unroll
  for (int j = 0; j < 4; ++j) {
    m[j] = m_part[((size_t)j * 2048 + s) * 16 + h];
    l[j] = l_part[((size_t)j * 2048 + s) * 16 + h];
  }
  float M = fmaxf(fmaxf(m[0], m[1]), fmaxf(m[2], m[3]));
  float den = 0.f;
  float4 acc = {0.f, 0.f, 0.f, 0.f};
  #pragma unroll
  for (int j = 0; j < 4; ++j) {
    float e = __expf(m[j] - M);
    den += l[j] * e;
    float4 o = *(const float4*)(o_part + ((size_t)j * 2048 + s) * 1024 + h * 64 + dg);
    acc.x += e * o.x; acc.y += e * o.y; acc.z += e * o.z; acc.w += e * o.w;
  }
  float sc = pl2s[0] / den;
  float add = sbr[s * 16 + h];
  __bf16* yp = yo + (size_t)s * 5120 + h * 64 + dg;
  yp[0] = (__bf16)(sc * acc.x + add);
  yp[1] = (__bf16)(sc * acc.y + add);
  yp[2] = (__bf16)(sc * acc.z + add);
  yp[3] = (__bf16)(sc * acc.w + add);
}

extern "C" void kernel_launch(void* const* d_in, const int* in_sizes, int n_in,
                              void* d_out, int out_size, void* d_ws, size_t ws_size,
                              hipStream_t stream) {
  (void)in_sizes; (void)n_in; (void)out_size; (void)ws_size;
  const float* hs   = (const float*)d_in[0];
  const float* Wq   = (const float*)d_in[1];
  const float* Wk   = (const float*)d_in[2];
  const float* Wv   = (const float*)d_in[3];
  const float* Wqb  = (const float*)d_in[4];
  const float* Wkb  = (const float*)d_in[5];
  const float* Wo   = (const float*)d_in[6];
  const float* bo   = (const float*)d_in[7];
  const float* W1   = (const float*)d_in[8];
  const float* b1   = (const float*)d_in[9];
  const float* W2   = (const float*)d_in[10];
  const float* b2   = (const float*)d_in[11];
  const float* plam = (const float*)d_in[12];
  const float* pl2s = (const float*)d_in[13];
  float* out = (float*)d_out;
  char* ws = (char*)d_ws;

  size_t off = 0;
  auto alloc = [&](size_t bytes) { char* p = ws + off; off += (bytes + 255) & ~(size_t)255; return p; };
  __bf16* Wt5    = (__bf16*)alloc((size_t)5 * 1024 * 1024 * 2);
  __bf16* WoW2t  = (__bf16*)alloc((size_t)1024 * 5120 * 2);   // [n][k], k: Wo 0..1023, W2 1024..5119
  __bf16* W1t    = (__bf16*)alloc((size_t)8192 * 1024 * 2);   // packed xp/gate 32-col interleave
  __bf16* xbf    = (__bf16*)alloc((size_t)2048 * 1024 * 2);
  __bf16* concat = (__bf16*)alloc((size_t)2048 * 5120 * 2);   // [y | ffin] bf16
  float*  proj  = (float*)alloc((size_t)2048 * 5120 * 4);
  float*  qbf32 = (float*)alloc((size_t)2048 * 1024 * 4);
  float*  kbf32 = (float*)alloc((size_t)2048 * 1024 * 4);
  __bf16* qbf   = (__bf16*)alloc((size_t)2048 * 1024 * 2);
  __bf16* kbf   = (__bf16*)alloc((size_t)2048 * 1024 * 2);
  float*  o_part = proj;                                      // 4 x 8 MB (proj dead after prep)
  float*  m_part = qbf32;                                     // 512 KB
  float*  l_part = qbf32 + (size_t)4 * 2048 * 16;             // 512 KB
  float*  gpart  = proj;                                      // 4 x 8 MB (after attnmerge)
  __bf16* vtbf  = (__bf16*)alloc((size_t)1024 * 2048 * 2);
  float*  sbrow = (float*)alloc((size_t)2048 * 16 * 4);
  float*  tsum  = (float*)alloc((size_t)64 * 16 * 64 * 4);

  // weight repack (batched)
  tconv5_k<<<dim3(32, 32, 5), 256, 0, stream>>>(Wq, Wk, Wv, Wqb, Wkb, Wt5);
  tconvwow2_k<<<dim3(32, 128, 2), 256, 0, stream>>>(Wo, W2, WoW2t);
  tconvw1p_k<<<dim3(256, 32), 256, 0, stream>>>(W1, W1t);

  rmsnorm_k<<<2048, 256, 0, stream>>>(hs, xbf);
  gemm_bt_k<<<dim3(40, 16), 256, 0, stream>>>(xbf, Wt5, proj, 5120, 1024);
  qkprep_k<<<8192, 256, 0, stream>>>(proj, qbf, kbf, qbf32, kbf32);
  tconv_k<<<dim3(32, 64), 256, 0, stream>>>(proj + 2048, vtbf, 5120, 2048);
  kbsum_k<<<dim3(64, 16), 64, 0, stream>>>(kbf32, tsum);
  sbrow2_k<<<dim3(64, 16), 64, 0, stream>>>(qbf32, kbf32, tsum, sbrow);
  attn_k<<<dim3(16, 4, 16), 256, 0, stream>>>(qbf, kbf, vtbf, o_part, m_part, l_part);
  attnmerge_k<<<2048, 256, 0, stream>>>(o_part, m_part, l_part, sbrow, pl2s, concat);
  // fused FFN1 + bias + SwiGLU -> concat cols 1024..5119 (256x256 ring-4)
  ffn1silu_k<<<dim3(32, 8), 512, 0, stream>>>(xbf, W1t, b1, concat);
  // merged (Wo + FFN2): [y|ffin] @ [Wo;W2], K=5120, split-K x4 -> partials
  gemm_partk_k<<<dim3(8, 16, 4), 256, 0, stream>>>(concat, WoW2t, gpart, 1024, 5120);
  // out = Σ partials + (bo+b2) + lam*h
  combine_k<<<2048, 256, 0, stream>>>(gpart, b2, bo, hs, plam, out);
}

// Round 4
// 385.896 us; speedup vs baseline: 1.0029x; 1.0029x over previous
//
#include <hip/hip_runtime.h>
#include <hip/hip_bf16.h>
#include <math.h>

typedef __bf16 bf16x8 __attribute__((ext_vector_type(8)));
typedef float  f32x4  __attribute__((ext_vector_type(4)));

#define GLD16(g, l) __builtin_amdgcn_global_load_lds(                      \
    (const __attribute__((address_space(1))) void*)(g),                    \
    (__attribute__((address_space(3))) void*)(l), 16, 0, 0)

#define SCHED_FENCE() __builtin_amdgcn_sched_barrier(0)

// BK=32 LDS tiles (64 B rows): global k-group g of row r stored at slot
// g ^ ((r>>1)&3) -> all ds_read_b128 fragment reads are 2-way (free).

// ---------------- generic 32x32 transpose tile body -------------------------
__device__ __forceinline__ void tconv_tile(const float* __restrict__ in,
                                           __bf16* __restrict__ out,
                                           int ldin, int ldout,
                                           int r0, int c0, int tid) {
  __shared__ float t[32][33];
  int tx = tid & 31, ty = tid >> 5;
  #pragma unroll
  for (int i = ty; i < 32; i += 8)
    t[i][tx] = in[(size_t)(r0 + i) * ldin + c0 + tx];
  __syncthreads();
  #pragma unroll
  for (int i = ty; i < 32; i += 8)
    out[(size_t)(c0 + i) * ldout + r0 + tx] = (__bf16)t[tx][i];
}

// plain transpose (used for V^T from proj)
__global__ __launch_bounds__(256) void tconv_k(const float* __restrict__ in,
                                               __bf16* __restrict__ out,
                                               int ldin, int ldout) {
  tconv_tile(in, out, ldin, ldout, blockIdx.y * 32, blockIdx.x * 32, threadIdx.x);
}

// W1 transpose with xp/gate 32-col interleave pack:
// packed out row r: group=r>>6, half=(r>>5)&1, idx=r&31
//   -> src output-col = half*4096 + group*32 + idx
__global__ __launch_bounds__(256) void tconvw1p_k(const float* __restrict__ W1,
                                                  __bf16* __restrict__ out) {
  int c0 = blockIdx.x * 32;
  int src_c0 = ((c0 >> 5) & 1) * 4096 + (c0 >> 6) * 32;
  __shared__ float t[32][33];
  int r0 = blockIdx.y * 32;
  int tid = threadIdx.x, tx = tid & 31, ty = tid >> 5;
  #pragma unroll
  for (int i = ty; i < 32; i += 8)
    t[i][tx] = W1[(size_t)(r0 + i) * 8192 + src_c0 + tx];
  __syncthreads();
  #pragma unroll
  for (int i = ty; i < 32; i += 8)
    out[(size_t)(c0 + i) * 1024 + r0 + tx] = (__bf16)t[tx][i];
}

// batched: 5 QKV-family weights (1024x1024 each) -> Wt5 (5 blocks of 1024x1024)
__global__ __launch_bounds__(256) void tconv5_k(const float* __restrict__ w0,
    const float* __restrict__ w1, const float* __restrict__ w2,
    const float* __restrict__ w3, const float* __restrict__ w4,
    __bf16* __restrict__ out) {
  const float* src[5] = {w0, w1, w2, w3, w4};
  int z = blockIdx.z;
  tconv_tile(src[z], out + (size_t)z * 1048576, 1024, 1024,
             blockIdx.y * 32, blockIdx.x * 32, threadIdx.x);
}

// batched: Wo (1024x1024) -> WoW2t cols 0..1023 ; W2 (4096x1024) -> cols 1024..
__global__ __launch_bounds__(256) void tconvwow2_k(const float* __restrict__ Wo,
    const float* __restrict__ W2, __bf16* __restrict__ WoW2t) {
  int tid = threadIdx.x;
  if (blockIdx.z == 0) {
    if (blockIdx.y >= 32) return;
    __shared__ float t[32][33];
    int r0 = blockIdx.y * 32, c0 = blockIdx.x * 32;
    int tx = tid & 31, ty = tid >> 5;
    #pragma unroll
    for (int i = ty; i < 32; i += 8)
      t[i][tx] = Wo[(size_t)(r0 + i) * 1024 + c0 + tx];
    __syncthreads();
    #pragma unroll
    for (int i = ty; i < 32; i += 8)
      WoW2t[(size_t)(c0 + i) * 5120 + r0 + tx] = (__bf16)t[tx][i];
  } else {
    __shared__ float t[32][33];
    int r0 = blockIdx.y * 32, c0 = blockIdx.x * 32;
    int tx = tid & 31, ty = tid >> 5;
    #pragma unroll
    for (int i = ty; i < 32; i += 8)
      t[i][tx] = W2[(size_t)(r0 + i) * 1024 + c0 + tx];
    __syncthreads();
    #pragma unroll
    for (int i = ty; i < 32; i += 8)
      WoW2t[(size_t)(c0 + i) * 5120 + 1024 + r0 + tx] = (__bf16)t[tx][i];
  }
}

// ---------------- RMSNorm ---------------------------------------------------
__global__ __launch_bounds__(256) void rmsnorm_k(const float* __restrict__ hs,
                                                 __bf16* __restrict__ x) {
  int row = blockIdx.x, tid = threadIdx.x;
  const float4 v = ((const float4*)(hs + (size_t)row * 1024))[tid];
  float ss = v.x * v.x + v.y * v.y + v.z * v.z + v.w * v.w;
  #pragma unroll
  for (int o = 32; o > 0; o >>= 1) ss += __shfl_xor(ss, o);
  __shared__ float ps[4];
  if ((tid & 63) == 0) ps[tid >> 6] = ss;
  __syncthreads();
  float tot = ps[0] + ps[1] + ps[2] + ps[3];
  float r = rsqrtf(tot * (1.0f / 1024.0f) + 1.1920929e-7f);
  __bf16* xr = x + (size_t)row * 1024 + tid * 4;
  xr[0] = (__bf16)(v.x * r); xr[1] = (__bf16)(v.y * r);
  xr[2] = (__bf16)(v.z * r); xr[3] = (__bf16)(v.w * r);
}

// ---------------- GEMM 128x128 ring-4, counted vmcnt, order-pinned ----------
__global__ __launch_bounds__(256, 2) void gemm_bt_k(
    const __bf16* __restrict__ A, const __bf16* __restrict__ Bt,
    float* __restrict__ C, int N, int K) {
  __shared__ __bf16 sA[4][128 * 32];
  __shared__ __bf16 sB[4][128 * 32];
  const int tid = threadIdx.x;
  const int lane = tid & 63;
  const int quad = lane >> 4, l16 = lane & 15;
  const int wave = tid >> 6;
  const int waveM = wave >> 1, waveN = wave & 1;
  const int m0 = blockIdx.y * 128, n0 = blockIdx.x * 128;
  const int nk = K >> 5;
  const int rowS = tid >> 2;
  const int kg = ((tid & 3) ^ ((rowS >> 1) & 3)) * 8;
  const __bf16* gA0 = A + (size_t)(m0 + rowS) * K + kg;
  const __bf16* gA1 = gA0 + (size_t)64 * K;
  const __bf16* gB0 = Bt + (size_t)(n0 + rowS) * K + kg;
  const __bf16* gB1 = gB0 + (size_t)64 * K;
  const int lo0 = tid * 8, lo1 = 2048 + tid * 8;

  auto stage = [&](int t) {
    __bf16* dA = sA[t & 3];
    __bf16* dB = sB[t & 3];
    GLD16(gA0 + t * 32, dA + lo0);
    GLD16(gA1 + t * 32, dA + lo1);
    GLD16(gB0 + t * 32, dB + lo0);
    GLD16(gB1 + t * 32, dB + lo1);
  };
  stage(0); stage(1); stage(2);

  f32x4 acc[4][4] = {};
  #pragma unroll 1
  for (int i = 0; i < nk; ++i) {
    if (i < nk - 2)
      asm volatile("s_waitcnt vmcnt(8)" ::: "memory");
    else if (i == nk - 2)
      asm volatile("s_waitcnt vmcnt(4)" ::: "memory");
    else
      asm volatile("s_waitcnt vmcnt(0)" ::: "memory");
    __builtin_amdgcn_s_barrier();
    SCHED_FENCE();
    const __bf16* cA = sA[i & 3];
    const __bf16* cB = sB[i & 3];
    if (i + 3 < nk) stage(i + 3);   // issue next-tile loads FIRST (pinned)
    SCHED_FENCE();
    bf16x8 af[4], bfv[4];
    #pragma unroll
    for (int mt = 0; mt < 4; ++mt) {
      int r = waveM * 64 + mt * 16 + l16;
      af[mt] = *(const bf16x8*)(cA + r * 32 + ((quad ^ ((r >> 1) & 3)) * 8));
    }
    #pragma unroll
    for (int nt = 0; nt < 4; ++nt) {
      int r = waveN * 64 + nt * 16 + l16;
      bfv[nt] = *(const bf16x8*)(cB + r * 32 + ((quad ^ ((r >> 1) & 3)) * 8));
    }
    __builtin_amdgcn_s_setprio(1);
    #pragma unroll
    for (int mt = 0; mt < 4; ++mt)
      #pragma unroll
      for (int nt = 0; nt < 4; ++nt)
        acc[mt][nt] = __builtin_amdgcn_mfma_f32_16x16x32_bf16(af[mt], bfv[nt], acc[mt][nt], 0, 0, 0);
    __builtin_amdgcn_s_setprio(0);
    SCHED_FENCE();
  }
  #pragma unroll
  for (int mt = 0; mt < 4; ++mt) {
    int row = m0 + waveM * 64 + mt * 16 + quad * 4;
    #pragma unroll
    for (int nt = 0; nt < 4; ++nt) {
      int col = n0 + waveN * 64 + nt * 16 + l16;
      #pragma unroll
      for (int r = 0; r < 4; ++r)
        C[(size_t)(row + r) * N + col] = acc[mt][nt][r];
    }
  }
}

// ---------------- GEMM 128x128 ring-4, split-K partial buffers --------------
__global__ __launch_bounds__(256, 2) void gemm_partk_k(
    const __bf16* __restrict__ A, const __bf16* __restrict__ Bt,
    float* __restrict__ P, int N, int K) {
  __shared__ __bf16 sA[4][128 * 32];
  __shared__ __bf16 sB[4][128 * 32];
  const int tid = threadIdx.x;
  const int lane = tid & 63;
  const int quad = lane >> 4, l16 = lane & 15;
  const int wave = tid >> 6;
  const int waveM = wave >> 1, waveN = wave & 1;
  const int m0 = blockIdx.y * 128, n0 = blockIdx.x * 128;
  const int kz = blockIdx.z, nz = gridDim.z;
  const int kper = K / nz, kbeg = kz * kper;
  const int nk = kper >> 5;
  const size_t MN = (size_t)gridDim.y * 128 * N;
  float* C = P + (size_t)kz * MN;
  const int rowS = tid >> 2;
  const int kg = ((tid & 3) ^ ((rowS >> 1) & 3)) * 8;
  const __bf16* gA0 = A + (size_t)(m0 + rowS) * K + kbeg + kg;
  const __bf16* gA1 = gA0 + (size_t)64 * K;
  const __bf16* gB0 = Bt + (size_t)(n0 + rowS) * K + kbeg + kg;
  const __bf16* gB1 = gB0 + (size_t)64 * K;
  const int lo0 = tid * 8, lo1 = 2048 + tid * 8;

  auto stage = [&](int t) {
    __bf16* dA = sA[t & 3];
    __bf16* dB = sB[t & 3];
    GLD16(gA0 + t * 32, dA + lo0);
    GLD16(gA1 + t * 32, dA + lo1);
    GLD16(gB0 + t * 32, dB + lo0);
    GLD16(gB1 + t * 32, dB + lo1);
  };
  stage(0); stage(1); stage(2);

  f32x4 acc[4][4] = {};
  #pragma unroll 1
  for (int i = 0; i < nk; ++i) {
    if (i < nk - 2)
      asm volatile("s_waitcnt vmcnt(8)" ::: "memory");
    else if (i == nk - 2)
      asm volatile("s_waitcnt vmcnt(4)" ::: "memory");
    else
      asm volatile("s_waitcnt vmcnt(0)" ::: "memory");
    __builtin_amdgcn_s_barrier();
    SCHED_FENCE();
    const __bf16* cA = sA[i & 3];
    const __bf16* cB = sB[i & 3];
    if (i + 3 < nk) stage(i + 3);
    SCHED_FENCE();
    bf16x8 af[4], bfv[4];
    #pragma unroll
    for (int mt = 0; mt < 4; ++mt) {
      int r = waveM * 64 + mt * 16 + l16;
      af[mt] = *(const bf16x8*)(cA + r * 32 + ((quad ^ ((r >> 1) & 3)) * 8));
    }
    #pragma unroll
    for (int nt = 0; nt < 4; ++nt) {
      int r = waveN * 64 + nt * 16 + l16;
      bfv[nt] = *(const bf16x8*)(cB + r * 32 + ((quad ^ ((r >> 1) & 3)) * 8));
    }
    __builtin_amdgcn_s_setprio(1);
    #pragma unroll
    for (int mt = 0; mt < 4; ++mt)
      #pragma unroll
      for (int nt = 0; nt < 4; ++nt)
        acc[mt][nt] = __builtin_amdgcn_mfma_f32_16x16x32_bf16(af[mt], bfv[nt], acc[mt][nt], 0, 0, 0);
    __builtin_amdgcn_s_setprio(0);
    SCHED_FENCE();
  }
  #pragma unroll
  for (int mt = 0; mt < 4; ++mt) {
    int row = m0 + waveM * 64 + mt * 16 + quad * 4;
    #pragma unroll
    for (int nt = 0; nt < 4; ++nt) {
      int col = n0 + waveN * 64 + nt * 16 + l16;
      #pragma unroll
      for (int r = 0; r < 4; ++r)
        C[(size_t)(row + r) * N + col] = acc[mt][nt][r];
    }
  }
}

// ---------------- fused FFN1 + bias + SwiGLU, 256x256 ring-4 pipeline -------
// Order-pinned per K-tile: {waitcnt,barrier | stageA | bfr ds_read + MFMA h0 |
// stageB | MFMA h1}. sched_barrier(0) at each cluster boundary makes the
// emitted issue order invariant to co-compilation context (round-3 lesson:
// identical source regressed 46.5->62 us when the scheduler re-shuffled the
// GLD issues relative to the MFMA clusters).
__global__ __launch_bounds__(512, 2) void ffn1silu_k(
    const __bf16* __restrict__ A, const __bf16* __restrict__ W1t,
    const float* __restrict__ b1, __bf16* __restrict__ ffout) {
  __shared__ __bf16 sA[4][256 * 32];
  __shared__ __bf16 sB[4][256 * 32];
  const int tid = threadIdx.x, lane = tid & 63, w = tid >> 6;
  const int quad = lane >> 4, l16 = lane & 15;
  const int wm = w >> 2, wn = w & 3;          // 2 M-waves x 4 N-waves
  const int m0 = blockIdx.y * 256;            // M = 2048 -> 8
  const int n0p = blockIdx.x * 256;           // packed N = 8192 -> 32
  const int K = 1024, NKT = 32;
  const int rowS = tid >> 2;                  // 0..127
  const int kg = ((tid & 3) ^ ((rowS >> 1) & 3)) * 8;
  const __bf16* gA0 = A + (size_t)(m0 + rowS) * K + kg;
  const __bf16* gA1 = gA0 + (size_t)128 * K;
  const __bf16* gB0 = W1t + (size_t)(n0p + rowS) * K + kg;
  const __bf16* gB1 = gB0 + (size_t)128 * K;
  const int lo0 = tid * 8, lo1 = 4096 + tid * 8;

  f32x4 acc[8][4] = {};

  auto stageA = [&](int t) {
    __bf16* d = sA[t & 3];
    GLD16(gA0 + t * 32, d + lo0);
    GLD16(gA1 + t * 32, d + lo1);
  };
  auto stageB = [&](int t) {
    __bf16* d = sB[t & 3];
    GLD16(gB0 + t * 32, d + lo0);
    GLD16(gB1 + t * 32, d + lo1);
  };

  auto compute_half = [&](const __bf16* cA, const bf16x8* bfr, int half) {
    bf16x8 af[4];
    #pragma unroll
    for (int mt = 0; mt < 4; ++mt) {
      int r = wm * 128 + half * 64 + mt * 16 + l16;
      af[mt] = *(const bf16x8*)(cA + r * 32 + ((quad ^ ((r >> 1) & 3)) * 8));
    }
    __builtin_amdgcn_s_setprio(1);
    #pragma unroll
    for (int mt = 0; mt < 4; ++mt)
      #pragma unroll
      for (int nt = 0; nt < 4; ++nt)
        acc[half * 4 + mt][nt] = __builtin_amdgcn_mfma_f32_16x16x32_bf16(
            af[mt], bfr[nt], acc[half * 4 + mt][nt], 0, 0, 0);
    __builtin_amdgcn_s_setprio(0);
  };

  // prologue: prime tiles 0,1,2 (12 loads in flight)
  stageA(0); stageB(0);
  stageA(1); stageB(1);
  stageA(2); stageB(2);

  #pragma unroll 1
  for (int t = 0; t < NKT; ++t) {
    if (t < NKT - 2)
      asm volatile("s_waitcnt vmcnt(8)" ::: "memory");
    else if (t == NKT - 2)
      asm volatile("s_waitcnt vmcnt(4)" ::: "memory");
    else
      asm volatile("s_waitcnt vmcnt(0)" ::: "memory");
    __builtin_amdgcn_s_barrier();
    SCHED_FENCE();
    const __bf16* cA = sA[t & 3];
    const __bf16* cB = sB[t & 3];
    if (t + 3 < NKT) stageA(t + 3);
    SCHED_FENCE();
    bf16x8 bfr[4];
    #pragma unroll
    for (int nt = 0; nt < 4; ++nt) {
      int r = wn * 64 + nt * 16 + l16;
      bfr[nt] = *(const bf16x8*)(cB + r * 32 + ((quad ^ ((r >> 1) & 3)) * 8));
    }
    compute_half(cA, bfr, 0);
    SCHED_FENCE();
    if (t + 3 < NKT) stageB(t + 3);
    SCHED_FENCE();
    compute_half(cA, bfr, 1);
    SCHED_FENCE();
  }

  // epilogue: bias + SwiGLU, unpack interleaved xp/gate
  const int colbase = (blockIdx.x * 4 + wn) * 32;   // logical col base (0..4095)
  #pragma unroll
  for (int j = 0; j < 8; ++j) {
    int row = m0 + wm * 128 + (j >> 2) * 64 + (j & 3) * 16 + quad * 4;
    #pragma unroll
    for (int p = 0; p < 2; ++p) {
      int col = colbase + p * 16 + l16;
      float bxv = b1[col], bgv = b1[col + 4096];
      #pragma unroll
      for (int r = 0; r < 4; ++r) {
        float xp = acc[j][p][r] + bxv;
        float g  = acc[j][p + 2][r] + bgv;
        float val = xp * g / (1.f + __expf(-g));
        ffout[(size_t)(row + r) * 5120 + 1024 + col] = (__bf16)val;
      }
    }
  }
}

// ---------------- combine: out = Σ4 partials + (bo+b2) + lam*h --------------
__global__ __launch_bounds__(256) void combine_k(
    const float* __restrict__ P, const float* __restrict__ b2,
    const float* __restrict__ bo, const float* __restrict__ hs,
    const float* __restrict__ plam, float* __restrict__ out) {
  const size_t MN = (size_t)2048 * 1024;
  size_t i = ((size_t)blockIdx.x * 256 + threadIdx.x) * 4;
  int col = (int)(i & 1023);
  float4 a0 = *(const float4*)(P + i);
  float4 a1 = *(const float4*)(P + MN + i);
  float4 a2 = *(const float4*)(P + 2 * MN + i);
  float4 a3 = *(const float4*)(P + 3 * MN + i);
  float4 h  = *(const float4*)(hs + i);
  float4 v2 = *(const float4*)(b2 + col);
  float4 vo = *(const float4*)(bo + col);
  float lam = plam[0];
  float4 o;
  o.x = (a0.x + a1.x) + (a2.x + a3.x) + v2.x + vo.x + lam * h.x;
  o.y = (a0.y + a1.y) + (a2.y + a3.y) + v2.y + vo.y + lam * h.y;
  o.z = (a0.z + a1.z) + (a2.z + a3.z) + v2.z + vo.z + lam * h.z;
  o.w = (a0.w + a1.w) + (a2.w + a3.w) + v2.w + vo.w + lam * h.w;
  *(float4*)(out + i) = o;
}

// ---------------- l2norm + RoPE for q,k,qb,kb -------------------------------
__global__ __launch_bounds__(256) void qkprep_k(const float* __restrict__ proj,
    __bf16* __restrict__ qo, __bf16* __restrict__ ko,
    float* __restrict__ qbo, float* __restrict__ kbo) {
  int gw = blockIdx.x * 4 + (threadIdx.x >> 6);
  int lane = threadIdx.x & 63;
  int s = gw >> 4, h = gw & 15;
  int j = lane & 31;
  float inv = powf(1000.0f, -(float)j * (1.0f / 32.0f));
  float ang = (float)s * inv;
  float cb = (float)(__bf16)cosf(ang);
  float sb = (float)(__bf16)sinf(ang);
  size_t ibase = (size_t)s * 5120 + h * 64 + lane;
  size_t obase = (size_t)s * 1024 + h * 64 + lane;
  bool lo = lane < 32;

  auto proc = [&](const float* src) -> float {
    float xv = src[ibase];
    float ss = xv * xv;
    #pragma unroll
    for (int o = 32; o > 0; o >>= 1) ss += __shfl_xor(ss, o);
    float y = xv / fmaxf(sqrtf(ss), 1e-12f);
    float yp = __shfl_xor(y, 32);
    return lo ? (y * cb + yp * sb) : (y * cb - yp * sb);
  };
  qo[obase]  = (__bf16)proc(proj + 0);
  ko[obase]  = (__bf16)proc(proj + 1024);
  qbo[obase] = proc(proj + 3072);
  kbo[obase] = proc(proj + 4096);
}

// ---------------- sb row-sum via two-level cumsum ---------------------------
__global__ __launch_bounds__(64) void kbsum_k(const float* __restrict__ kb,
                                              float* __restrict__ tsum) {
  int t = blockIdx.x, h = blockIdx.y, d = threadIdx.x;
  size_t base = (size_t)h * 64 + d;
  float s = 0.f;
  #pragma unroll 4
  for (int r = 0; r < 32; ++r)
    s += kb[(size_t)(t * 32 + r) * 1024 + base];
  tsum[(t * 16 + h) * 64 + d] = s;
}

__global__ __launch_bounds__(64) void sbrow2_k(const float* __restrict__ qb,
                                               const float* __restrict__ kb,
                                               const float* __restrict__ tsum,
                                               float* __restrict__ sb) {
  int t = blockIdx.x, h = blockIdx.y, d = threadIdx.x;
  size_t base = (size_t)h * 64 + d;
  float run = 0.f;
  for (int tp = 0; tp < t; ++tp) run += tsum[(tp * 16 + h) * 64 + d];
  for (int s0 = 0; s0 < 32; s0 += 4) {
    float p[4];
    #pragma unroll
    for (int u = 0; u < 4; ++u) {
      size_t off = (size_t)(t * 32 + s0 + u) * 1024 + base;
      run += kb[off];
      p[u] = qb[off] * run;
    }
    #pragma unroll
    for (int o = 32; o > 0; o >>= 1) {
      #pragma unroll
      for (int u = 0; u < 4; ++u) p[u] += __shfl_xor(p[u], o);
    }
    if (d == 0) {
      #pragma unroll
      for (int u = 0; u < 4; ++u) sb[(t * 32 + s0 + u) * 16 + h] = 0.125f * p[u];
    }
  }
}

// ---------------- flash attention: split-KV x4, swizzled LDS ----------------
__global__ __launch_bounds__(256) void attn_k(const __bf16* __restrict__ qg,
    const __bf16* __restrict__ kg, const __bf16* __restrict__ vtg,
    float* __restrict__ o_part, float* __restrict__ m_part,
    float* __restrict__ l_part) {
  __shared__ __bf16 sK[64 * 64];
  __shared__ __bf16 sVt[64 * 64];
  __shared__ __bf16 sP[4][16 * 64];
  const int pair = blockIdx.x, j4 = blockIdx.y, hh = blockIdx.z;
  const int tid = threadIdx.x, lane = tid & 63, w = tid >> 6;
  const int quad = lane >> 4, l16 = lane & 15;
  const int srow = tid >> 3;
  const int sg = (tid & 7) ^ (srow & 7);
  __bf16* ldsK = sK + tid * 8;
  __bf16* ldsV = sVt + tid * 8;
  __bf16* sPw = sP[w];

  for (int phase = 0; phase < 2; ++phase) {
    const int qt = phase ? 31 - pair : pair;
    const int q0 = qt * 64;
    const int n = qt + 1;
    const int kb = (j4 * n) >> 2, ke = ((j4 + 1) * n) >> 2;
    bf16x8 qf[2];
    #pragma unroll
    for (int kk = 0; kk < 2; ++kk)
      qf[kk] = *(const bf16x8*)(qg + (size_t)(q0 + w * 16 + l16) * 1024 + hh * 64 + kk * 32 + quad * 8);
    f32x4 accO[4] = {};
    float m_[4], l_[4];
    #pragma unroll
    for (int r = 0; r < 4; ++r) { m_[r] = -INFINITY; l_[r] = 0.f; }

    for (int kt = kb; kt < ke; ++kt) {
      const __bf16* gK = kg + (size_t)(kt * 64 + srow) * 1024 + hh * 64 + sg * 8;
      const __bf16* gV = vtg + (size_t)(hh * 64 + srow) * 2048 + kt * 64 + sg * 8;
      GLD16(gK, ldsK);
      GLD16(gK + (size_t)32 * 1024, ldsK + 2048);
      GLD16(gV, ldsV);
      GLD16(gV + (size_t)32 * 2048, ldsV + 2048);
      __syncthreads();

      f32x4 s4[4];
      #pragma unroll
      for (int nt = 0; nt < 4; ++nt) {
        int r = nt * 16 + l16;
        bf16x8 b0 = *(const bf16x8*)(sK + r * 64 + ((quad ^ (r & 7)) * 8));
        bf16x8 b1 = *(const bf16x8*)(sK + r * 64 + (((4 + quad) ^ (r & 7)) * 8));
        f32x4 sa = {0.f, 0.f, 0.f, 0.f};
        sa = __builtin_amdgcn_mfma_f32_16x16x32_bf16(qf[0], b0, sa, 0, 0, 0);
        sa = __builtin_amdgcn_mfma_f32_16x16x32_bf16(qf[1], b1, sa, 0, 0, 0);
        s4[nt] = sa;
      }
      if (kt == qt) {
        #pragma unroll
        for (int nt = 0; nt < 4; ++nt)
          #pragma unroll
          for (int r = 0; r < 4; ++r)
            if (nt * 16 + l16 > w * 16 + quad * 4 + r) s4[nt][r] = -INFINITY;
      }
      float mx[4], al[4], rs[4];
      #pragma unroll
      for (int r = 0; r < 4; ++r)
        mx[r] = fmaxf(fmaxf(s4[0][r], s4[1][r]), fmaxf(s4[2][r], s4[3][r]));
      #pragma unroll
      for (int o = 1; o < 16; o <<= 1)
        #pragma unroll
        for (int r = 0; r < 4; ++r) mx[r] = fmaxf(mx[r], __shfl_xor(mx[r], o));
      #pragma unroll
      for (int r = 0; r < 4; ++r) {
        float mn = fmaxf(m_[r], mx[r]);
        al[r] = __expf(m_[r] - mn);
        m_[r] = mn;
      }
      float p[4][4];
      #pragma unroll
      for (int nt = 0; nt < 4; ++nt)
        #pragma unroll
        for (int r = 0; r < 4; ++r)
          p[nt][r] = __expf(s4[nt][r] - m_[r]);
      #pragma unroll
      for (int r = 0; r < 4; ++r)
        rs[r] = (p[0][r] + p[1][r]) + (p[2][r] + p[3][r]);
      #pragma unroll
      for (int o = 1; o < 16; o <<= 1)
        #pragma unroll
        for (int r = 0; r < 4; ++r) rs[r] += __shfl_xor(rs[r], o);
      #pragma unroll
      for (int r = 0; r < 4; ++r) l_[r] = l_[r] * al[r] + rs[r];
      #pragma unroll
      for (int nt = 0; nt < 4; ++nt)
        #pragma unroll
        for (int r = 0; r < 4; ++r) accO[nt][r] *= al[r];
      #pragma unroll
      for (int nt = 0; nt < 4; ++nt)
        #pragma unroll
        for (int r = 0; r < 4; ++r) {
          int row = quad * 4 + r, col = nt * 16 + l16;
          sPw[row * 64 + (col ^ ((row & 7) << 3))] = (__bf16)p[nt][r];
        }
      #pragma unroll
      for (int kk = 0; kk < 2; ++kk) {
        bf16x8 a = *(const bf16x8*)(sPw + l16 * 64 + (((kk * 4 + quad) ^ (l16 & 7)) * 8));
        #pragma unroll
        for (int nt = 0; nt < 4; ++nt) {
          int vr = nt * 16 + l16;
          bf16x8 bv = *(const bf16x8*)(sVt + vr * 64 + (((kk * 4 + quad) ^ (vr & 7)) * 8));
          accO[nt] = __builtin_amdgcn_mfma_f32_16x16x32_bf16(a, bv, accO[nt], 0, 0, 0);
        }
      }
      __syncthreads();
    }
    #pragma unroll
    for (int r = 0; r < 4; ++r) {
      int grow = q0 + w * 16 + quad * 4 + r;
      if (l16 == 0) {
        m_part[((size_t)j4 * 2048 + grow) * 16 + hh] = m_[r];
        l_part[((size_t)j4 * 2048 + grow) * 16 + hh] = l_[r];
      }
      #pragma unroll
      for (int nt = 0; nt < 4; ++nt)
        o_part[((size_t)j4 * 2048 + grow) * 1024 + hh * 64 + nt * 16 + l16] = accO[nt][r];
    }
  }
}

// ---------------- merge 4 KV-partials -> y into concat (stride 5120) --------
__global__ __launch_bounds__(256) void attnmerge_k(const float* __restrict__ o_part,
    const float* __restrict__ m_part, const float* __restrict__ l_part,
    const float* __restrict__ sbr, const float* __restrict__ pl2s,
    __bf16* __restrict__ yo) {
  int idx = blockIdx.x * 256 + threadIdx.x;
  int s = idx >> 8, rem = idx & 255;
  int h = rem >> 4, dg = (rem & 15) * 4;
  float m[4], l[4];
  #pragma unroll
  for (int j = 0; j < 4; ++j) {
    m[j] = m_part[((size_t)j * 2048 + s) * 16 + h];
    l[j] = l_part[((size_t)j * 2048 + s) * 16 + h];
  }
  float M = fmaxf(fmaxf(m[0], m[1]), fmaxf(m[2], m[3]));
  float den = 0.f;
  float4 acc = {0.f, 0.f, 0.f, 0.f};
  #pragma unroll
  for (int j = 0; j < 4; ++j) {
    float e = __expf(m[j] - M);
    den += l[j] * e;
    float4 o = *(const float4*)(o_part + ((size_t)j * 2048 + s) * 1024 + h * 64 + dg);
    acc.x += e * o.x; acc.y += e * o.y; acc.z += e * o.z; acc.w += e * o.w;
  }
  float sc = pl2s[0] / den;
  float add = sbr[s * 16 + h];
  __bf16* yp = yo + (size_t)s * 5120 + h * 64 + dg;
  yp[0] = (__bf16)(sc * acc.x + add);
  yp[1] = (__bf16)(sc * acc.y + add);
  yp[2] = (__bf16)(sc * acc.z + add);
  yp[3] = (__bf16)(sc * acc.w + add);
}

extern "C" void kernel_launch(void* const* d_in, const int* in_sizes, int n_in,
                              void* d_out, int out_size, void* d_ws, size_t ws_size,
                              hipStream_t stream) {
  (void)in_sizes; (void)n_in; (void)out_size; (void)ws_size;
  const float* hs   = (const float*)d_in[0];
  const float* Wq   = (const float*)d_in[1];
  const float* Wk   = (const float*)d_in[2];
  const float* Wv   = (const float*)d_in[3];
  const float* Wqb  = (const float*)d_in[4];
  const float* Wkb  = (const float*)d_in[5];
  const float* Wo   = (const float*)d_in[6];
  const float* bo   = (const float*)d_in[7];
  const float* W1   = (const float*)d_in[8];
  const float* b1   = (const float*)d_in[9];
  const float* W2   = (const float*)d_in[10];
  const float* b2   = (const float*)d_in[11];
  const float* plam = (const float*)d_in[12];
  const float* pl2s = (const float*)d_in[13];
  float* out = (float*)d_out;
  char* ws = (char*)d_ws;

  size_t off = 0;
  auto alloc = [&](size_t bytes) { char* p = ws + off; off += (bytes + 255) & ~(size_t)255; return p; };
  __bf16* Wt5    = (__bf16*)alloc((size_t)5 * 1024 * 1024 * 2);
  __bf16* WoW2t  = (__bf16*)alloc((size_t)1024 * 5120 * 2);   // [n][k], k: Wo 0..1023, W2 1024..5119
  __bf16* W1t    = (__bf16*)alloc((size_t)8192 * 1024 * 2);   // packed xp/gate 32-col interleave
  __bf16* xbf    = (__bf16*)alloc((size_t)2048 * 1024 * 2);
  __bf16* concat = (__bf16*)alloc((size_t)2048 * 5120 * 2);   // [y | ffin] bf16
  float*  proj  = (float*)alloc((size_t)2048 * 5120 * 4);
  float*  qbf32 = (float*)alloc((size_t)2048 * 1024 * 4);
  float*  kbf32 = (float*)alloc((size_t)2048 * 1024 * 4);
  __bf16* qbf   = (__bf16*)alloc((size_t)2048 * 1024 * 2);
  __bf16* kbf   = (__bf16*)alloc((size_t)2048 * 1024 * 2);
  float*  o_part = proj;                                      // 4 x 8 MB (proj dead after prep)
  float*  m_part = qbf32;                                     // 512 KB
  float*  l_part = qbf32 + (size_t)4 * 2048 * 16;             // 512 KB
  float*  gpart  = proj;                                      // 4 x 8 MB (after attnmerge)
  __bf16* vtbf  = (__bf16*)alloc((size_t)1024 * 2048 * 2);
  float*  sbrow = (float*)alloc((size_t)2048 * 16 * 4);
  float*  tsum  = (float*)alloc((size_t)64 * 16 * 64 * 4);

  // weight repack (batched)
  tconv5_k<<<dim3(32, 32, 5), 256, 0, stream>>>(Wq, Wk, Wv, Wqb, Wkb, Wt5);
  tconvwow2_k<<<dim3(32, 128, 2), 256, 0, stream>>>(Wo, W2, WoW2t);
  tconvw1p_k<<<dim3(256, 32), 256, 0, stream>>>(W1, W1t);

  rmsnorm_k<<<2048, 256, 0, stream>>>(hs, xbf);
  gemm_bt_k<<<dim3(40, 16), 256, 0, stream>>>(xbf, Wt5, proj, 5120, 1024);
  qkprep_k<<<8192, 256, 0, stream>>>(proj, qbf, kbf, qbf32, kbf32);
  tconv_k<<<dim3(32, 64), 256, 0, stream>>>(proj + 2048, vtbf, 5120, 2048);
  kbsum_k<<<dim3(64, 16), 64, 0, stream>>>(kbf32, tsum);
  sbrow2_k<<<dim3(64, 16), 64, 0, stream>>>(qbf32, kbf32, tsum, sbrow);
  attn_k<<<dim3(16, 4, 16), 256, 0, stream>>>(qbf, kbf, vtbf, o_part, m_part, l_part);
  attnmerge_k<<<2048, 256, 0, stream>>>(o_part, m_part, l_part, sbrow, pl2s, concat);
  // fused FFN1 + bias + SwiGLU -> concat cols 1024..5119 (256x256 ring-4)
  ffn1silu_k<<<dim3(32, 8), 512, 0, stream>>>(xbf, W1t, b1, concat);
  // merged (Wo + FFN2): [y|ffin] @ [Wo;W2], K=5120, split-K x4 -> partials
  gemm_partk_k<<<dim3(8, 16, 4), 256, 0, stream>>>(concat, WoW2t, gpart, 1024, 5120);
  // out = Σ partials + (bo+b2) + lam*h
  combine_k<<<2048, 256, 0, stream>>>(gpart, b2, bo, hs, plam, out);
}

// Round 5
// 372.527 us; speedup vs baseline: 1.0388x; 1.0359x over previous
//
#include <hip/hip_runtime.h>
#include <hip/hip_bf16.h>
#include <math.h>

typedef __bf16 bf16x8 __attribute__((ext_vector_type(8)));
typedef float  f32x4  __attribute__((ext_vector_type(4)));

#define GLD16(g, l) __builtin_amdgcn_global_load_lds(                      \
    (const __attribute__((address_space(1))) void*)(g),                    \
    (__attribute__((address_space(3))) void*)(l), 16, 0, 0)

#define SCHED_FENCE() __builtin_amdgcn_sched_barrier(0)

// BK=32 LDS tiles (64 B rows): global k-group g of row r stored at slot
// g ^ ((r>>1)&3) -> all ds_read_b128 fragment reads are 2-way (free).

// ---------------- generic 32x32 transpose tile body -------------------------
__device__ __forceinline__ void tconv_tile(const float* __restrict__ in,
                                           __bf16* __restrict__ out,
                                           int ldin, int ldout,
                                           int r0, int c0, int tid) {
  __shared__ float t[32][33];
  int tx = tid & 31, ty = tid >> 5;
  #pragma unroll
  for (int i = ty; i < 32; i += 8)
    t[i][tx] = in[(size_t)(r0 + i) * ldin + c0 + tx];
  __syncthreads();
  #pragma unroll
  for (int i = ty; i < 32; i += 8)
    out[(size_t)(c0 + i) * ldout + r0 + tx] = (__bf16)t[tx][i];
}

// plain transpose (used for V^T from proj)
__global__ __launch_bounds__(256) void tconv_k(const float* __restrict__ in,
                                               __bf16* __restrict__ out,
                                               int ldin, int ldout) {
  tconv_tile(in, out, ldin, ldout, blockIdx.y * 32, blockIdx.x * 32, threadIdx.x);
}

// W1 transpose with xp/gate 32-col interleave pack:
// packed out row r: group=r>>6, half=(r>>5)&1, idx=r&31
//   -> src output-col = half*4096 + group*32 + idx
__global__ __launch_bounds__(256) void tconvw1p_k(const float* __restrict__ W1,
                                                  __bf16* __restrict__ out) {
  int c0 = blockIdx.x * 32;
  int src_c0 = ((c0 >> 5) & 1) * 4096 + (c0 >> 6) * 32;
  __shared__ float t[32][33];
  int r0 = blockIdx.y * 32;
  int tid = threadIdx.x, tx = tid & 31, ty = tid >> 5;
  #pragma unroll
  for (int i = ty; i < 32; i += 8)
    t[i][tx] = W1[(size_t)(r0 + i) * 8192 + src_c0 + tx];
  __syncthreads();
  #pragma unroll
  for (int i = ty; i < 32; i += 8)
    out[(size_t)(c0 + i) * 1024 + r0 + tx] = (__bf16)t[tx][i];
}

// batched: 5 QKV-family weights (1024x1024 each) -> Wt5 (5 blocks of 1024x1024)
__global__ __launch_bounds__(256) void tconv5_k(const float* __restrict__ w0,
    const float* __restrict__ w1, const float* __restrict__ w2,
    const float* __restrict__ w3, const float* __restrict__ w4,
    __bf16* __restrict__ out) {
  const float* src[5] = {w0, w1, w2, w3, w4};
  int z = blockIdx.z;
  tconv_tile(src[z], out + (size_t)z * 1048576, 1024, 1024,
             blockIdx.y * 32, blockIdx.x * 32, threadIdx.x);
}

// batched: Wo (1024x1024) -> WoW2t cols 0..1023 ; W2 (4096x1024) -> cols 1024..
__global__ __launch_bounds__(256) void tconvwow2_k(const float* __restrict__ Wo,
    const float* __restrict__ W2, __bf16* __restrict__ WoW2t) {
  int tid = threadIdx.x;
  if (blockIdx.z == 0) {
    if (blockIdx.y >= 32) return;
    __shared__ float t[32][33];
    int r0 = blockIdx.y * 32, c0 = blockIdx.x * 32;
    int tx = tid & 31, ty = tid >> 5;
    #pragma unroll
    for (int i = ty; i < 32; i += 8)
      t[i][tx] = Wo[(size_t)(r0 + i) * 1024 + c0 + tx];
    __syncthreads();
    #pragma unroll
    for (int i = ty; i < 32; i += 8)
      WoW2t[(size_t)(c0 + i) * 5120 + r0 + tx] = (__bf16)t[tx][i];
  } else {
    __shared__ float t[32][33];
    int r0 = blockIdx.y * 32, c0 = blockIdx.x * 32;
    int tx = tid & 31, ty = tid >> 5;
    #pragma unroll
    for (int i = ty; i < 32; i += 8)
      t[i][tx] = W2[(size_t)(r0 + i) * 1024 + c0 + tx];
    __syncthreads();
    #pragma unroll
    for (int i = ty; i < 32; i += 8)
      WoW2t[(size_t)(c0 + i) * 5120 + 1024 + r0 + tx] = (__bf16)t[tx][i];
  }
}

// ---------------- RMSNorm ---------------------------------------------------
__global__ __launch_bounds__(256) void rmsnorm_k(const float* __restrict__ hs,
                                                 __bf16* __restrict__ x) {
  int row = blockIdx.x, tid = threadIdx.x;
  const float4 v = ((const float4*)(hs + (size_t)row * 1024))[tid];
  float ss = v.x * v.x + v.y * v.y + v.z * v.z + v.w * v.w;
  #pragma unroll
  for (int o = 32; o > 0; o >>= 1) ss += __shfl_xor(ss, o);
  __shared__ float ps[4];
  if ((tid & 63) == 0) ps[tid >> 6] = ss;
  __syncthreads();
  float tot = ps[0] + ps[1] + ps[2] + ps[3];
  float r = rsqrtf(tot * (1.0f / 1024.0f) + 1.1920929e-7f);
  __bf16* xr = x + (size_t)row * 1024 + tid * 4;
  xr[0] = (__bf16)(v.x * r); xr[1] = (__bf16)(v.y * r);
  xr[2] = (__bf16)(v.z * r); xr[3] = (__bf16)(v.w * r);
}

// ---------------- GEMM 128x128 ring-3, counted vmcnt, order-pinned ----------
// Ring-3 (48 KiB LDS) -> 3 blocks/CU (768 slots >= 640-block grid: single
// dispatch round, no tail — round-4's ring-4 at 64 KiB capped 2/CU and
// created a 1.25-round tail). Prefetch depth 2: vmcnt(4) main loop,
// vmcnt(0) last tile. stage(t+2) targets the slot sealed dead by this
// tile's barrier (read at t-1, same mod-3 slot) -> race-free.
__global__ __launch_bounds__(256, 3) void gemm_bt_k(
    const __bf16* __restrict__ A, const __bf16* __restrict__ Bt,
    float* __restrict__ C, int N, int K) {
  __shared__ __bf16 sA[3][128 * 32];
  __shared__ __bf16 sB[3][128 * 32];
  const int tid = threadIdx.x;
  const int lane = tid & 63;
  const int quad = lane >> 4, l16 = lane & 15;
  const int wave = tid >> 6;
  const int waveM = wave >> 1, waveN = wave & 1;
  const int m0 = blockIdx.y * 128, n0 = blockIdx.x * 128;
  const int nk = K >> 5;
  const int rowS = tid >> 2;
  const int kg = ((tid & 3) ^ ((rowS >> 1) & 3)) * 8;
  const __bf16* gA0 = A + (size_t)(m0 + rowS) * K + kg;
  const __bf16* gA1 = gA0 + (size_t)64 * K;
  const __bf16* gB0 = Bt + (size_t)(n0 + rowS) * K + kg;
  const __bf16* gB1 = gB0 + (size_t)64 * K;
  const int lo0 = tid * 8, lo1 = 2048 + tid * 8;

  auto stage = [&](int t) {
    int s = t % 3;
    __bf16* dA = sA[s];
    __bf16* dB = sB[s];
    GLD16(gA0 + t * 32, dA + lo0);
    GLD16(gA1 + t * 32, dA + lo1);
    GLD16(gB0 + t * 32, dB + lo0);
    GLD16(gB1 + t * 32, dB + lo1);
  };
  stage(0); stage(1);

  f32x4 acc[4][4] = {};
  #pragma unroll 1
  for (int i = 0; i < nk; ++i) {
    if (i < nk - 1)
      asm volatile("s_waitcnt vmcnt(4)" ::: "memory");
    else
      asm volatile("s_waitcnt vmcnt(0)" ::: "memory");
    __builtin_amdgcn_s_barrier();
    SCHED_FENCE();
    int cs = i % 3;
    const __bf16* cA = sA[cs];
    const __bf16* cB = sB[cs];
    if (i + 2 < nk) stage(i + 2);   // issue next-tile loads FIRST (pinned)
    SCHED_FENCE();
    bf16x8 af[4], bfv[4];
    #pragma unroll
    for (int mt = 0; mt < 4; ++mt) {
      int r = waveM * 64 + mt * 16 + l16;
      af[mt] = *(const bf16x8*)(cA + r * 32 + ((quad ^ ((r >> 1) & 3)) * 8));
    }
    #pragma unroll
    for (int nt = 0; nt < 4; ++nt) {
      int r = waveN * 64 + nt * 16 + l16;
      bfv[nt] = *(const bf16x8*)(cB + r * 32 + ((quad ^ ((r >> 1) & 3)) * 8));
    }
    __builtin_amdgcn_s_setprio(1);
    #pragma unroll
    for (int mt = 0; mt < 4; ++mt)
      #pragma unroll
      for (int nt = 0; nt < 4; ++nt)
        acc[mt][nt] = __builtin_amdgcn_mfma_f32_16x16x32_bf16(af[mt], bfv[nt], acc[mt][nt], 0, 0, 0);
    __builtin_amdgcn_s_setprio(0);
    SCHED_FENCE();
  }
  #pragma unroll
  for (int mt = 0; mt < 4; ++mt) {
    int row = m0 + waveM * 64 + mt * 16 + quad * 4;
    #pragma unroll
    for (int nt = 0; nt < 4; ++nt) {
      int col = n0 + waveN * 64 + nt * 16 + l16;
      #pragma unroll
      for (int r = 0; r < 4; ++r)
        C[(size_t)(row + r) * N + col] = acc[mt][nt][r];
    }
  }
}

// ---------------- GEMM 128x128 ring-3, split-K partial buffers --------------
__global__ __launch_bounds__(256, 3) void gemm_partk_k(
    const __bf16* __restrict__ A, const __bf16* __restrict__ Bt,
    float* __restrict__ P, int N, int K) {
  __shared__ __bf16 sA[3][128 * 32];
  __shared__ __bf16 sB[3][128 * 32];
  const int tid = threadIdx.x;
  const int lane = tid & 63;
  const int quad = lane >> 4, l16 = lane & 15;
  const int wave = tid >> 6;
  const int waveM = wave >> 1, waveN = wave & 1;
  const int m0 = blockIdx.y * 128, n0 = blockIdx.x * 128;
  const int kz = blockIdx.z, nz = gridDim.z;
  const int kper = K / nz, kbeg = kz * kper;
  const int nk = kper >> 5;
  const size_t MN = (size_t)gridDim.y * 128 * N;
  float* C = P + (size_t)kz * MN;
  const int rowS = tid >> 2;
  const int kg = ((tid & 3) ^ ((rowS >> 1) & 3)) * 8;
  const __bf16* gA0 = A + (size_t)(m0 + rowS) * K + kbeg + kg;
  const __bf16* gA1 = gA0 + (size_t)64 * K;
  const __bf16* gB0 = Bt + (size_t)(n0 + rowS) * K + kbeg + kg;
  const __bf16* gB1 = gB0 + (size_t)64 * K;
  const int lo0 = tid * 8, lo1 = 2048 + tid * 8;

  auto stage = [&](int t) {
    int s = t % 3;
    __bf16* dA = sA[s];
    __bf16* dB = sB[s];
    GLD16(gA0 + t * 32, dA + lo0);
    GLD16(gA1 + t * 32, dA + lo1);
    GLD16(gB0 + t * 32, dB + lo0);
    GLD16(gB1 + t * 32, dB + lo1);
  };
  stage(0); stage(1);

  f32x4 acc[4][4] = {};
  #pragma unroll 1
  for (int i = 0; i < nk; ++i) {
    if (i < nk - 1)
      asm volatile("s_waitcnt vmcnt(4)" ::: "memory");
    else
      asm volatile("s_waitcnt vmcnt(0)" ::: "memory");
    __builtin_amdgcn_s_barrier();
    SCHED_FENCE();
    int cs = i % 3;
    const __bf16* cA = sA[cs];
    const __bf16* cB = sB[cs];
    if (i + 2 < nk) stage(i + 2);
    SCHED_FENCE();
    bf16x8 af[4], bfv[4];
    #pragma unroll
    for (int mt = 0; mt < 4; ++mt) {
      int r = waveM * 64 + mt * 16 + l16;
      af[mt] = *(const bf16x8*)(cA + r * 32 + ((quad ^ ((r >> 1) & 3)) * 8));
    }
    #pragma unroll
    for (int nt = 0; nt < 4; ++nt) {
      int r = waveN * 64 + nt * 16 + l16;
      bfv[nt] = *(const bf16x8*)(cB + r * 32 + ((quad ^ ((r >> 1) & 3)) * 8));
    }
    __builtin_amdgcn_s_setprio(1);
    #pragma unroll
    for (int mt = 0; mt < 4; ++mt)
      #pragma unroll
      for (int nt = 0; nt < 4; ++nt)
        acc[mt][nt] = __builtin_amdgcn_mfma_f32_16x16x32_bf16(af[mt], bfv[nt], acc[mt][nt], 0, 0, 0);
    __builtin_amdgcn_s_setprio(0);
    SCHED_FENCE();
  }
  #pragma unroll
  for (int mt = 0; mt < 4; ++mt) {
    int row = m0 + waveM * 64 + mt * 16 + quad * 4;
    #pragma unroll
    for (int nt = 0; nt < 4; ++nt) {
      int col = n0 + waveN * 64 + nt * 16 + l16;
      #pragma unroll
      for (int r = 0; r < 4; ++r)
        C[(size_t)(row + r) * N + col] = acc[mt][nt][r];
    }
  }
}

// ---------------- fused FFN1 + bias + SwiGLU, 256x256 ring-4 pipeline -------
// Order-pinned per K-tile: {waitcnt,barrier | stageA | bfr ds_read + MFMA h0 |
// stageB | MFMA h1}. sched_barrier(0) at each cluster boundary makes the
// emitted issue order invariant to co-compilation context (round-3 lesson).
__global__ __launch_bounds__(512, 2) void ffn1silu_k(
    const __bf16* __restrict__ A, const __bf16* __restrict__ W1t,
    const float* __restrict__ b1, __bf16* __restrict__ ffout) {
  __shared__ __bf16 sA[4][256 * 32];
  __shared__ __bf16 sB[4][256 * 32];
  const int tid = threadIdx.x, lane = tid & 63, w = tid >> 6;
  const int quad = lane >> 4, l16 = lane & 15;
  const int wm = w >> 2, wn = w & 3;          // 2 M-waves x 4 N-waves
  const int m0 = blockIdx.y * 256;            // M = 2048 -> 8
  const int n0p = blockIdx.x * 256;           // packed N = 8192 -> 32
  const int K = 1024, NKT = 32;
  const int rowS = tid >> 2;                  // 0..127
  const int kg = ((tid & 3) ^ ((rowS >> 1) & 3)) * 8;
  const __bf16* gA0 = A + (size_t)(m0 + rowS) * K + kg;
  const __bf16* gA1 = gA0 + (size_t)128 * K;
  const __bf16* gB0 = W1t + (size_t)(n0p + rowS) * K + kg;
  const __bf16* gB1 = gB0 + (size_t)128 * K;
  const int lo0 = tid * 8, lo1 = 4096 + tid * 8;

  f32x4 acc[8][4] = {};

  auto stageA = [&](int t) {
    __bf16* d = sA[t & 3];
    GLD16(gA0 + t * 32, d + lo0);
    GLD16(gA1 + t * 32, d + lo1);
  };
  auto stageB = [&](int t) {
    __bf16* d = sB[t & 3];
    GLD16(gB0 + t * 32, d + lo0);
    GLD16(gB1 + t * 32, d + lo1);
  };

  auto compute_half = [&](const __bf16* cA, const bf16x8* bfr, int half) {
    bf16x8 af[4];
    #pragma unroll
    for (int mt = 0; mt < 4; ++mt) {
      int r = wm * 128 + half * 64 + mt * 16 + l16;
      af[mt] = *(const bf16x8*)(cA + r * 32 + ((quad ^ ((r >> 1) & 3)) * 8));
    }
    __builtin_amdgcn_s_setprio(1);
    #pragma unroll
    for (int mt = 0; mt < 4; ++mt)
      #pragma unroll
      for (int nt = 0; nt < 4; ++nt)
        acc[half * 4 + mt][nt] = __builtin_amdgcn_mfma_f32_16x16x32_bf16(
            af[mt], bfr[nt], acc[half * 4 + mt][nt], 0, 0, 0);
    __builtin_amdgcn_s_setprio(0);
  };

  // prologue: prime tiles 0,1,2 (12 loads in flight)
  stageA(0); stageB(0);
  stageA(1); stageB(1);
  stageA(2); stageB(2);

  #pragma unroll 1
  for (int t = 0; t < NKT; ++t) {
    if (t < NKT - 2)
      asm volatile("s_waitcnt vmcnt(8)" ::: "memory");
    else if (t == NKT - 2)
      asm volatile("s_waitcnt vmcnt(4)" ::: "memory");
    else
      asm volatile("s_waitcnt vmcnt(0)" ::: "memory");
    __builtin_amdgcn_s_barrier();
    SCHED_FENCE();
    const __bf16* cA = sA[t & 3];
    const __bf16* cB = sB[t & 3];
    if (t + 3 < NKT) stageA(t + 3);
    SCHED_FENCE();
    bf16x8 bfr[4];
    #pragma unroll
    for (int nt = 0; nt < 4; ++nt) {
      int r = wn * 64 + nt * 16 + l16;
      bfr[nt] = *(const bf16x8*)(cB + r * 32 + ((quad ^ ((r >> 1) & 3)) * 8));
    }
    compute_half(cA, bfr, 0);
    SCHED_FENCE();
    if (t + 3 < NKT) stageB(t + 3);
    SCHED_FENCE();
    compute_half(cA, bfr, 1);
    SCHED_FENCE();
  }

  // epilogue: bias + SwiGLU, unpack interleaved xp/gate
  const int colbase = (blockIdx.x * 4 + wn) * 32;   // logical col base (0..4095)
  #pragma unroll
  for (int j = 0; j < 8; ++j) {
    int row = m0 + wm * 128 + (j >> 2) * 64 + (j & 3) * 16 + quad * 4;
    #pragma unroll
    for (int p = 0; p < 2; ++p) {
      int col = colbase + p * 16 + l16;
      float bxv = b1[col], bgv = b1[col + 4096];
      #pragma unroll
      for (int r = 0; r < 4; ++r) {
        float xp = acc[j][p][r] + bxv;
        float g  = acc[j][p + 2][r] + bgv;
        float val = xp * g / (1.f + __expf(-g));
        ffout[(size_t)(row + r) * 5120 + 1024 + col] = (__bf16)val;
      }
    }
  }
}

// ---------------- combine: out = Σ4 partials + (bo+b2) + lam*h --------------
__global__ __launch_bounds__(256) void combine_k(
    const float* __restrict__ P, const float* __restrict__ b2,
    const float* __restrict__ bo, const float* __restrict__ hs,
    const float* __restrict__ plam, float* __restrict__ out) {
  const size_t MN = (size_t)2048 * 1024;
  size_t i = ((size_t)blockIdx.x * 256 + threadIdx.x) * 4;
  int col = (int)(i & 1023);
  float4 a0 = *(const float4*)(P + i);
  float4 a1 = *(const float4*)(P + MN + i);
  float4 a2 = *(const float4*)(P + 2 * MN + i);
  float4 a3 = *(const float4*)(P + 3 * MN + i);
  float4 h  = *(const float4*)(hs + i);
  float4 v2 = *(const float4*)(b2 + col);
  float4 vo = *(const float4*)(bo + col);
  float lam = plam[0];
  float4 o;
  o.x = (a0.x + a1.x) + (a2.x + a3.x) + v2.x + vo.x + lam * h.x;
  o.y = (a0.y + a1.y) + (a2.y + a3.y) + v2.y + vo.y + lam * h.y;
  o.z = (a0.z + a1.z) + (a2.z + a3.z) + v2.z + vo.z + lam * h.z;
  o.w = (a0.w + a1.w) + (a2.w + a3.w) + v2.w + vo.w + lam * h.w;
  *(float4*)(out + i) = o;
}

// ---------------- l2norm + RoPE for q,k,qb,kb -------------------------------
__global__ __launch_bounds__(256) void qkprep_k(const float* __restrict__ proj,
    __bf16* __restrict__ qo, __bf16* __restrict__ ko,
    float* __restrict__ qbo, float* __restrict__ kbo) {
  int gw = blockIdx.x * 4 + (threadIdx.x >> 6);
  int lane = threadIdx.x & 63;
  int s = gw >> 4, h = gw & 15;
  int j = lane & 31;
  float inv = powf(1000.0f, -(float)j * (1.0f / 32.0f));
  float ang = (float)s * inv;
  float cb = (float)(__bf16)cosf(ang);
  float sb = (float)(__bf16)sinf(ang);
  size_t ibase = (size_t)s * 5120 + h * 64 + lane;
  size_t obase = (size_t)s * 1024 + h * 64 + lane;
  bool lo = lane < 32;

  auto proc = [&](const float* src) -> float {
    float xv = src[ibase];
    float ss = xv * xv;
    #pragma unroll
    for (int o = 32; o > 0; o >>= 1) ss += __shfl_xor(ss, o);
    float y = xv / fmaxf(sqrtf(ss), 1e-12f);
    float yp = __shfl_xor(y, 32);
    return lo ? (y * cb + yp * sb) : (y * cb - yp * sb);
  };
  qo[obase]  = (__bf16)proc(proj + 0);
  ko[obase]  = (__bf16)proc(proj + 1024);
  qbo[obase] = proc(proj + 3072);
  kbo[obase] = proc(proj + 4096);
}

// ---------------- sb row-sum via two-level cumsum ---------------------------
__global__ __launch_bounds__(64) void kbsum_k(const float* __restrict__ kb,
                                              float* __restrict__ tsum) {
  int t = blockIdx.x, h = blockIdx.y, d = threadIdx.x;
  size_t base = (size_t)h * 64 + d;
  float s = 0.f;
  #pragma unroll 4
  for (int r = 0; r < 32; ++r)
    s += kb[(size_t)(t * 32 + r) * 1024 + base];
  tsum[(t * 16 + h) * 64 + d] = s;
}

__global__ __launch_bounds__(64) void sbrow2_k(const float* __restrict__ qb,
                                               const float* __restrict__ kb,
                                               const float* __restrict__ tsum,
                                               float* __restrict__ sb) {
  int t = blockIdx.x, h = blockIdx.y, d = threadIdx.x;
  size_t base = (size_t)h * 64 + d;
  float run = 0.f;
  for (int tp = 0; tp < t; ++tp) run += tsum[(tp * 16 + h) * 64 + d];
  for (int s0 = 0; s0 < 32; s0 += 4) {
    float p[4];
    #pragma unroll
    for (int u = 0; u < 4; ++u) {
      size_t off = (size_t)(t * 32 + s0 + u) * 1024 + base;
      run += kb[off];
      p[u] = qb[off] * run;
    }
    #pragma unroll
    for (int o = 32; o > 0; o >>= 1) {
      #pragma unroll
      for (int u = 0; u < 4; ++u) p[u] += __shfl_xor(p[u], o);
    }
    if (d == 0) {
      #pragma unroll
      for (int u = 0; u < 4; ++u) sb[(t * 32 + s0 + u) * 16 + h] = 0.125f * p[u];
    }
  }
}

// ---------------- flash attention: split-KV x4, swizzled LDS ----------------
__global__ __launch_bounds__(256) void attn_k(const __bf16* __restrict__ qg,
    const __bf16* __restrict__ kg, const __bf16* __restrict__ vtg,
    float* __restrict__ o_part, float* __restrict__ m_part,
    float* __restrict__ l_part) {
  __shared__ __bf16 sK[64 * 64];
  __shared__ __bf16 sVt[64 * 64];
  __shared__ __bf16 sP[4][16 * 64];
  const int pair = blockIdx.x, j4 = blockIdx.y, hh = blockIdx.z;
  const int tid = threadIdx.x, lane = tid & 63, w = tid >> 6;
  const int quad = lane >> 4, l16 = lane & 15;
  const int srow = tid >> 3;
  const int sg = (tid & 7) ^ (srow & 7);
  __bf16* ldsK = sK + tid * 8;
  __bf16* ldsV = sVt + tid * 8;
  __bf16* sPw = sP[w];

  for (int phase = 0; phase < 2; ++phase) {
    const int qt = phase ? 31 - pair : pair;
    const int q0 = qt * 64;
    const int n = qt + 1;
    const int kb = (j4 * n) >> 2, ke = ((j4 + 1) * n) >> 2;
    bf16x8 qf[2];
    #pragma unroll
    for (int kk = 0; kk < 2; ++kk)
      qf[kk] = *(const bf16x8*)(qg + (size_t)(q0 + w * 16 + l16) * 1024 + hh * 64 + kk * 32 + quad * 8);
    f32x4 accO[4] = {};
    float m_[4], l_[4];
    #pragma unroll
    for (int r = 0; r < 4; ++r) { m_[r] = -INFINITY; l_[r] = 0.f; }

    for (int kt = kb; kt < ke; ++kt) {
      const __bf16* gK = kg + (size_t)(kt * 64 + srow) * 1024 + hh * 64 + sg * 8;
      const __bf16* gV = vtg + (size_t)(hh * 64 + srow) * 2048 + kt * 64 + sg * 8;
      GLD16(gK, ldsK);
      GLD16(gK + (size_t)32 * 1024, ldsK + 2048);
      GLD16(gV, ldsV);
      GLD16(gV + (size_t)32 * 2048, ldsV + 2048);
      __syncthreads();

      f32x4 s4[4];
      #pragma unroll
      for (int nt = 0; nt < 4; ++nt) {
        int r = nt * 16 + l16;
        bf16x8 b0 = *(const bf16x8*)(sK + r * 64 + ((quad ^ (r & 7)) * 8));
        bf16x8 b1 = *(const bf16x8*)(sK + r * 64 + (((4 + quad) ^ (r & 7)) * 8));
        f32x4 sa = {0.f, 0.f, 0.f, 0.f};
        sa = __builtin_amdgcn_mfma_f32_16x16x32_bf16(qf[0], b0, sa, 0, 0, 0);
        sa = __builtin_amdgcn_mfma_f32_16x16x32_bf16(qf[1], b1, sa, 0, 0, 0);
        s4[nt] = sa;
      }
      if (kt == qt) {
        #pragma unroll
        for (int nt = 0; nt < 4; ++nt)
          #pragma unroll
          for (int r = 0; r < 4; ++r)
            if (nt * 16 + l16 > w * 16 + quad * 4 + r) s4[nt][r] = -INFINITY;
      }
      float mx[4], al[4], rs[4];
      #pragma unroll
      for (int r = 0; r < 4; ++r)
        mx[r] = fmaxf(fmaxf(s4[0][r], s4[1][r]), fmaxf(s4[2][r], s4[3][r]));
      #pragma unroll
      for (int o = 1; o < 16; o <<= 1)
        #pragma unroll
        for (int r = 0; r < 4; ++r) mx[r] = fmaxf(mx[r], __shfl_xor(mx[r], o));
      #pragma unroll
      for (int r = 0; r < 4; ++r) {
        float mn = fmaxf(m_[r], mx[r]);
        al[r] = __expf(m_[r] - mn);
        m_[r] = mn;
      }
      float p[4][4];
      #pragma unroll
      for (int nt = 0; nt < 4; ++nt)
        #pragma unroll
        for (int r = 0; r < 4; ++r)
          p[nt][r] = __expf(s4[nt][r] - m_[r]);
      #pragma unroll
      for (int r = 0; r < 4; ++r)
        rs[r] = (p[0][r] + p[1][r]) + (p[2][r] + p[3][r]);
      #pragma unroll
      for (int o = 1; o < 16; o <<= 1)
        #pragma unroll
        for (int r = 0; r < 4; ++r) rs[r] += __shfl_xor(rs[r], o);
      #pragma unroll
      for (int r = 0; r < 4; ++r) l_[r] = l_[r] * al[r] + rs[r];
      #pragma unroll
      for (int nt = 0; nt < 4; ++nt)
        #pragma unroll
        for (int r = 0; r < 4; ++r) accO[nt][r] *= al[r];
      #pragma unroll
      for (int nt = 0; nt < 4; ++nt)
        #pragma unroll
        for (int r = 0; r < 4; ++r) {
          int row = quad * 4 + r, col = nt * 16 + l16;
          sPw[row * 64 + (col ^ ((row & 7) << 3))] = (__bf16)p[nt][r];
        }
      #pragma unroll
      for (int kk = 0; kk < 2; ++kk) {
        bf16x8 a = *(const bf16x8*)(sPw + l16 * 64 + (((kk * 4 + quad) ^ (l16 & 7)) * 8));
        #pragma unroll
        for (int nt = 0; nt < 4; ++nt) {
          int vr = nt * 16 + l16;
          bf16x8 bv = *(const bf16x8*)(sVt + vr * 64 + (((kk * 4 + quad) ^ (vr & 7)) * 8));
          accO[nt] = __builtin_amdgcn_mfma_f32_16x16x32_bf16(a, bv, accO[nt], 0, 0, 0);
        }
      }
      __syncthreads();
    }
    #pragma unroll
    for (int r = 0; r < 4; ++r) {
      int grow = q0 + w * 16 + quad * 4 + r;
      if (l16 == 0) {
        m_part[((size_t)j4 * 2048 + grow) * 16 + hh] = m_[r];
        l_part[((size_t)j4 * 2048 + grow) * 16 + hh] = l_[r];
      }
      #pragma unroll
      for (int nt = 0; nt < 4; ++nt)
        o_part[((size_t)j4 * 2048 + grow) * 1024 + hh * 64 + nt * 16 + l16] = accO[nt][r];
    }
  }
}

// ---------------- merge 4 KV-partials -> y into concat (stride 5120) --------
__global__ __launch_bounds__(256) void attnmerge_k(const float* __restrict__ o_part,
    const float* __restrict__ m_part, const float* __restrict__ l_part,
    const float* __restrict__ sbr, const float* __restrict__ pl2s,
    __bf16* __restrict__ yo) {
  int idx = blockIdx.x * 256 + threadIdx.x;
  int s = idx >> 8, rem = idx & 255;
  int h = rem >> 4, dg = (rem & 15) * 4;
  float m[4], l[4];
  #pragma unroll
  for (int j = 0; j < 4; ++j) {
    m[j] = m_part[((size_t)j * 2048 + s) * 16 + h];
    l[j] = l_part[((size_t)j * 2048 + s) * 16 + h];
  }
  float M = fmaxf(fmaxf(m[0], m[1]), fmaxf(m[2], m[3]));
  float den = 0.f;
  float4 acc = {0.f, 0.f, 0.f, 0.f};
  #pragma unroll
  for (int j = 0; j < 4; ++j) {
    float e = __expf(m[j] - M);
    den += l[j] * e;
    float4 o = *(const float4*)(o_part + ((size_t)j * 2048 + s) * 1024 + h * 64 + dg);
    acc.x += e * o.x; acc.y += e * o.y; acc.z += e * o.z; acc.w += e * o.w;
  }
  float sc = pl2s[0] / den;
  float add = sbr[s * 16 + h];
  __bf16* yp = yo + (size_t)s * 5120 + h * 64 + dg;
  yp[0] = (__bf16)(sc * acc.x + add);
  yp[1] = (__bf16)(sc * acc.y + add);
  yp[2] = (__bf16)(sc * acc.z + add);
  yp[3] = (__bf16)(sc * acc.w + add);
}

extern "C" void kernel_launch(void* const* d_in, const int* in_sizes, int n_in,
                              void* d_out, int out_size, void* d_ws, size_t ws_size,
                              hipStream_t stream) {
  (void)in_sizes; (void)n_in; (void)out_size; (void)ws_size;
  const float* hs   = (const float*)d_in[0];
  const float* Wq   = (const float*)d_in[1];
  const float* Wk   = (const float*)d_in[2];
  const float* Wv   = (const float*)d_in[3];
  const float* Wqb  = (const float*)d_in[4];
  const float* Wkb  = (const float*)d_in[5];
  const float* Wo   = (const float*)d_in[6];
  const float* bo   = (const float*)d_in[7];
  const float* W1   = (const float*)d_in[8];
  const float* b1   = (const float*)d_in[9];
  const float* W2   = (const float*)d_in[10];
  const float* b2   = (const float*)d_in[11];
  const float* plam = (const float*)d_in[12];
  const float* pl2s = (const float*)d_in[13];
  float* out = (float*)d_out;
  char* ws = (char*)d_ws;

  size_t off = 0;
  auto alloc = [&](size_t bytes) { char* p = ws + off; off += (bytes + 255) & ~(size_t)255; return p; };
  __bf16* Wt5    = (__bf16*)alloc((size_t)5 * 1024 * 1024 * 2);
  __bf16* WoW2t  = (__bf16*)alloc((size_t)1024 * 5120 * 2);   // [n][k], k: Wo 0..1023, W2 1024..5119
  __bf16* W1t    = (__bf16*)alloc((size_t)8192 * 1024 * 2);   // packed xp/gate 32-col interleave
  __bf16* xbf    = (__bf16*)alloc((size_t)2048 * 1024 * 2);
  __bf16* concat = (__bf16*)alloc((size_t)2048 * 5120 * 2);   // [y | ffin] bf16
  float*  proj  = (float*)alloc((size_t)2048 * 5120 * 4);
  float*  qbf32 = (float*)alloc((size_t)2048 * 1024 * 4);
  float*  kbf32 = (float*)alloc((size_t)2048 * 1024 * 4);
  __bf16* qbf   = (__bf16*)alloc((size_t)2048 * 1024 * 2);
  __bf16* kbf   = (__bf16*)alloc((size_t)2048 * 1024 * 2);
  float*  o_part = proj;                                      // 4 x 8 MB (proj dead after prep)
  float*  m_part = qbf32;                                     // 512 KB
  float*  l_part = qbf32 + (size_t)4 * 2048 * 16;             // 512 KB
  float*  gpart  = proj;                                      // 4 x 8 MB (after attnmerge)
  __bf16* vtbf  = (__bf16*)alloc((size_t)1024 * 2048 * 2);
  float*  sbrow = (float*)alloc((size_t)2048 * 16 * 4);
  float*  tsum  = (float*)alloc((size_t)64 * 16 * 64 * 4);

  // weight repack (batched)
  tconv5_k<<<dim3(32, 32, 5), 256, 0, stream>>>(Wq, Wk, Wv, Wqb, Wkb, Wt5);
  tconvwow2_k<<<dim3(32, 128, 2), 256, 0, stream>>>(Wo, W2, WoW2t);
  tconvw1p_k<<<dim3(256, 32), 256, 0, stream>>>(W1, W1t);

  rmsnorm_k<<<2048, 256, 0, stream>>>(hs, xbf);
  gemm_bt_k<<<dim3(40, 16), 256, 0, stream>>>(xbf, Wt5, proj, 5120, 1024);
  qkprep_k<<<8192, 256, 0, stream>>>(proj, qbf, kbf, qbf32, kbf32);
  tconv_k<<<dim3(32, 64), 256, 0, stream>>>(proj + 2048, vtbf, 5120, 2048);
  kbsum_k<<<dim3(64, 16), 64, 0, stream>>>(kbf32, tsum);
  sbrow2_k<<<dim3(64, 16), 64, 0, stream>>>(qbf32, kbf32, tsum, sbrow);
  attn_k<<<dim3(16, 4, 16), 256, 0, stream>>>(qbf, kbf, vtbf, o_part, m_part, l_part);
  attnmerge_k<<<2048, 256, 0, stream>>>(o_part, m_part, l_part, sbrow, pl2s, concat);
  // fused FFN1 + bias + SwiGLU -> concat cols 1024..5119 (256x256 ring-4)
  ffn1silu_k<<<dim3(32, 8), 512, 0, stream>>>(xbf, W1t, b1, concat);
  // merged (Wo + FFN2): [y|ffin] @ [Wo;W2], K=5120, split-K x4 -> partials
  gemm_partk_k<<<dim3(8, 16, 4), 256, 0, stream>>>(concat, WoW2t, gpart, 1024, 5120);
  // out = Σ partials + (bo+b2) + lam*h
  combine_k<<<2048, 256, 0, stream>>>(gpart, b2, bo, hs, plam, out);
}

// Round 6
// 361.248 us; speedup vs baseline: 1.0713x; 1.0312x over previous
//
#include <hip/hip_runtime.h>
#include <hip/hip_bf16.h>
#include <math.h>

typedef __bf16 bf16x8 __attribute__((ext_vector_type(8)));
typedef float  f32x4  __attribute__((ext_vector_type(4)));

#define GLD16(g, l) __builtin_amdgcn_global_load_lds(                      \
    (const __attribute__((address_space(1))) void*)(g),                    \
    (__attribute__((address_space(3))) void*)(l), 16, 0, 0)

#define SCHED_FENCE() __builtin_amdgcn_sched_barrier(0)

// BK=32 LDS tiles (64 B rows): global k-group g of row r stored at slot
// g ^ ((r>>1)&3) -> all ds_read_b128 fragment reads are 2-way (free).

// ---------------- generic 32x32 transpose tile body -------------------------
__device__ __forceinline__ void tconv_tile(const float* __restrict__ in,
                                           __bf16* __restrict__ out,
                                           int ldin, int ldout,
                                           int r0, int c0, int tid) {
  __shared__ float t[32][33];
  int tx = tid & 31, ty = tid >> 5;
  #pragma unroll
  for (int i = ty; i < 32; i += 8)
    t[i][tx] = in[(size_t)(r0 + i) * ldin + c0 + tx];
  __syncthreads();
  #pragma unroll
  for (int i = ty; i < 32; i += 8)
    out[(size_t)(c0 + i) * ldout + r0 + tx] = (__bf16)t[tx][i];
}

// plain transpose (used for V^T from proj)
__global__ __launch_bounds__(256) void tconv_k(const float* __restrict__ in,
                                               __bf16* __restrict__ out,
                                               int ldin, int ldout) {
  tconv_tile(in, out, ldin, ldout, blockIdx.y * 32, blockIdx.x * 32, threadIdx.x);
}

// W1 transpose with xp/gate 32-col interleave pack:
// packed out row r: group=r>>6, half=(r>>5)&1, idx=r&31
//   -> src output-col = half*4096 + group*32 + idx
__global__ __launch_bounds__(256) void tconvw1p_k(const float* __restrict__ W1,
                                                  __bf16* __restrict__ out) {
  int c0 = blockIdx.x * 32;
  int src_c0 = ((c0 >> 5) & 1) * 4096 + (c0 >> 6) * 32;
  __shared__ float t[32][33];
  int r0 = blockIdx.y * 32;
  int tid = threadIdx.x, tx = tid & 31, ty = tid >> 5;
  #pragma unroll
  for (int i = ty; i < 32; i += 8)
    t[i][tx] = W1[(size_t)(r0 + i) * 8192 + src_c0 + tx];
  __syncthreads();
  #pragma unroll
  for (int i = ty; i < 32; i += 8)
    out[(size_t)(c0 + i) * 1024 + r0 + tx] = (__bf16)t[tx][i];
}

// batched: 5 QKV-family weights (1024x1024 each) -> Wt5 (5 blocks of 1024x1024)
__global__ __launch_bounds__(256) void tconv5_k(const float* __restrict__ w0,
    const float* __restrict__ w1, const float* __restrict__ w2,
    const float* __restrict__ w3, const float* __restrict__ w4,
    __bf16* __restrict__ out) {
  const float* src[5] = {w0, w1, w2, w3, w4};
  int z = blockIdx.z;
  tconv_tile(src[z], out + (size_t)z * 1048576, 1024, 1024,
             blockIdx.y * 32, blockIdx.x * 32, threadIdx.x);
}

// batched: Wo (1024x1024) -> WoW2t cols 0..1023 ; W2 (4096x1024) -> cols 1024..
__global__ __launch_bounds__(256) void tconvwow2_k(const float* __restrict__ Wo,
    const float* __restrict__ W2, __bf16* __restrict__ WoW2t) {
  int tid = threadIdx.x;
  if (blockIdx.z == 0) {
    if (blockIdx.y >= 32) return;
    __shared__ float t[32][33];
    int r0 = blockIdx.y * 32, c0 = blockIdx.x * 32;
    int tx = tid & 31, ty = tid >> 5;
    #pragma unroll
    for (int i = ty; i < 32; i += 8)
      t[i][tx] = Wo[(size_t)(r0 + i) * 1024 + c0 + tx];
    __syncthreads();
    #pragma unroll
    for (int i = ty; i < 32; i += 8)
      WoW2t[(size_t)(c0 + i) * 5120 + r0 + tx] = (__bf16)t[tx][i];
  } else {
    __shared__ float t[32][33];
    int r0 = blockIdx.y * 32, c0 = blockIdx.x * 32;
    int tx = tid & 31, ty = tid >> 5;
    #pragma unroll
    for (int i = ty; i < 32; i += 8)
      t[i][tx] = W2[(size_t)(r0 + i) * 1024 + c0 + tx];
    __syncthreads();
    #pragma unroll
    for (int i = ty; i < 32; i += 8)
      WoW2t[(size_t)(c0 + i) * 5120 + 1024 + r0 + tx] = (__bf16)t[tx][i];
  }
}

// ---------------- RMSNorm ---------------------------------------------------
__global__ __launch_bounds__(256) void rmsnorm_k(const float* __restrict__ hs,
                                                 __bf16* __restrict__ x) {
  int row = blockIdx.x, tid = threadIdx.x;
  const float4 v = ((const float4*)(hs + (size_t)row * 1024))[tid];
  float ss = v.x * v.x + v.y * v.y + v.z * v.z + v.w * v.w;
  #pragma unroll
  for (int o = 32; o > 0; o >>= 1) ss += __shfl_xor(ss, o);
  __shared__ float ps[4];
  if ((tid & 63) == 0) ps[tid >> 6] = ss;
  __syncthreads();
  float tot = ps[0] + ps[1] + ps[2] + ps[3];
  float r = rsqrtf(tot * (1.0f / 1024.0f) + 1.1920929e-7f);
  __bf16* xr = x + (size_t)row * 1024 + tid * 4;
  xr[0] = (__bf16)(v.x * r); xr[1] = (__bf16)(v.y * r);
  xr[2] = (__bf16)(v.z * r); xr[3] = (__bf16)(v.w * r);
}

// ---------------- GEMM 128x128 ring-3, counted vmcnt, order-pinned ----------
__global__ __launch_bounds__(256, 3) void gemm_bt_k(
    const __bf16* __restrict__ A, const __bf16* __restrict__ Bt,
    float* __restrict__ C, int N, int K) {
  __shared__ __bf16 sA[3][128 * 32];
  __shared__ __bf16 sB[3][128 * 32];
  const int tid = threadIdx.x;
  const int lane = tid & 63;
  const int quad = lane >> 4, l16 = lane & 15;
  const int wave = tid >> 6;
  const int waveM = wave >> 1, waveN = wave & 1;
  const int m0 = blockIdx.y * 128, n0 = blockIdx.x * 128;
  const int nk = K >> 5;
  const int rowS = tid >> 2;
  const int kg = ((tid & 3) ^ ((rowS >> 1) & 3)) * 8;
  const __bf16* gA0 = A + (size_t)(m0 + rowS) * K + kg;
  const __bf16* gA1 = gA0 + (size_t)64 * K;
  const __bf16* gB0 = Bt + (size_t)(n0 + rowS) * K + kg;
  const __bf16* gB1 = gB0 + (size_t)64 * K;
  const int lo0 = tid * 8, lo1 = 2048 + tid * 8;

  auto stage = [&](int t) {
    int s = t % 3;
    __bf16* dA = sA[s];
    __bf16* dB = sB[s];
    GLD16(gA0 + t * 32, dA + lo0);
    GLD16(gA1 + t * 32, dA + lo1);
    GLD16(gB0 + t * 32, dB + lo0);
    GLD16(gB1 + t * 32, dB + lo1);
  };
  stage(0); stage(1);

  f32x4 acc[4][4] = {};
  #pragma unroll 1
  for (int i = 0; i < nk; ++i) {
    if (i < nk - 1)
      asm volatile("s_waitcnt vmcnt(4)" ::: "memory");
    else
      asm volatile("s_waitcnt vmcnt(0)" ::: "memory");
    __builtin_amdgcn_s_barrier();
    SCHED_FENCE();
    int cs = i % 3;
    const __bf16* cA = sA[cs];
    const __bf16* cB = sB[cs];
    if (i + 2 < nk) stage(i + 2);   // issue next-tile loads FIRST (pinned)
    SCHED_FENCE();
    bf16x8 af[4], bfv[4];
    #pragma unroll
    for (int mt = 0; mt < 4; ++mt) {
      int r = waveM * 64 + mt * 16 + l16;
      af[mt] = *(const bf16x8*)(cA + r * 32 + ((quad ^ ((r >> 1) & 3)) * 8));
    }
    #pragma unroll
    for (int nt = 0; nt < 4; ++nt) {
      int r = waveN * 64 + nt * 16 + l16;
      bfv[nt] = *(const bf16x8*)(cB + r * 32 + ((quad ^ ((r >> 1) & 3)) * 8));
    }
    __builtin_amdgcn_s_setprio(1);
    #pragma unroll
    for (int mt = 0; mt < 4; ++mt)
      #pragma unroll
      for (int nt = 0; nt < 4; ++nt)
        acc[mt][nt] = __builtin_amdgcn_mfma_f32_16x16x32_bf16(af[mt], bfv[nt], acc[mt][nt], 0, 0, 0);
    __builtin_amdgcn_s_setprio(0);
    SCHED_FENCE();
  }
  #pragma unroll
  for (int mt = 0; mt < 4; ++mt) {
    int row = m0 + waveM * 64 + mt * 16 + quad * 4;
    #pragma unroll
    for (int nt = 0; nt < 4; ++nt) {
      int col = n0 + waveN * 64 + nt * 16 + l16;
      #pragma unroll
      for (int r = 0; r < 4; ++r)
        C[(size_t)(row + r) * N + col] = acc[mt][nt][r];
    }
  }
}

// ---------------- GEMM 128x128 ring-3, split-K partial buffers --------------
__global__ __launch_bounds__(256, 3) void gemm_partk_k(
    const __bf16* __restrict__ A, const __bf16* __restrict__ Bt,
    float* __restrict__ P, int N, int K) {
  __shared__ __bf16 sA[3][128 * 32];
  __shared__ __bf16 sB[3][128 * 32];
  const int tid = threadIdx.x;
  const int lane = tid & 63;
  const int quad = lane >> 4, l16 = lane & 15;
  const int wave = tid >> 6;
  const int waveM = wave >> 1, waveN = wave & 1;
  const int m0 = blockIdx.y * 128, n0 = blockIdx.x * 128;
  const int kz = blockIdx.z, nz = gridDim.z;
  const int kper = K / nz, kbeg = kz * kper;
  const int nk = kper >> 5;
  const size_t MN = (size_t)gridDim.y * 128 * N;
  float* C = P + (size_t)kz * MN;
  const int rowS = tid >> 2;
  const int kg = ((tid & 3) ^ ((rowS >> 1) & 3)) * 8;
  const __bf16* gA0 = A + (size_t)(m0 + rowS) * K + kbeg + kg;
  const __bf16* gA1 = gA0 + (size_t)64 * K;
  const __bf16* gB0 = Bt + (size_t)(n0 + rowS) * K + kbeg + kg;
  const __bf16* gB1 = gB0 + (size_t)64 * K;
  const int lo0 = tid * 8, lo1 = 2048 + tid * 8;

  auto stage = [&](int t) {
    int s = t % 3;
    __bf16* dA = sA[s];
    __bf16* dB = sB[s];
    GLD16(gA0 + t * 32, dA + lo0);
    GLD16(gA1 + t * 32, dA + lo1);
    GLD16(gB0 + t * 32, dB + lo0);
    GLD16(gB1 + t * 32, dB + lo1);
  };
  stage(0); stage(1);

  f32x4 acc[4][4] = {};
  #pragma unroll 1
  for (int i = 0; i < nk; ++i) {
    if (i < nk - 1)
      asm volatile("s_waitcnt vmcnt(4)" ::: "memory");
    else
      asm volatile("s_waitcnt vmcnt(0)" ::: "memory");
    __builtin_amdgcn_s_barrier();
    SCHED_FENCE();
    int cs = i % 3;
    const __bf16* cA = sA[cs];
    const __bf16* cB = sB[cs];
    if (i + 2 < nk) stage(i + 2);
    SCHED_FENCE();
    bf16x8 af[4], bfv[4];
    #pragma unroll
    for (int mt = 0; mt < 4; ++mt) {
      int r = waveM * 64 + mt * 16 + l16;
      af[mt] = *(const bf16x8*)(cA + r * 32 + ((quad ^ ((r >> 1) & 3)) * 8));
    }
    #pragma unroll
    for (int nt = 0; nt < 4; ++nt) {
      int r = waveN * 64 + nt * 16 + l16;
      bfv[nt] = *(const bf16x8*)(cB + r * 32 + ((quad ^ ((r >> 1) & 3)) * 8));
    }
    __builtin_amdgcn_s_setprio(1);
    #pragma unroll
    for (int mt = 0; mt < 4; ++mt)
      #pragma unroll
      for (int nt = 0; nt < 4; ++nt)
        acc[mt][nt] = __builtin_amdgcn_mfma_f32_16x16x32_bf16(af[mt], bfv[nt], acc[mt][nt], 0, 0, 0);
    __builtin_amdgcn_s_setprio(0);
    SCHED_FENCE();
  }
  #pragma unroll
  for (int mt = 0; mt < 4; ++mt) {
    int row = m0 + waveM * 64 + mt * 16 + quad * 4;
    #pragma unroll
    for (int nt = 0; nt < 4; ++nt) {
      int col = n0 + waveN * 64 + nt * 16 + l16;
      #pragma unroll
      for (int r = 0; r < 4; ++r)
        C[(size_t)(row + r) * N + col] = acc[mt][nt][r];
    }
  }
}

// ---------------- fused FFN1 + bias + SwiGLU, 256x256 ring-4 pipeline -------
// Order-pinned per K-tile (round-3 lesson); FROZEN — verified 46.4 us.
__global__ __launch_bounds__(512, 2) void ffn1silu_k(
    const __bf16* __restrict__ A, const __bf16* __restrict__ W1t,
    const float* __restrict__ b1, __bf16* __restrict__ ffout) {
  __shared__ __bf16 sA[4][256 * 32];
  __shared__ __bf16 sB[4][256 * 32];
  const int tid = threadIdx.x, lane = tid & 63, w = tid >> 6;
  const int quad = lane >> 4, l16 = lane & 15;
  const int wm = w >> 2, wn = w & 3;          // 2 M-waves x 4 N-waves
  const int m0 = blockIdx.y * 256;            // M = 2048 -> 8
  const int n0p = blockIdx.x * 256;           // packed N = 8192 -> 32
  const int K = 1024, NKT = 32;
  const int rowS = tid >> 2;                  // 0..127
  const int kg = ((tid & 3) ^ ((rowS >> 1) & 3)) * 8;
  const __bf16* gA0 = A + (size_t)(m0 + rowS) * K + kg;
  const __bf16* gA1 = gA0 + (size_t)128 * K;
  const __bf16* gB0 = W1t + (size_t)(n0p + rowS) * K + kg;
  const __bf16* gB1 = gB0 + (size_t)128 * K;
  const int lo0 = tid * 8, lo1 = 4096 + tid * 8;

  f32x4 acc[8][4] = {};

  auto stageA = [&](int t) {
    __bf16* d = sA[t & 3];
    GLD16(gA0 + t * 32, d + lo0);
    GLD16(gA1 + t * 32, d + lo1);
  };
  auto stageB = [&](int t) {
    __bf16* d = sB[t & 3];
    GLD16(gB0 + t * 32, d + lo0);
    GLD16(gB1 + t * 32, d + lo1);
  };

  auto compute_half = [&](const __bf16* cA, const bf16x8* bfr, int half) {
    bf16x8 af[4];
    #pragma unroll
    for (int mt = 0; mt < 4; ++mt) {
      int r = wm * 128 + half * 64 + mt * 16 + l16;
      af[mt] = *(const bf16x8*)(cA + r * 32 + ((quad ^ ((r >> 1) & 3)) * 8));
    }
    __builtin_amdgcn_s_setprio(1);
    #pragma unroll
    for (int mt = 0; mt < 4; ++mt)
      #pragma unroll
      for (int nt = 0; nt < 4; ++nt)
        acc[half * 4 + mt][nt] = __builtin_amdgcn_mfma_f32_16x16x32_bf16(
            af[mt], bfr[nt], acc[half * 4 + mt][nt], 0, 0, 0);
    __builtin_amdgcn_s_setprio(0);
  };

  // prologue: prime tiles 0,1,2 (12 loads in flight)
  stageA(0); stageB(0);
  stageA(1); stageB(1);
  stageA(2); stageB(2);

  #pragma unroll 1
  for (int t = 0; t < NKT; ++t) {
    if (t < NKT - 2)
      asm volatile("s_waitcnt vmcnt(8)" ::: "memory");
    else if (t == NKT - 2)
      asm volatile("s_waitcnt vmcnt(4)" ::: "memory");
    else
      asm volatile("s_waitcnt vmcnt(0)" ::: "memory");
    __builtin_amdgcn_s_barrier();
    SCHED_FENCE();
    const __bf16* cA = sA[t & 3];
    const __bf16* cB = sB[t & 3];
    if (t + 3 < NKT) stageA(t + 3);
    SCHED_FENCE();
    bf16x8 bfr[4];
    #pragma unroll
    for (int nt = 0; nt < 4; ++nt) {
      int r = wn * 64 + nt * 16 + l16;
      bfr[nt] = *(const bf16x8*)(cB + r * 32 + ((quad ^ ((r >> 1) & 3)) * 8));
    }
    compute_half(cA, bfr, 0);
    SCHED_FENCE();
    if (t + 3 < NKT) stageB(t + 3);
    SCHED_FENCE();
    compute_half(cA, bfr, 1);
    SCHED_FENCE();
  }

  // epilogue: bias + SwiGLU, unpack interleaved xp/gate
  const int colbase = (blockIdx.x * 4 + wn) * 32;   // logical col base (0..4095)
  #pragma unroll
  for (int j = 0; j < 8; ++j) {
    int row = m0 + wm * 128 + (j >> 2) * 64 + (j & 3) * 16 + quad * 4;
    #pragma unroll
    for (int p = 0; p < 2; ++p) {
      int col = colbase + p * 16 + l16;
      float bxv = b1[col], bgv = b1[col + 4096];
      #pragma unroll
      for (int r = 0; r < 4; ++r) {
        float xp = acc[j][p][r] + bxv;
        float g  = acc[j][p + 2][r] + bgv;
        float val = xp * g / (1.f + __expf(-g));
        ffout[(size_t)(row + r) * 5120 + 1024 + col] = (__bf16)val;
      }
    }
  }
}

// ---------------- combine: out = Σ4 partials + (bo+b2) + lam*h --------------
__global__ __launch_bounds__(256) void combine_k(
    const float* __restrict__ P, const float* __restrict__ b2,
    const float* __restrict__ bo, const float* __restrict__ hs,
    const float* __restrict__ plam, float* __restrict__ out) {
  const size_t MN = (size_t)2048 * 1024;
  size_t i = ((size_t)blockIdx.x * 256 + threadIdx.x) * 4;
  int col = (int)(i & 1023);
  float4 a0 = *(const float4*)(P + i);
  float4 a1 = *(const float4*)(P + MN + i);
  float4 a2 = *(const float4*)(P + 2 * MN + i);
  float4 a3 = *(const float4*)(P + 3 * MN + i);
  float4 h  = *(const float4*)(hs + i);
  float4 v2 = *(const float4*)(b2 + col);
  float4 vo = *(const float4*)(bo + col);
  float lam = plam[0];
  float4 o;
  o.x = (a0.x + a1.x) + (a2.x + a3.x) + v2.x + vo.x + lam * h.x;
  o.y = (a0.y + a1.y) + (a2.y + a3.y) + v2.y + vo.y + lam * h.y;
  o.z = (a0.z + a1.z) + (a2.z + a3.z) + v2.z + vo.z + lam * h.z;
  o.w = (a0.w + a1.w) + (a2.w + a3.w) + v2.w + vo.w + lam * h.w;
  *(float4*)(out + i) = o;
}

// ---------------- l2norm + RoPE for q,k,qb,kb -------------------------------
// powf -> exp2f (1 v_exp) and fast __sinf/__cosf: trig error ~1e-4 rad is
// far below the intentional bf16 cast quantum (2^-8), matching reference.
__global__ __launch_bounds__(256) void qkprep_k(const float* __restrict__ proj,
    __bf16* __restrict__ qo, __bf16* __restrict__ ko,
    float* __restrict__ qbo, float* __restrict__ kbo) {
  int gw = blockIdx.x * 4 + (threadIdx.x >> 6);
  int lane = threadIdx.x & 63;
  int s = gw >> 4, h = gw & 15;
  int j = lane & 31;
  // 1000^(-j/32) == 2^(-j*log2(1000)/32)
  float inv = exp2f(-0.31143076f * (float)j);
  float ang = (float)s * inv;
  float cb = (float)(__bf16)__cosf(ang);
  float sb = (float)(__bf16)__sinf(ang);
  size_t ibase = (size_t)s * 5120 + h * 64 + lane;
  size_t obase = (size_t)s * 1024 + h * 64 + lane;
  bool lo = lane < 32;

  auto proc = [&](const float* src) -> float {
    float xv = src[ibase];
    float ss = xv * xv;
    #pragma unroll
    for (int o = 32; o > 0; o >>= 1) ss += __shfl_xor(ss, o);
    float y = xv / fmaxf(sqrtf(ss), 1e-12f);
    float yp = __shfl_xor(y, 32);
    return lo ? (y * cb + yp * sb) : (y * cb - yp * sb);
  };
  qo[obase]  = (__bf16)proc(proj + 0);
  ko[obase]  = (__bf16)proc(proj + 1024);
  qbo[obase] = proc(proj + 3072);
  kbo[obase] = proc(proj + 4096);
}

// ---------------- sb row-sum via two-level cumsum ---------------------------
// 256-thread kbsum: 4 waves each sum 8 rows; writes 8-row partials (tsum8)
// and the 32-row tile sum (tsum).
__global__ __launch_bounds__(256) void kbsum_k(const float* __restrict__ kb,
                                               float* __restrict__ tsum,
                                               float* __restrict__ tsum8) {
  int t = blockIdx.x, h = blockIdx.y;
  int d = threadIdx.x & 63, w = threadIdx.x >> 6;
  size_t base = (size_t)h * 64 + d;
  float s = 0.f;
  #pragma unroll
  for (int r = 0; r < 8; ++r)
    s += kb[(size_t)(t * 32 + w * 8 + r) * 1024 + base];
  tsum8[(size_t)((t * 4 + w) * 16 + h) * 64 + d] = s;
  __shared__ float ps[4][64];
  ps[w][d] = s;
  __syncthreads();
  if (w == 0)
    tsum[(size_t)(t * 16 + h) * 64 + d] = (ps[0][d] + ps[1][d]) + (ps[2][d] + ps[3][d]);
}

// 256-thread sbrow2: wave g handles rows [g*8, g*8+8) of the tile; its cumsum
// seed = tile-prefix (tsum) + in-tile prefix from tsum8 (<=3 loads) instead of
// re-reading up to 24 kb rows. 4x parallel reduce, 16 waves/CU (was 4).
__global__ __launch_bounds__(256) void sbrow2_k(const float* __restrict__ qb,
                                                const float* __restrict__ kb,
                                                const float* __restrict__ tsum,
                                                const float* __restrict__ tsum8,
                                                float* __restrict__ sb) {
  int t = blockIdx.x, h = blockIdx.y;
  int d = threadIdx.x & 63, g = threadIdx.x >> 6;
  size_t base = (size_t)h * 64 + d;
  float run = 0.f;
  for (int tp = 0; tp < t; ++tp) run += tsum[(size_t)(tp * 16 + h) * 64 + d];
  for (int w = 0; w < g; ++w) run += tsum8[(size_t)((t * 4 + w) * 16 + h) * 64 + d];
  int r0 = t * 32 + g * 8;
  for (int s0 = 0; s0 < 8; s0 += 4) {
    float p[4];
    #pragma unroll
    for (int u = 0; u < 4; ++u) {
      size_t off = (size_t)(r0 + s0 + u) * 1024 + base;
      run += kb[off];
      p[u] = qb[off] * run;
    }
    #pragma unroll
    for (int o = 32; o > 0; o >>= 1) {
      #pragma unroll
      for (int u = 0; u < 4; ++u) p[u] += __shfl_xor(p[u], o);
    }
    if (d == 0) {
      #pragma unroll
      for (int u = 0; u < 4; ++u) sb[(r0 + s0 + u) * 16 + h] = 0.125f * p[u];
    }
  }
}

// ---------------- flash attention: split-KV x4, double-buffered K/V ---------
// K/V ring-2: stage(kt+1) issued AFTER the per-tile barrier into the buffer
// sealed dead by it (last read at kt-1); compute(kt) reads data staged a full
// tile ago, so the barrier's implicit vmcnt(0) drains OLD loads (latency
// hidden under prior tile's compute). One barrier per tile (was 2 + fresh
// drain). LDS 40KB -> 4 blocks/CU = grid limit, no occupancy loss.
__global__ __launch_bounds__(256) void attn_k(const __bf16* __restrict__ qg,
    const __bf16* __restrict__ kg, const __bf16* __restrict__ vtg,
    float* __restrict__ o_part, float* __restrict__ m_part,
    float* __restrict__ l_part) {
  __shared__ __bf16 sK[2][64 * 64];
  __shared__ __bf16 sVt[2][64 * 64];
  __shared__ __bf16 sP[4][16 * 64];
  const int pair = blockIdx.x, j4 = blockIdx.y, hh = blockIdx.z;
  const int tid = threadIdx.x, lane = tid & 63, w = tid >> 6;
  const int quad = lane >> 4, l16 = lane & 15;
  const int srow = tid >> 3;
  const int sg = (tid & 7) ^ (srow & 7);
  __bf16* sPw = sP[w];

  auto stage = [&](int kt) {
    int b = kt & 1;
    const __bf16* gK = kg + (size_t)(kt * 64 + srow) * 1024 + hh * 64 + sg * 8;
    const __bf16* gV = vtg + (size_t)(hh * 64 + srow) * 2048 + kt * 64 + sg * 8;
    GLD16(gK, sK[b] + tid * 8);
    GLD16(gK + (size_t)32 * 1024, sK[b] + tid * 8 + 2048);
    GLD16(gV, sVt[b] + tid * 8);
    GLD16(gV + (size_t)32 * 2048, sVt[b] + tid * 8 + 2048);
  };

  for (int phase = 0; phase < 2; ++phase) {
    const int qt = phase ? 31 - pair : pair;
    const int q0 = qt * 64;
    const int n = qt + 1;
    const int kb = (j4 * n) >> 2, ke = ((j4 + 1) * n) >> 2;
    bf16x8 qf[2];
    #pragma unroll
    for (int kk = 0; kk < 2; ++kk)
      qf[kk] = *(const bf16x8*)(qg + (size_t)(q0 + w * 16 + l16) * 1024 + hh * 64 + kk * 32 + quad * 8);
    f32x4 accO[4] = {};
    float m_[4], l_[4];
    #pragma unroll
    for (int r = 0; r < 4; ++r) { m_[r] = -INFINITY; l_[r] = 0.f; }

    __syncthreads();                 // seal previous phase's buffer reads
    if (kb < ke) stage(kb);

    for (int kt = kb; kt < ke; ++kt) {
      __syncthreads();               // implicit vmcnt(0): buf[kt&1] ready;
                                     // seals buf[(kt+1)&1] (last read kt-1)
      SCHED_FENCE();
      if (kt + 1 < ke) stage(kt + 1);
      SCHED_FENCE();
      const __bf16* cK = sK[kt & 1];
      const __bf16* cV = sVt[kt & 1];

      f32x4 s4[4];
      #pragma unroll
      for (int nt = 0; nt < 4; ++nt) {
        int r = nt * 16 + l16;
        bf16x8 b0 = *(const bf16x8*)(cK + r * 64 + ((quad ^ (r & 7)) * 8));
        bf16x8 b1 = *(const bf16x8*)(cK + r * 64 + (((4 + quad) ^ (r & 7)) * 8));
        f32x4 sa = {0.f, 0.f, 0.f, 0.f};
        sa = __builtin_amdgcn_mfma_f32_16x16x32_bf16(qf[0], b0, sa, 0, 0, 0);
        sa = __builtin_amdgcn_mfma_f32_16x16x32_bf16(qf[1], b1, sa, 0, 0, 0);
        s4[nt] = sa;
      }
      if (kt == qt) {
        #pragma unroll
        for (int nt = 0; nt < 4; ++nt)
          #pragma unroll
          for (int r = 0; r < 4; ++r)
            if (nt * 16 + l16 > w * 16 + quad * 4 + r) s4[nt][r] = -INFINITY;
      }
      float mx[4], al[4], rs[4];
      #pragma unroll
      for (int r = 0; r < 4; ++r)
        mx[r] = fmaxf(fmaxf(s4[0][r], s4[1][r]), fmaxf(s4[2][r], s4[3][r]));
      #pragma unroll
      for (int o = 1; o < 16; o <<= 1)
        #pragma unroll
        for (int r = 0; r < 4; ++r) mx[r] = fmaxf(mx[r], __shfl_xor(mx[r], o));
      #pragma unroll
      for (int r = 0; r < 4; ++r) {
        float mn = fmaxf(m_[r], mx[r]);
        al[r] = __expf(m_[r] - mn);
        m_[r] = mn;
      }
      float p[4][4];
      #pragma unroll
      for (int nt = 0; nt < 4; ++nt)
        #pragma unroll
        for (int r = 0; r < 4; ++r)
          p[nt][r] = __expf(s4[nt][r] - m_[r]);
      #pragma unroll
      for (int r = 0; r < 4; ++r)
        rs[r] = (p[0][r] + p[1][r]) + (p[2][r] + p[3][r]);
      #pragma unroll
      for (int o = 1; o < 16; o <<= 1)
        #pragma unroll
        for (int r = 0; r < 4; ++r) rs[r] += __shfl_xor(rs[r], o);
      #pragma unroll
      for (int r = 0; r < 4; ++r) l_[r] = l_[r] * al[r] + rs[r];
      #pragma unroll
      for (int nt = 0; nt < 4; ++nt)
        #pragma unroll
        for (int r = 0; r < 4; ++r) accO[nt][r] *= al[r];
      #pragma unroll
      for (int nt = 0; nt < 4; ++nt)
        #pragma unroll
        for (int r = 0; r < 4; ++r) {
          int row = quad * 4 + r, col = nt * 16 + l16;
          sPw[row * 64 + (col ^ ((row & 7) << 3))] = (__bf16)p[nt][r];
        }
      #pragma unroll
      for (int kk = 0; kk < 2; ++kk) {
        bf16x8 a = *(const bf16x8*)(sPw + l16 * 64 + (((kk * 4 + quad) ^ (l16 & 7)) * 8));
        #pragma unroll
        for (int nt = 0; nt < 4; ++nt) {
          int vr = nt * 16 + l16;
          bf16x8 bv = *(const bf16x8*)(cV + vr * 64 + (((kk * 4 + quad) ^ (vr & 7)) * 8));
          accO[nt] = __builtin_amdgcn_mfma_f32_16x16x32_bf16(a, bv, accO[nt], 0, 0, 0);
        }
      }
      // no trailing barrier: sP is wave-private; K/V buffers are ring-2 sealed
    }
    #pragma unroll
    for (int r = 0; r < 4; ++r) {
      int grow = q0 + w * 16 + quad * 4 + r;
      if (l16 == 0) {
        m_part[((size_t)j4 * 2048 + grow) * 16 + hh] = m_[r];
        l_part[((size_t)j4 * 2048 + grow) * 16 + hh] = l_[r];
      }
      #pragma unroll
      for (int nt = 0; nt < 4; ++nt)
        o_part[((size_t)j4 * 2048 + grow) * 1024 + hh * 64 + nt * 16 + l16] = accO[nt][r];
    }
  }
}

// ---------------- merge 4 KV-partials -> y into concat (stride 5120) --------
__global__ __launch_bounds__(256) void attnmerge_k(const float* __restrict__ o_part,
    const float* __restrict__ m_part, const float* __restrict__ l_part,
    const float* __restrict__ sbr, const float* __restrict__ pl2s,
    __bf16* __restrict__ yo) {
  int idx = blockIdx.x * 256 + threadIdx.x;
  int s = idx >> 8, rem = idx & 255;
  int h = rem >> 4, dg = (rem & 15) * 4;
  float m[4], l[4];
  #pragma unroll
  for (int j = 0; j < 4; ++j) {
    m[j] = m_part[((size_t)j * 2048 + s) * 16 + h];
    l[j] = l_part[((size_t)j * 2048 + s) * 16 + h];
  }
  float M = fmaxf(fmaxf(m[0], m[1]), fmaxf(m[2], m[3]));
  float den = 0.f;
  float4 acc = {0.f, 0.f, 0.f, 0.f};
  #pragma unroll
  for (int j = 0; j < 4; ++j) {
    float e = __expf(m[j] - M);
    den += l[j] * e;
    float4 o = *(const float4*)(o_part + ((size_t)j * 2048 + s) * 1024 + h * 64 + dg);
    acc.x += e * o.x; acc.y += e * o.y; acc.z += e * o.z; acc.w += e * o.w;
  }
  float sc = pl2s[0] / den;
  float add = sbr[s * 16 + h];
  __bf16* yp = yo + (size_t)s * 5120 + h * 64 + dg;
  yp[0] = (__bf16)(sc * acc.x + add);
  yp[1] = (__bf16)(sc * acc.y + add);
  yp[2] = (__bf16)(sc * acc.z + add);
  yp[3] = (__bf16)(sc * acc.w + add);
}

extern "C" void kernel_launch(void* const* d_in, const int* in_sizes, int n_in,
                              void* d_out, int out_size, void* d_ws, size_t ws_size,
                              hipStream_t stream) {
  (void)in_sizes; (void)n_in; (void)out_size; (void)ws_size;
  const float* hs   = (const float*)d_in[0];
  const float* Wq   = (const float*)d_in[1];
  const float* Wk   = (const float*)d_in[2];
  const float* Wv   = (const float*)d_in[3];
  const float* Wqb  = (const float*)d_in[4];
  const float* Wkb  = (const float*)d_in[5];
  const float* Wo   = (const float*)d_in[6];
  const float* bo   = (const float*)d_in[7];
  const float* W1   = (const float*)d_in[8];
  const float* b1   = (const float*)d_in[9];
  const float* W2   = (const float*)d_in[10];
  const float* b2   = (const float*)d_in[11];
  const float* plam = (const float*)d_in[12];
  const float* pl2s = (const float*)d_in[13];
  float* out = (float*)d_out;
  char* ws = (char*)d_ws;

  size_t off = 0;
  auto alloc = [&](size_t bytes) { char* p = ws + off; off += (bytes + 255) & ~(size_t)255; return p; };
  __bf16* Wt5    = (__bf16*)alloc((size_t)5 * 1024 * 1024 * 2);
  __bf16* WoW2t  = (__bf16*)alloc((size_t)1024 * 5120 * 2);   // [n][k], k: Wo 0..1023, W2 1024..5119
  __bf16* W1t    = (__bf16*)alloc((size_t)8192 * 1024 * 2);   // packed xp/gate 32-col interleave
  __bf16* xbf    = (__bf16*)alloc((size_t)2048 * 1024 * 2);
  __bf16* concat = (__bf16*)alloc((size_t)2048 * 5120 * 2);   // [y | ffin] bf16
  float*  proj  = (float*)alloc((size_t)2048 * 5120 * 4);
  float*  qbf32 = (float*)alloc((size_t)2048 * 1024 * 4);
  float*  kbf32 = (float*)alloc((size_t)2048 * 1024 * 4);
  __bf16* qbf   = (__bf16*)alloc((size_t)2048 * 1024 * 2);
  __bf16* kbf   = (__bf16*)alloc((size_t)2048 * 1024 * 2);
  float*  o_part = proj;                                      // 4 x 8 MB (proj dead after prep)
  float*  m_part = qbf32;                                     // 512 KB
  float*  l_part = qbf32 + (size_t)4 * 2048 * 16;             // 512 KB
  float*  gpart  = proj;                                      // 4 x 8 MB (after attnmerge)
  __bf16* vtbf  = (__bf16*)alloc((size_t)1024 * 2048 * 2);
  float*  sbrow = (float*)alloc((size_t)2048 * 16 * 4);
  float*  tsum  = (float*)alloc((size_t)64 * 16 * 64 * 4);
  float*  tsum8 = (float*)alloc((size_t)256 * 16 * 64 * 4);

  // weight repack (batched)
  tconv5_k<<<dim3(32, 32, 5), 256, 0, stream>>>(Wq, Wk, Wv, Wqb, Wkb, Wt5);
  tconvwow2_k<<<dim3(32, 128, 2), 256, 0, stream>>>(Wo, W2, WoW2t);
  tconvw1p_k<<<dim3(256, 32), 256, 0, stream>>>(W1, W1t);

  rmsnorm_k<<<2048, 256, 0, stream>>>(hs, xbf);
  gemm_bt_k<<<dim3(40, 16), 256, 0, stream>>>(xbf, Wt5, proj, 5120, 1024);
  qkprep_k<<<8192, 256, 0, stream>>>(proj, qbf, kbf, qbf32, kbf32);
  tconv_k<<<dim3(32, 64), 256, 0, stream>>>(proj + 2048, vtbf, 5120, 2048);
  kbsum_k<<<dim3(64, 16), 256, 0, stream>>>(kbf32, tsum, tsum8);
  sbrow2_k<<<dim3(64, 16), 256, 0, stream>>>(qbf32, kbf32, tsum, tsum8, sbrow);
  attn_k<<<dim3(16, 4, 16), 256, 0, stream>>>(qbf, kbf, vtbf, o_part, m_part, l_part);
  attnmerge_k<<<2048, 256, 0, stream>>>(o_part, m_part, l_part, sbrow, pl2s, concat);
  // fused FFN1 + bias + SwiGLU -> concat cols 1024..5119 (256x256 ring-4)
  ffn1silu_k<<<dim3(32, 8), 512, 0, stream>>>(xbf, W1t, b1, concat);
  // merged (Wo + FFN2): [y|ffin] @ [Wo;W2], K=5120, split-K x4 -> partials
  gemm_partk_k<<<dim3(8, 16, 4), 256, 0, stream>>>(concat, WoW2t, gpart, 1024, 5120);
  // out = Σ partials + (bo+b2) + lam*h
  combine_k<<<2048, 256, 0, stream>>>(gpart, b2, bo, hs, plam, out);
}

// Round 7
// 343.968 us; speedup vs baseline: 1.1251x; 1.0502x over previous
//
#include <hip/hip_runtime.h>
#include <hip/hip_bf16.h>
#include <math.h>

typedef __bf16 bf16x8 __attribute__((ext_vector_type(8)));
typedef float  f32x4  __attribute__((ext_vector_type(4)));

#define GLD16(g, l) __builtin_amdgcn_global_load_lds(                      \
    (const __attribute__((address_space(1))) void*)(g),                    \
    (__attribute__((address_space(3))) void*)(l), 16, 0, 0)

#define SCHED_FENCE() __builtin_amdgcn_sched_barrier(0)

// BK=32 LDS tiles (64 B rows): global k-group g of row r stored at slot
// g ^ ((r>>1)&3) -> all ds_read_b128 fragment reads are 2-way (free).

// ---------------- merged weight repack (was 3 kernels) ----------------------
// 1D grid 18432 tiles: [0,5120) QKV-family 5x1024x1024 -> Wt5;
// [5120,6144) Wo -> WoW2t cols 0..1023; [6144,10240) W2 -> WoW2t cols 1024..;
// [10240,18432) W1 -> W1t with xp/gate 32-col interleave pack.
__global__ __launch_bounds__(256) void repack_k(
    const float* __restrict__ Wq, const float* __restrict__ Wk,
    const float* __restrict__ Wv, const float* __restrict__ Wqb,
    const float* __restrict__ Wkb, const float* __restrict__ Wo,
    const float* __restrict__ W2, const float* __restrict__ W1,
    __bf16* __restrict__ Wt5, __bf16* __restrict__ WoW2t,
    __bf16* __restrict__ W1t) {
  int t = blockIdx.x;
  const float* in; __bf16* outp;
  int ldin, ldout, r0, c0, cin0, oofs;
  if (t < 5120) {
    int w = t >> 10, rem = t & 1023;
    const float* src[5] = {Wq, Wk, Wv, Wqb, Wkb};
    in = src[w]; ldin = 1024;
    r0 = (rem >> 5) << 5; c0 = (rem & 31) << 5; cin0 = c0;
    outp = Wt5 + (size_t)w * 1048576; ldout = 1024; oofs = 0;
  } else if (t < 6144) {
    int rem = t - 5120;
    in = Wo; ldin = 1024;
    r0 = (rem >> 5) << 5; c0 = (rem & 31) << 5; cin0 = c0;
    outp = WoW2t; ldout = 5120; oofs = 0;
  } else if (t < 10240) {
    int rem = t - 6144;
    in = W2; ldin = 1024;
    r0 = (rem >> 5) << 5; c0 = (rem & 31) << 5; cin0 = c0;
    outp = WoW2t; ldout = 5120; oofs = 1024;
  } else {
    int rem = t - 10240;
    in = W1; ldin = 8192;
    c0 = (rem & 255) << 5; r0 = (rem >> 8) << 5;
    cin0 = ((c0 >> 5) & 1) * 4096 + (c0 >> 6) * 32;
    outp = W1t; ldout = 1024; oofs = 0;
  }
  __shared__ float sh[32][33];
  int tid = threadIdx.x, tx = tid & 31, ty = tid >> 5;
  #pragma unroll
  for (int i = ty; i < 32; i += 8)
    sh[i][tx] = in[(size_t)(r0 + i) * ldin + cin0 + tx];
  __syncthreads();
  #pragma unroll
  for (int i = ty; i < 32; i += 8)
    outp[(size_t)(c0 + i) * ldout + oofs + r0 + tx] = (__bf16)sh[tx][i];
}

// plain transpose (used for V^T from vproj)
__global__ __launch_bounds__(256) void tconv_k(const float* __restrict__ in,
                                               __bf16* __restrict__ out,
                                               int ldin, int ldout) {
  __shared__ float t[32][33];
  int r0 = blockIdx.y * 32, c0 = blockIdx.x * 32;
  int tid = threadIdx.x, tx = tid & 31, ty = tid >> 5;
  #pragma unroll
  for (int i = ty; i < 32; i += 8)
    t[i][tx] = in[(size_t)(r0 + i) * ldin + c0 + tx];
  __syncthreads();
  #pragma unroll
  for (int i = ty; i < 32; i += 8)
    out[(size_t)(c0 + i) * ldout + r0 + tx] = (__bf16)t[tx][i];
}

// ---------------- RMSNorm ---------------------------------------------------
__global__ __launch_bounds__(256) void rmsnorm_k(const float* __restrict__ hs,
                                                 __bf16* __restrict__ x) {
  int row = blockIdx.x, tid = threadIdx.x;
  const float4 v = ((const float4*)(hs + (size_t)row * 1024))[tid];
  float ss = v.x * v.x + v.y * v.y + v.z * v.z + v.w * v.w;
  #pragma unroll
  for (int o = 32; o > 0; o >>= 1) ss += __shfl_xor(ss, o);
  __shared__ float ps[4];
  if ((tid & 63) == 0) ps[tid >> 6] = ss;
  __syncthreads();
  float tot = ps[0] + ps[1] + ps[2] + ps[3];
  float r = rsqrtf(tot * (1.0f / 1024.0f) + 1.1920929e-7f);
  __bf16* xr = x + (size_t)row * 1024 + tid * 4;
  xr[0] = (__bf16)(v.x * r); xr[1] = (__bf16)(v.y * r);
  xr[2] = (__bf16)(v.z * r); xr[3] = (__bf16)(v.w * r);
}

// ---------------- GEMM 128x128 ring-3 + fused l2norm/RoPE epilogue ----------
// Main loop identical to the verified ring-3 gemm_bt_k (order-pinned, counted
// vmcnt). Epilogue: each wave's 64-col quadrant is exactly one head, so
// row-l2norm = 4 squares + 16-lane shfl reduce; RoPE pair (d,d+32) is
// acc[mt][nt] <-> acc[mt][nt+2] in the SAME lane. Replaces the proj round
// trip (40MB write + 32MB read) + the qkprep launch. Values bit-identical
// (same f32 acc, same round-6 math).
__global__ __launch_bounds__(256, 3) void gemm_qkv_k(
    const __bf16* __restrict__ A, const __bf16* __restrict__ Bt,
    __bf16* __restrict__ qbf, __bf16* __restrict__ kbf,
    float* __restrict__ qb32, float* __restrict__ kb32,
    float* __restrict__ vproj) {
  const int K = 1024;
  __shared__ __bf16 sA[3][128 * 32];
  __shared__ __bf16 sB[3][128 * 32];
  const int tid = threadIdx.x;
  const int lane = tid & 63;
  const int quad = lane >> 4, l16 = lane & 15;
  const int wave = tid >> 6;
  const int waveM = wave >> 1, waveN = wave & 1;
  const int m0 = blockIdx.y * 128, n0 = blockIdx.x * 128;
  const int nk = K >> 5;
  const int rowS = tid >> 2;
  const int kg = ((tid & 3) ^ ((rowS >> 1) & 3)) * 8;
  const __bf16* gA0 = A + (size_t)(m0 + rowS) * K + kg;
  const __bf16* gA1 = gA0 + (size_t)64 * K;
  const __bf16* gB0 = Bt + (size_t)(n0 + rowS) * K + kg;
  const __bf16* gB1 = gB0 + (size_t)64 * K;
  const int lo0 = tid * 8, lo1 = 2048 + tid * 8;

  auto stage = [&](int t) {
    int s = t % 3;
    __bf16* dA = sA[s];
    __bf16* dB = sB[s];
    GLD16(gA0 + t * 32, dA + lo0);
    GLD16(gA1 + t * 32, dA + lo1);
    GLD16(gB0 + t * 32, dB + lo0);
    GLD16(gB1 + t * 32, dB + lo1);
  };
  stage(0); stage(1);

  f32x4 acc[4][4] = {};
  #pragma unroll 1
  for (int i = 0; i < nk; ++i) {
    if (i < nk - 1)
      asm volatile("s_waitcnt vmcnt(4)" ::: "memory");
    else
      asm volatile("s_waitcnt vmcnt(0)" ::: "memory");
    __builtin_amdgcn_s_barrier();
    SCHED_FENCE();
    int cs = i % 3;
    const __bf16* cA = sA[cs];
    const __bf16* cB = sB[cs];
    if (i + 2 < nk) stage(i + 2);
    SCHED_FENCE();
    bf16x8 af[4], bfv[4];
    #pragma unroll
    for (int mt = 0; mt < 4; ++mt) {
      int r = waveM * 64 + mt * 16 + l16;
      af[mt] = *(const bf16x8*)(cA + r * 32 + ((quad ^ ((r >> 1) & 3)) * 8));
    }
    #pragma unroll
    for (int nt = 0; nt < 4; ++nt) {
      int r = waveN * 64 + nt * 16 + l16;
      bfv[nt] = *(const bf16x8*)(cB + r * 32 + ((quad ^ ((r >> 1) & 3)) * 8));
    }
    __builtin_amdgcn_s_setprio(1);
    #pragma unroll
    for (int mt = 0; mt < 4; ++mt)
      #pragma unroll
      for (int nt = 0; nt < 4; ++nt)
        acc[mt][nt] = __builtin_amdgcn_mfma_f32_16x16x32_bf16(af[mt], bfv[nt], acc[mt][nt], 0, 0, 0);
    __builtin_amdgcn_s_setprio(0);
    SCHED_FENCE();
  }

  const int wid = n0 >> 10;                  // 0:q 1:k 2:v 3:qb 4:kb
  const int cw0 = (n0 & 1023) + waveN * 64;  // head-aligned col within weight
  if (wid == 2) {
    #pragma unroll
    for (int mt = 0; mt < 4; ++mt) {
      int row = m0 + waveM * 64 + mt * 16 + quad * 4;
      #pragma unroll
      for (int nt = 0; nt < 4; ++nt) {
        int col = cw0 + nt * 16 + l16;
        #pragma unroll
        for (int r = 0; r < 4; ++r)
          vproj[(size_t)(row + r) * 1024 + col] = acc[mt][nt][r];
      }
    }
  } else {
    const float inv0 = exp2f(-0.31143076f * (float)l16);
    const float inv1 = exp2f(-0.31143076f * (float)(16 + l16));
    #pragma unroll
    for (int mt = 0; mt < 4; ++mt) {
      #pragma unroll
      for (int r = 0; r < 4; ++r) {
        int srow = m0 + waveM * 64 + mt * 16 + quad * 4 + r;
        float a0 = acc[mt][0][r], a1 = acc[mt][1][r];
        float a2 = acc[mt][2][r], a3 = acc[mt][3][r];
        float ss = a0 * a0 + a1 * a1 + a2 * a2 + a3 * a3;
        ss += __shfl_xor(ss, 1); ss += __shfl_xor(ss, 2);
        ss += __shfl_xor(ss, 4); ss += __shfl_xor(ss, 8);
        float yn = 1.0f / fmaxf(sqrtf(ss), 1e-12f);
        float ang0 = (float)srow * inv0;
        float cb0 = (float)(__bf16)__cosf(ang0);
        float sb0 = (float)(__bf16)__sinf(ang0);
        float ang1 = (float)srow * inv1;
        float cb1 = (float)(__bf16)__cosf(ang1);
        float sb1 = (float)(__bf16)__sinf(ang1);
        float y0 = a0 * yn, y1 = a1 * yn, y2 = a2 * yn, y3 = a3 * yn;
        float o0 =  y0 * cb0 + y2 * sb0;   // d = l16
        float o1 =  y1 * cb1 + y3 * sb1;   // d = 16+l16
        float o2 = -y0 * sb0 + y2 * cb0;   // d = 32+l16
        float o3 = -y1 * sb1 + y3 * cb1;   // d = 48+l16
        size_t base = (size_t)srow * 1024 + cw0 + l16;
        if (wid == 0) {
          qbf[base]      = (__bf16)o0; qbf[base + 16] = (__bf16)o1;
          qbf[base + 32] = (__bf16)o2; qbf[base + 48] = (__bf16)o3;
        } else if (wid == 1) {
          kbf[base]      = (__bf16)o0; kbf[base + 16] = (__bf16)o1;
          kbf[base + 32] = (__bf16)o2; kbf[base + 48] = (__bf16)o3;
        } else if (wid == 3) {
          qb32[base]      = o0; qb32[base + 16] = o1;
          qb32[base + 32] = o2; qb32[base + 48] = o3;
        } else {
          kb32[base]      = o0; kb32[base + 16] = o1;
          kb32[base + 32] = o2; kb32[base + 48] = o3;
        }
      }
    }
  }
}

// ---------------- GEMM 128x128 ring-3, split-K partial buffers --------------
__global__ __launch_bounds__(256, 3) void gemm_partk_k(
    const __bf16* __restrict__ A, const __bf16* __restrict__ Bt,
    float* __restrict__ P, int N, int K) {
  __shared__ __bf16 sA[3][128 * 32];
  __shared__ __bf16 sB[3][128 * 32];
  const int tid = threadIdx.x;
  const int lane = tid & 63;
  const int quad = lane >> 4, l16 = lane & 15;
  const int wave = tid >> 6;
  const int waveM = wave >> 1, waveN = wave & 1;
  const int m0 = blockIdx.y * 128, n0 = blockIdx.x * 128;
  const int kz = blockIdx.z, nz = gridDim.z;
  const int kper = K / nz, kbeg = kz * kper;
  const int nk = kper >> 5;
  const size_t MN = (size_t)gridDim.y * 128 * N;
  float* C = P + (size_t)kz * MN;
  const int rowS = tid >> 2;
  const int kg = ((tid & 3) ^ ((rowS >> 1) & 3)) * 8;
  const __bf16* gA0 = A + (size_t)(m0 + rowS) * K + kbeg + kg;
  const __bf16* gA1 = gA0 + (size_t)64 * K;
  const __bf16* gB0 = Bt + (size_t)(n0 + rowS) * K + kbeg + kg;
  const __bf16* gB1 = gB0 + (size_t)64 * K;
  const int lo0 = tid * 8, lo1 = 2048 + tid * 8;

  auto stage = [&](int t) {
    int s = t % 3;
    __bf16* dA = sA[s];
    __bf16* dB = sB[s];
    GLD16(gA0 + t * 32, dA + lo0);
    GLD16(gA1 + t * 32, dA + lo1);
    GLD16(gB0 + t * 32, dB + lo0);
    GLD16(gB1 + t * 32, dB + lo1);
  };
  stage(0); stage(1);

  f32x4 acc[4][4] = {};
  #pragma unroll 1
  for (int i = 0; i < nk; ++i) {
    if (i < nk - 1)
      asm volatile("s_waitcnt vmcnt(4)" ::: "memory");
    else
      asm volatile("s_waitcnt vmcnt(0)" ::: "memory");
    __builtin_amdgcn_s_barrier();
    SCHED_FENCE();
    int cs = i % 3;
    const __bf16* cA = sA[cs];
    const __bf16* cB = sB[cs];
    if (i + 2 < nk) stage(i + 2);
    SCHED_FENCE();
    bf16x8 af[4], bfv[4];
    #pragma unroll
    for (int mt = 0; mt < 4; ++mt) {
      int r = waveM * 64 + mt * 16 + l16;
      af[mt] = *(const bf16x8*)(cA + r * 32 + ((quad ^ ((r >> 1) & 3)) * 8));
    }
    #pragma unroll
    for (int nt = 0; nt < 4; ++nt) {
      int r = waveN * 64 + nt * 16 + l16;
      bfv[nt] = *(const bf16x8*)(cB + r * 32 + ((quad ^ ((r >> 1) & 3)) * 8));
    }
    __builtin_amdgcn_s_setprio(1);
    #pragma unroll
    for (int mt = 0; mt < 4; ++mt)
      #pragma unroll
      for (int nt = 0; nt < 4; ++nt)
        acc[mt][nt] = __builtin_amdgcn_mfma_f32_16x16x32_bf16(af[mt], bfv[nt], acc[mt][nt], 0, 0, 0);
    __builtin_amdgcn_s_setprio(0);
    SCHED_FENCE();
  }
  #pragma unroll
  for (int mt = 0; mt < 4; ++mt) {
    int row = m0 + waveM * 64 + mt * 16 + quad * 4;
    #pragma unroll
    for (int nt = 0; nt < 4; ++nt) {
      int col = n0 + waveN * 64 + nt * 16 + l16;
      #pragma unroll
      for (int r = 0; r < 4; ++r)
        C[(size_t)(row + r) * N + col] = acc[mt][nt][r];
    }
  }
}

// ---------------- fused FFN1 + bias + SwiGLU, 256x256 ring-4 pipeline -------
// Order-pinned per K-tile (round-3 lesson); FROZEN — verified 46.4 us.
__global__ __launch_bounds__(512, 2) void ffn1silu_k(
    const __bf16* __restrict__ A, const __bf16* __restrict__ W1t,
    const float* __restrict__ b1, __bf16* __restrict__ ffout) {
  __shared__ __bf16 sA[4][256 * 32];
  __shared__ __bf16 sB[4][256 * 32];
  const int tid = threadIdx.x, lane = tid & 63, w = tid >> 6;
  const int quad = lane >> 4, l16 = lane & 15;
  const int wm = w >> 2, wn = w & 3;          // 2 M-waves x 4 N-waves
  const int m0 = blockIdx.y * 256;            // M = 2048 -> 8
  const int n0p = blockIdx.x * 256;           // packed N = 8192 -> 32
  const int K = 1024, NKT = 32;
  const int rowS = tid >> 2;                  // 0..127
  const int kg = ((tid & 3) ^ ((rowS >> 1) & 3)) * 8;
  const __bf16* gA0 = A + (size_t)(m0 + rowS) * K + kg;
  const __bf16* gA1 = gA0 + (size_t)128 * K;
  const __bf16* gB0 = W1t + (size_t)(n0p + rowS) * K + kg;
  const __bf16* gB1 = gB0 + (size_t)128 * K;
  const int lo0 = tid * 8, lo1 = 4096 + tid * 8;

  f32x4 acc[8][4] = {};

  auto stageA = [&](int t) {
    __bf16* d = sA[t & 3];
    GLD16(gA0 + t * 32, d + lo0);
    GLD16(gA1 + t * 32, d + lo1);
  };
  auto stageB = [&](int t) {
    __bf16* d = sB[t & 3];
    GLD16(gB0 + t * 32, d + lo0);
    GLD16(gB1 + t * 32, d + lo1);
  };

  auto compute_half = [&](const __bf16* cA, const bf16x8* bfr, int half) {
    bf16x8 af[4];
    #pragma unroll
    for (int mt = 0; mt < 4; ++mt) {
      int r = wm * 128 + half * 64 + mt * 16 + l16;
      af[mt] = *(const bf16x8*)(cA + r * 32 + ((quad ^ ((r >> 1) & 3)) * 8));
    }
    __builtin_amdgcn_s_setprio(1);
    #pragma unroll
    for (int mt = 0; mt < 4; ++mt)
      #pragma unroll
      for (int nt = 0; nt < 4; ++nt)
        acc[half * 4 + mt][nt] = __builtin_amdgcn_mfma_f32_16x16x32_bf16(
            af[mt], bfr[nt], acc[half * 4 + mt][nt], 0, 0, 0);
    __builtin_amdgcn_s_setprio(0);
  };

  // prologue: prime tiles 0,1,2 (12 loads in flight)
  stageA(0); stageB(0);
  stageA(1); stageB(1);
  stageA(2); stageB(2);

  #pragma unroll 1
  for (int t = 0; t < NKT; ++t) {
    if (t < NKT - 2)
      asm volatile("s_waitcnt vmcnt(8)" ::: "memory");
    else if (t == NKT - 2)
      asm volatile("s_waitcnt vmcnt(4)" ::: "memory");
    else
      asm volatile("s_waitcnt vmcnt(0)" ::: "memory");
    __builtin_amdgcn_s_barrier();
    SCHED_FENCE();
    const __bf16* cA = sA[t & 3];
    const __bf16* cB = sB[t & 3];
    if (t + 3 < NKT) stageA(t + 3);
    SCHED_FENCE();
    bf16x8 bfr[4];
    #pragma unroll
    for (int nt = 0; nt < 4; ++nt) {
      int r = wn * 64 + nt * 16 + l16;
      bfr[nt] = *(const bf16x8*)(cB + r * 32 + ((quad ^ ((r >> 1) & 3)) * 8));
    }
    compute_half(cA, bfr, 0);
    SCHED_FENCE();
    if (t + 3 < NKT) stageB(t + 3);
    SCHED_FENCE();
    compute_half(cA, bfr, 1);
    SCHED_FENCE();
  }

  // epilogue: bias + SwiGLU, unpack interleaved xp/gate
  const int colbase = (blockIdx.x * 4 + wn) * 32;   // logical col base (0..4095)
  #pragma unroll
  for (int j = 0; j < 8; ++j) {
    int row = m0 + wm * 128 + (j >> 2) * 64 + (j & 3) * 16 + quad * 4;
    #pragma unroll
    for (int p = 0; p < 2; ++p) {
      int col = colbase + p * 16 + l16;
      float bxv = b1[col], bgv = b1[col + 4096];
      #pragma unroll
      for (int r = 0; r < 4; ++r) {
        float xp = acc[j][p][r] + bxv;
        float g  = acc[j][p + 2][r] + bgv;
        float val = xp * g / (1.f + __expf(-g));
        ffout[(size_t)(row + r) * 5120 + 1024 + col] = (__bf16)val;
      }
    }
  }
}

// ---------------- combine: out = Σ4 partials + (bo+b2) + lam*h --------------
__global__ __launch_bounds__(256) void combine_k(
    const float* __restrict__ P, const float* __restrict__ b2,
    const float* __restrict__ bo, const float* __restrict__ hs,
    const float* __restrict__ plam, float* __restrict__ out) {
  const size_t MN = (size_t)2048 * 1024;
  size_t i = ((size_t)blockIdx.x * 256 + threadIdx.x) * 4;
  int col = (int)(i & 1023);
  float4 a0 = *(const float4*)(P + i);
  float4 a1 = *(const float4*)(P + MN + i);
  float4 a2 = *(const float4*)(P + 2 * MN + i);
  float4 a3 = *(const float4*)(P + 3 * MN + i);
  float4 h  = *(const float4*)(hs + i);
  float4 v2 = *(const float4*)(b2 + col);
  float4 vo = *(const float4*)(bo + col);
  float lam = plam[0];
  float4 o;
  o.x = (a0.x + a1.x) + (a2.x + a3.x) + v2.x + vo.x + lam * h.x;
  o.y = (a0.y + a1.y) + (a2.y + a3.y) + v2.y + vo.y + lam * h.y;
  o.z = (a0.z + a1.z) + (a2.z + a3.z) + v2.z + vo.z + lam * h.z;
  o.w = (a0.w + a1.w) + (a2.w + a3.w) + v2.w + vo.w + lam * h.w;
  *(float4*)(out + i) = o;
}

// ---------------- sb row-sum via two-level cumsum ---------------------------
__global__ __launch_bounds__(256) void kbsum_k(const float* __restrict__ kb,
                                               float* __restrict__ tsum,
                                               float* __restrict__ tsum8) {
  int t = blockIdx.x, h = blockIdx.y;
  int d = threadIdx.x & 63, w = threadIdx.x >> 6;
  size_t base = (size_t)h * 64 + d;
  float s = 0.f;
  #pragma unroll
  for (int r = 0; r < 8; ++r)
    s += kb[(size_t)(t * 32 + w * 8 + r) * 1024 + base];
  tsum8[(size_t)((t * 4 + w) * 16 + h) * 64 + d] = s;
  __shared__ float ps[4][64];
  ps[w][d] = s;
  __syncthreads();
  if (w == 0)
    tsum[(size_t)(t * 16 + h) * 64 + d] = (ps[0][d] + ps[1][d]) + (ps[2][d] + ps[3][d]);
}

__global__ __launch_bounds__(256) void sbrow2_k(const float* __restrict__ qb,
                                                const float* __restrict__ kb,
                                                const float* __restrict__ tsum,
                                                const float* __restrict__ tsum8,
                                                float* __restrict__ sb) {
  int t = blockIdx.x, h = blockIdx.y;
  int d = threadIdx.x & 63, g = threadIdx.x >> 6;
  size_t base = (size_t)h * 64 + d;
  float run = 0.f;
  for (int tp = 0; tp < t; ++tp) run += tsum[(size_t)(tp * 16 + h) * 64 + d];
  for (int w = 0; w < g; ++w) run += tsum8[(size_t)((t * 4 + w) * 16 + h) * 64 + d];
  int r0 = t * 32 + g * 8;
  for (int s0 = 0; s0 < 8; s0 += 4) {
    float p[4];
    #pragma unroll
    for (int u = 0; u < 4; ++u) {
      size_t off = (size_t)(r0 + s0 + u) * 1024 + base;
      run += kb[off];
      p[u] = qb[off] * run;
    }
    #pragma unroll
    for (int o = 32; o > 0; o >>= 1) {
      #pragma unroll
      for (int u = 0; u < 4; ++u) p[u] += __shfl_xor(p[u], o);
    }
    if (d == 0) {
      #pragma unroll
      for (int u = 0; u < 4; ++u) sb[(r0 + s0 + u) * 16 + h] = 0.125f * p[u];
    }
  }
}

// ---------------- flash attention: split-KV x4, double-buffered K/V ---------
__global__ __launch_bounds__(256) void attn_k(const __bf16* __restrict__ qg,
    const __bf16* __restrict__ kg, const __bf16* __restrict__ vtg,
    float* __restrict__ o_part, float* __restrict__ m_part,
    float* __restrict__ l_part) {
  __shared__ __bf16 sK[2][64 * 64];
  __shared__ __bf16 sVt[2][64 * 64];
  __shared__ __bf16 sP[4][16 * 64];
  const int pair = blockIdx.x, j4 = blockIdx.y, hh = blockIdx.z;
  const int tid = threadIdx.x, lane = tid & 63, w = tid >> 6;
  const int quad = lane >> 4, l16 = lane & 15;
  const int srow = tid >> 3;
  const int sg = (tid & 7) ^ (srow & 7);
  __bf16* sPw = sP[w];

  auto stage = [&](int kt) {
    int b = kt & 1;
    const __bf16* gK = kg + (size_t)(kt * 64 + srow) * 1024 + hh * 64 + sg * 8;
    const __bf16* gV = vtg + (size_t)(hh * 64 + srow) * 2048 + kt * 64 + sg * 8;
    GLD16(gK, sK[b] + tid * 8);
    GLD16(gK + (size_t)32 * 1024, sK[b] + tid * 8 + 2048);
    GLD16(gV, sVt[b] + tid * 8);
    GLD16(gV + (size_t)32 * 2048, sVt[b] + tid * 8 + 2048);
  };

  for (int phase = 0; phase < 2; ++phase) {
    const int qt = phase ? 31 - pair : pair;
    const int q0 = qt * 64;
    const int n = qt + 1;
    const int kb = (j4 * n) >> 2, ke = ((j4 + 1) * n) >> 2;
    bf16x8 qf[2];
    #pragma unroll
    for (int kk = 0; kk < 2; ++kk)
      qf[kk] = *(const bf16x8*)(qg + (size_t)(q0 + w * 16 + l16) * 1024 + hh * 64 + kk * 32 + quad * 8);
    f32x4 accO[4] = {};
    float m_[4], l_[4];
    #pragma unroll
    for (int r = 0; r < 4; ++r) { m_[r] = -INFINITY; l_[r] = 0.f; }

    __syncthreads();                 // seal previous phase's buffer reads
    if (kb < ke) stage(kb);

    for (int kt = kb; kt < ke; ++kt) {
      __syncthreads();               // implicit vmcnt(0): buf[kt&1] ready;
                                     // seals buf[(kt+1)&1] (last read kt-1)
      SCHED_FENCE();
      if (kt + 1 < ke) stage(kt + 1);
      SCHED_FENCE();
      const __bf16* cK = sK[kt & 1];
      const __bf16* cV = sVt[kt & 1];

      f32x4 s4[4];
      #pragma unroll
      for (int nt = 0; nt < 4; ++nt) {
        int r = nt * 16 + l16;
        bf16x8 b0 = *(const bf16x8*)(cK + r * 64 + ((quad ^ (r & 7)) * 8));
        bf16x8 b1 = *(const bf16x8*)(cK + r * 64 + (((4 + quad) ^ (r & 7)) * 8));
        f32x4 sa = {0.f, 0.f, 0.f, 0.f};
        sa = __builtin_amdgcn_mfma_f32_16x16x32_bf16(qf[0], b0, sa, 0, 0, 0);
        sa = __builtin_amdgcn_mfma_f32_16x16x32_bf16(qf[1], b1, sa, 0, 0, 0);
        s4[nt] = sa;
      }
      if (kt == qt) {
        #pragma unroll
        for (int nt = 0; nt < 4; ++nt)
          #pragma unroll
          for (int r = 0; r < 4; ++r)
            if (nt * 16 + l16 > w * 16 + quad * 4 + r) s4[nt][r] = -INFINITY;
      }
      float mx[4], al[4], rs[4];
      #pragma unroll
      for (int r = 0; r < 4; ++r)
        mx[r] = fmaxf(fmaxf(s4[0][r], s4[1][r]), fmaxf(s4[2][r], s4[3][r]));
      #pragma unroll
      for (int o = 1; o < 16; o <<= 1)
        #pragma unroll
        for (int r = 0; r < 4; ++r) mx[r] = fmaxf(mx[r], __shfl_xor(mx[r], o));
      #pragma unroll
      for (int r = 0; r < 4; ++r) {
        float mn = fmaxf(m_[r], mx[r]);
        al[r] = __expf(m_[r] - mn);
        m_[r] = mn;
      }
      float p[4][4];
      #pragma unroll
      for (int nt = 0; nt < 4; ++nt)
        #pragma unroll
        for (int r = 0; r < 4; ++r)
          p[nt][r] = __expf(s4[nt][r] - m_[r]);
      #pragma unroll
      for (int r = 0; r < 4; ++r)
        rs[r] = (p[0][r] + p[1][r]) + (p[2][r] + p[3][r]);
      #pragma unroll
      for (int o = 1; o < 16; o <<= 1)
        #pragma unroll
        for (int r = 0; r < 4; ++r) rs[r] += __shfl_xor(rs[r], o);
      #pragma unroll
      for (int r = 0; r < 4; ++r) l_[r] = l_[r] * al[r] + rs[r];
      #pragma unroll
      for (int nt = 0; nt < 4; ++nt)
        #pragma unroll
        for (int r = 0; r < 4; ++r) accO[nt][r] *= al[r];
      #pragma unroll
      for (int nt = 0; nt < 4; ++nt)
        #pragma unroll
        for (int r = 0; r < 4; ++r) {
          int row = quad * 4 + r, col = nt * 16 + l16;
          sPw[row * 64 + (col ^ ((row & 7) << 3))] = (__bf16)p[nt][r];
        }
      #pragma unroll
      for (int kk = 0; kk < 2; ++kk) {
        bf16x8 a = *(const bf16x8*)(sPw + l16 * 64 + (((kk * 4 + quad) ^ (l16 & 7)) * 8));
        #pragma unroll
        for (int nt = 0; nt < 4; ++nt) {
          int vr = nt * 16 + l16;
          bf16x8 bv = *(const bf16x8*)(cV + vr * 64 + (((kk * 4 + quad) ^ (vr & 7)) * 8));
          accO[nt] = __builtin_amdgcn_mfma_f32_16x16x32_bf16(a, bv, accO[nt], 0, 0, 0);
        }
      }
      // no trailing barrier: sP is wave-private; K/V buffers are ring-2 sealed
    }
    #pragma unroll
    for (int r = 0; r < 4; ++r) {
      int grow = q0 + w * 16 + quad * 4 + r;
      if (l16 == 0) {
        m_part[((size_t)j4 * 2048 + grow) * 16 + hh] = m_[r];
        l_part[((size_t)j4 * 2048 + grow) * 16 + hh] = l_[r];
      }
      #pragma unroll
      for (int nt = 0; nt < 4; ++nt)
        o_part[((size_t)j4 * 2048 + grow) * 1024 + hh * 64 + nt * 16 + l16] = accO[nt][r];
    }
  }
}

// ---------------- merge 4 KV-partials -> y into concat (stride 5120) --------
__global__ __launch_bounds__(256) void attnmerge_k(const float* __restrict__ o_part,
    const float* __restrict__ m_part, const float* __restrict__ l_part,
    const float* __restrict__ sbr, const float* __restrict__ pl2s,
    __bf16* __restrict__ yo) {
  int idx = blockIdx.x * 256 + threadIdx.x;
  int s = idx >> 8, rem = idx & 255;
  int h = rem >> 4, dg = (rem & 15) * 4;
  float m[4], l[4];
  #pragma unroll
  for (int j = 0; j < 4; ++j) {
    m[j] = m_part[((size_t)j * 2048 + s) * 16 + h];
    l[j] = l_part[((size_t)j * 2048 + s) * 16 + h];
  }
  float M = fmaxf(fmaxf(m[0], m[1]), fmaxf(m[2], m[3]));
  float den = 0.f;
  float4 acc = {0.f, 0.f, 0.f, 0.f};
  #pragma unroll
  for (int j = 0; j < 4; ++j) {
    float e = __expf(m[j] - M);
    den += l[j] * e;
    float4 o = *(const float4*)(o_part + ((size_t)j * 2048 + s) * 1024 + h * 64 + dg);
    acc.x += e * o.x; acc.y += e * o.y; acc.z += e * o.z; acc.w += e * o.w;
  }
  float sc = pl2s[0] / den;
  float add = sbr[s * 16 + h];
  __bf16* yp = yo + (size_t)s * 5120 + h * 64 + dg;
  yp[0] = (__bf16)(sc * acc.x + add);
  yp[1] = (__bf16)(sc * acc.y + add);
  yp[2] = (__bf16)(sc * acc.z + add);
  yp[3] = (__bf16)(sc * acc.w + add);
}

extern "C" void kernel_launch(void* const* d_in, const int* in_sizes, int n_in,
                              void* d_out, int out_size, void* d_ws, size_t ws_size,
                              hipStream_t stream) {
  (void)in_sizes; (void)n_in; (void)out_size; (void)ws_size;
  const float* hs   = (const float*)d_in[0];
  const float* Wq   = (const float*)d_in[1];
  const float* Wk   = (const float*)d_in[2];
  const float* Wv   = (const float*)d_in[3];
  const float* Wqb  = (const float*)d_in[4];
  const float* Wkb  = (const float*)d_in[5];
  const float* Wo   = (const float*)d_in[6];
  const float* bo   = (const float*)d_in[7];
  const float* W1   = (const float*)d_in[8];
  const float* b1   = (const float*)d_in[9];
  const float* W2   = (const float*)d_in[10];
  const float* b2   = (const float*)d_in[11];
  const float* plam = (const float*)d_in[12];
  const float* pl2s = (const float*)d_in[13];
  float* out = (float*)d_out;
  char* ws = (char*)d_ws;

  size_t off = 0;
  auto alloc = [&](size_t bytes) { char* p = ws + off; off += (bytes + 255) & ~(size_t)255; return p; };
  __bf16* Wt5    = (__bf16*)alloc((size_t)5 * 1024 * 1024 * 2);
  __bf16* WoW2t  = (__bf16*)alloc((size_t)1024 * 5120 * 2);   // [n][k], k: Wo 0..1023, W2 1024..5119
  __bf16* W1t    = (__bf16*)alloc((size_t)8192 * 1024 * 2);   // packed xp/gate 32-col interleave
  __bf16* xbf    = (__bf16*)alloc((size_t)2048 * 1024 * 2);
  __bf16* concat = (__bf16*)alloc((size_t)2048 * 5120 * 2);   // [y | ffin] bf16
  float*  proj  = (float*)alloc((size_t)2048 * 5120 * 4);     // vproj / o_part / gpart scratch
  float*  qbf32 = (float*)alloc((size_t)2048 * 1024 * 4);
  float*  kbf32 = (float*)alloc((size_t)2048 * 1024 * 4);
  __bf16* qbf   = (__bf16*)alloc((size_t)2048 * 1024 * 2);
  __bf16* kbf   = (__bf16*)alloc((size_t)2048 * 1024 * 2);
  float*  vproj  = proj;                                      // 8 MB (v only)
  float*  o_part = proj;                                      // 4 x 8 MB (after tconv)
  float*  m_part = qbf32;                                     // 512 KB (after sbrow2)
  float*  l_part = qbf32 + (size_t)4 * 2048 * 16;             // 512 KB
  float*  gpart  = proj;                                      // 4 x 8 MB (after attnmerge)
  __bf16* vtbf  = (__bf16*)alloc((size_t)1024 * 2048 * 2);
  float*  sbrow = (float*)alloc((size_t)2048 * 16 * 4);
  float*  tsum  = (float*)alloc((size_t)64 * 16 * 64 * 4);
  float*  tsum8 = (float*)alloc((size_t)256 * 16 * 64 * 4);

  // merged weight repack (was 3 launches)
  repack_k<<<18432, 256, 0, stream>>>(Wq, Wk, Wv, Wqb, Wkb, Wo, W2, W1,
                                      Wt5, WoW2t, W1t);

  rmsnorm_k<<<2048, 256, 0, stream>>>(hs, xbf);
  // QKV-family GEMM with fused l2norm+RoPE epilogue (replaces gemm_bt + qkprep)
  gemm_qkv_k<<<dim3(40, 16), 256, 0, stream>>>(xbf, Wt5, qbf, kbf,
                                               qbf32, kbf32, vproj);
  tconv_k<<<dim3(32, 64), 256, 0, stream>>>(vproj, vtbf, 1024, 2048);
  kbsum_k<<<dim3(64, 16), 256, 0, stream>>>(kbf32, tsum, tsum8);
  sbrow2_k<<<dim3(64, 16), 256, 0, stream>>>(qbf32, kbf32, tsum, tsum8, sbrow);
  attn_k<<<dim3(16, 4, 16), 256, 0, stream>>>(qbf, kbf, vtbf, o_part, m_part, l_part);
  attnmerge_k<<<2048, 256, 0, stream>>>(o_part, m_part, l_part, sbrow, pl2s, concat);
  // fused FFN1 + bias + SwiGLU -> concat cols 1024..5119 (256x256 ring-4)
  ffn1silu_k<<<dim3(32, 8), 512, 0, stream>>>(xbf, W1t, b1, concat);
  // merged (Wo + FFN2): [y|ffin] @ [Wo;W2], K=5120, split-K x4 -> partials
  gemm_partk_k<<<dim3(8, 16, 4), 256, 0, stream>>>(concat, WoW2t, gpart, 1024, 5120);
  // out = Σ partials + (bo+b2) + lam*h
  combine_k<<<2048, 256, 0, stream>>>(gpart, b2, bo, hs, plam, out);
}

// Round 8
// 333.364 us; speedup vs baseline: 1.1609x; 1.0318x over previous
//
#include <hip/hip_runtime.h>
#include <hip/hip_bf16.h>
#include <math.h>

typedef __bf16 bf16x8 __attribute__((ext_vector_type(8)));
typedef float  f32x4  __attribute__((ext_vector_type(4)));

#define GLD16(g, l) __builtin_amdgcn_global_load_lds(                      \
    (const __attribute__((address_space(1))) void*)(g),                    \
    (__attribute__((address_space(3))) void*)(l), 16, 0, 0)

#define SCHED_FENCE() __builtin_amdgcn_sched_barrier(0)

// BK=32 LDS tiles (64 B rows): global k-group g of row r stored at slot
// g ^ ((r>>1)&3) -> all ds_read_b128 fragment reads are 2-way (free).

// ---------------- merged weight repack (was 3 kernels) ----------------------
__global__ __launch_bounds__(256) void repack_k(
    const float* __restrict__ Wq, const float* __restrict__ Wk,
    const float* __restrict__ Wv, const float* __restrict__ Wqb,
    const float* __restrict__ Wkb, const float* __restrict__ Wo,
    const float* __restrict__ W2, const float* __restrict__ W1,
    __bf16* __restrict__ Wt5, __bf16* __restrict__ WoW2t,
    __bf16* __restrict__ W1t) {
  int t = blockIdx.x;
  const float* in; __bf16* outp;
  int ldin, ldout, r0, c0, cin0, oofs;
  if (t < 5120) {
    int w = t >> 10, rem = t & 1023;
    const float* src[5] = {Wq, Wk, Wv, Wqb, Wkb};
    in = src[w]; ldin = 1024;
    r0 = (rem >> 5) << 5; c0 = (rem & 31) << 5; cin0 = c0;
    outp = Wt5 + (size_t)w * 1048576; ldout = 1024; oofs = 0;
  } else if (t < 6144) {
    int rem = t - 5120;
    in = Wo; ldin = 1024;
    r0 = (rem >> 5) << 5; c0 = (rem & 31) << 5; cin0 = c0;
    outp = WoW2t; ldout = 5120; oofs = 0;
  } else if (t < 10240) {
    int rem = t - 6144;
    in = W2; ldin = 1024;
    r0 = (rem >> 5) << 5; c0 = (rem & 31) << 5; cin0 = c0;
    outp = WoW2t; ldout = 5120; oofs = 1024;
  } else {
    int rem = t - 10240;
    in = W1; ldin = 8192;
    c0 = (rem & 255) << 5; r0 = (rem >> 8) << 5;
    cin0 = ((c0 >> 5) & 1) * 4096 + (c0 >> 6) * 32;
    outp = W1t; ldout = 1024; oofs = 0;
  }
  __shared__ float sh[32][33];
  int tid = threadIdx.x, tx = tid & 31, ty = tid >> 5;
  #pragma unroll
  for (int i = ty; i < 32; i += 8)
    sh[i][tx] = in[(size_t)(r0 + i) * ldin + cin0 + tx];
  __syncthreads();
  #pragma unroll
  for (int i = ty; i < 32; i += 8)
    outp[(size_t)(c0 + i) * ldout + oofs + r0 + tx] = (__bf16)sh[tx][i];
}

// plain transpose (used for V^T from vproj)
__global__ __launch_bounds__(256) void tconv_k(const float* __restrict__ in,
                                               __bf16* __restrict__ out,
                                               int ldin, int ldout) {
  __shared__ float t[32][33];
  int r0 = blockIdx.y * 32, c0 = blockIdx.x * 32;
  int tid = threadIdx.x, tx = tid & 31, ty = tid >> 5;
  #pragma unroll
  for (int i = ty; i < 32; i += 8)
    t[i][tx] = in[(size_t)(r0 + i) * ldin + c0 + tx];
  __syncthreads();
  #pragma unroll
  for (int i = ty; i < 32; i += 8)
    out[(size_t)(c0 + i) * ldout + r0 + tx] = (__bf16)t[tx][i];
}

// ---------------- RMSNorm ---------------------------------------------------
__global__ __launch_bounds__(256) void rmsnorm_k(const float* __restrict__ hs,
                                                 __bf16* __restrict__ x) {
  int row = blockIdx.x, tid = threadIdx.x;
  const float4 v = ((const float4*)(hs + (size_t)row * 1024))[tid];
  float ss = v.x * v.x + v.y * v.y + v.z * v.z + v.w * v.w;
  #pragma unroll
  for (int o = 32; o > 0; o >>= 1) ss += __shfl_xor(ss, o);
  __shared__ float ps[4];
  if ((tid & 63) == 0) ps[tid >> 6] = ss;
  __syncthreads();
  float tot = ps[0] + ps[1] + ps[2] + ps[3];
  float r = rsqrtf(tot * (1.0f / 1024.0f) + 1.1920929e-7f);
  __bf16* xr = x + (size_t)row * 1024 + tid * 4;
  xr[0] = (__bf16)(v.x * r); xr[1] = (__bf16)(v.y * r);
  xr[2] = (__bf16)(v.z * r); xr[3] = (__bf16)(v.w * r);
}

// ---------------- GEMM 128x128 ring-3 + fused l2norm/RoPE epilogue ----------
__global__ __launch_bounds__(256, 3) void gemm_qkv_k(
    const __bf16* __restrict__ A, const __bf16* __restrict__ Bt,
    __bf16* __restrict__ qbf, __bf16* __restrict__ kbf,
    float* __restrict__ qb32, float* __restrict__ kb32,
    float* __restrict__ vproj) {
  const int K = 1024;
  __shared__ __bf16 sA[3][128 * 32];
  __shared__ __bf16 sB[3][128 * 32];
  const int tid = threadIdx.x;
  const int lane = tid & 63;
  const int quad = lane >> 4, l16 = lane & 15;
  const int wave = tid >> 6;
  const int waveM = wave >> 1, waveN = wave & 1;
  const int m0 = blockIdx.y * 128, n0 = blockIdx.x * 128;
  const int nk = K >> 5;
  const int rowS = tid >> 2;
  const int kg = ((tid & 3) ^ ((rowS >> 1) & 3)) * 8;
  const __bf16* gA0 = A + (size_t)(m0 + rowS) * K + kg;
  const __bf16* gA1 = gA0 + (size_t)64 * K;
  const __bf16* gB0 = Bt + (size_t)(n0 + rowS) * K + kg;
  const __bf16* gB1 = gB0 + (size_t)64 * K;
  const int lo0 = tid * 8, lo1 = 2048 + tid * 8;

  auto stage = [&](int t) {
    int s = t % 3;
    __bf16* dA = sA[s];
    __bf16* dB = sB[s];
    GLD16(gA0 + t * 32, dA + lo0);
    GLD16(gA1 + t * 32, dA + lo1);
    GLD16(gB0 + t * 32, dB + lo0);
    GLD16(gB1 + t * 32, dB + lo1);
  };
  stage(0); stage(1);

  f32x4 acc[4][4] = {};
  #pragma unroll 1
  for (int i = 0; i < nk; ++i) {
    if (i < nk - 1)
      asm volatile("s_waitcnt vmcnt(4)" ::: "memory");
    else
      asm volatile("s_waitcnt vmcnt(0)" ::: "memory");
    __builtin_amdgcn_s_barrier();
    SCHED_FENCE();
    int cs = i % 3;
    const __bf16* cA = sA[cs];
    const __bf16* cB = sB[cs];
    if (i + 2 < nk) stage(i + 2);
    SCHED_FENCE();
    bf16x8 af[4], bfv[4];
    #pragma unroll
    for (int mt = 0; mt < 4; ++mt) {
      int r = waveM * 64 + mt * 16 + l16;
      af[mt] = *(const bf16x8*)(cA + r * 32 + ((quad ^ ((r >> 1) & 3)) * 8));
    }
    #pragma unroll
    for (int nt = 0; nt < 4; ++nt) {
      int r = waveN * 64 + nt * 16 + l16;
      bfv[nt] = *(const bf16x8*)(cB + r * 32 + ((quad ^ ((r >> 1) & 3)) * 8));
    }
    __builtin_amdgcn_s_setprio(1);
    #pragma unroll
    for (int mt = 0; mt < 4; ++mt)
      #pragma unroll
      for (int nt = 0; nt < 4; ++nt)
        acc[mt][nt] = __builtin_amdgcn_mfma_f32_16x16x32_bf16(af[mt], bfv[nt], acc[mt][nt], 0, 0, 0);
    __builtin_amdgcn_s_setprio(0);
    SCHED_FENCE();
  }

  const int wid = n0 >> 10;                  // 0:q 1:k 2:v 3:qb 4:kb
  const int cw0 = (n0 & 1023) + waveN * 64;  // head-aligned col within weight
  if (wid == 2) {
    #pragma unroll
    for (int mt = 0; mt < 4; ++mt) {
      int row = m0 + waveM * 64 + mt * 16 + quad * 4;
      #pragma unroll
      for (int nt = 0; nt < 4; ++nt) {
        int col = cw0 + nt * 16 + l16;
        #pragma unroll
        for (int r = 0; r < 4; ++r)
          vproj[(size_t)(row + r) * 1024 + col] = acc[mt][nt][r];
      }
    }
  } else {
    const float inv0 = exp2f(-0.31143076f * (float)l16);
    const float inv1 = exp2f(-0.31143076f * (float)(16 + l16));
    #pragma unroll
    for (int mt = 0; mt < 4; ++mt) {
      #pragma unroll
      for (int r = 0; r < 4; ++r) {
        int srow = m0 + waveM * 64 + mt * 16 + quad * 4 + r;
        float a0 = acc[mt][0][r], a1 = acc[mt][1][r];
        float a2 = acc[mt][2][r], a3 = acc[mt][3][r];
        float ss = a0 * a0 + a1 * a1 + a2 * a2 + a3 * a3;
        ss += __shfl_xor(ss, 1); ss += __shfl_xor(ss, 2);
        ss += __shfl_xor(ss, 4); ss += __shfl_xor(ss, 8);
        float yn = 1.0f / fmaxf(sqrtf(ss), 1e-12f);
        float ang0 = (float)srow * inv0;
        float cb0 = (float)(__bf16)__cosf(ang0);
        float sb0 = (float)(__bf16)__sinf(ang0);
        float ang1 = (float)srow * inv1;
        float cb1 = (float)(__bf16)__cosf(ang1);
        float sb1 = (float)(__bf16)__sinf(ang1);
        float y0 = a0 * yn, y1 = a1 * yn, y2 = a2 * yn, y3 = a3 * yn;
        float o0 =  y0 * cb0 + y2 * sb0;   // d = l16
        float o1 =  y1 * cb1 + y3 * sb1;   // d = 16+l16
        float o2 = -y0 * sb0 + y2 * cb0;   // d = 32+l16
        float o3 = -y1 * sb1 + y3 * cb1;   // d = 48+l16
        size_t base = (size_t)srow * 1024 + cw0 + l16;
        if (wid == 0) {
          qbf[base]      = (__bf16)o0; qbf[base + 16] = (__bf16)o1;
          qbf[base + 32] = (__bf16)o2; qbf[base + 48] = (__bf16)o3;
        } else if (wid == 1) {
          kbf[base]      = (__bf16)o0; kbf[base + 16] = (__bf16)o1;
          kbf[base + 32] = (__bf16)o2; kbf[base + 48] = (__bf16)o3;
        } else if (wid == 3) {
          qb32[base]      = o0; qb32[base + 16] = o1;
          qb32[base + 32] = o2; qb32[base + 48] = o3;
        } else {
          kb32[base]      = o0; kb32[base + 16] = o1;
          kb32[base + 32] = o2; kb32[base + 48] = o3;
        }
      }
    }
  }
}

// ---------------- GEMM 128x128 ring-3, split-K partial buffers --------------
__global__ __launch_bounds__(256, 3) void gemm_partk_k(
    const __bf16* __restrict__ A, const __bf16* __restrict__ Bt,
    float* __restrict__ P, int N, int K) {
  __shared__ __bf16 sA[3][128 * 32];
  __shared__ __bf16 sB[3][128 * 32];
  const int tid = threadIdx.x;
  const int lane = tid & 63;
  const int quad = lane >> 4, l16 = lane & 15;
  const int wave = tid >> 6;
  const int waveM = wave >> 1, waveN = wave & 1;
  const int m0 = blockIdx.y * 128, n0 = blockIdx.x * 128;
  const int kz = blockIdx.z, nz = gridDim.z;
  const int kper = K / nz, kbeg = kz * kper;
  const int nk = kper >> 5;
  const size_t MN = (size_t)gridDim.y * 128 * N;
  float* C = P + (size_t)kz * MN;
  const int rowS = tid >> 2;
  const int kg = ((tid & 3) ^ ((rowS >> 1) & 3)) * 8;
  const __bf16* gA0 = A + (size_t)(m0 + rowS) * K + kbeg + kg;
  const __bf16* gA1 = gA0 + (size_t)64 * K;
  const __bf16* gB0 = Bt + (size_t)(n0 + rowS) * K + kbeg + kg;
  const __bf16* gB1 = gB0 + (size_t)64 * K;
  const int lo0 = tid * 8, lo1 = 2048 + tid * 8;

  auto stage = [&](int t) {
    int s = t % 3;
    __bf16* dA = sA[s];
    __bf16* dB = sB[s];
    GLD16(gA0 + t * 32, dA + lo0);
    GLD16(gA1 + t * 32, dA + lo1);
    GLD16(gB0 + t * 32, dB + lo0);
    GLD16(gB1 + t * 32, dB + lo1);
  };
  stage(0); stage(1);

  f32x4 acc[4][4] = {};
  #pragma unroll 1
  for (int i = 0; i < nk; ++i) {
    if (i < nk - 1)
      asm volatile("s_waitcnt vmcnt(4)" ::: "memory");
    else
      asm volatile("s_waitcnt vmcnt(0)" ::: "memory");
    __builtin_amdgcn_s_barrier();
    SCHED_FENCE();
    int cs = i % 3;
    const __bf16* cA = sA[cs];
    const __bf16* cB = sB[cs];
    if (i + 2 < nk) stage(i + 2);
    SCHED_FENCE();
    bf16x8 af[4], bfv[4];
    #pragma unroll
    for (int mt = 0; mt < 4; ++mt) {
      int r = waveM * 64 + mt * 16 + l16;
      af[mt] = *(const bf16x8*)(cA + r * 32 + ((quad ^ ((r >> 1) & 3)) * 8));
    }
    #pragma unroll
    for (int nt = 0; nt < 4; ++nt) {
      int r = waveN * 64 + nt * 16 + l16;
      bfv[nt] = *(const bf16x8*)(cB + r * 32 + ((quad ^ ((r >> 1) & 3)) * 8));
    }
    __builtin_amdgcn_s_setprio(1);
    #pragma unroll
    for (int mt = 0; mt < 4; ++mt)
      #pragma unroll
      for (int nt = 0; nt < 4; ++nt)
        acc[mt][nt] = __builtin_amdgcn_mfma_f32_16x16x32_bf16(af[mt], bfv[nt], acc[mt][nt], 0, 0, 0);
    __builtin_amdgcn_s_setprio(0);
    SCHED_FENCE();
  }
  #pragma unroll
  for (int mt = 0; mt < 4; ++mt) {
    int row = m0 + waveM * 64 + mt * 16 + quad * 4;
    #pragma unroll
    for (int nt = 0; nt < 4; ++nt) {
      int col = n0 + waveN * 64 + nt * 16 + l16;
      #pragma unroll
      for (int r = 0; r < 4; ++r)
        C[(size_t)(row + r) * N + col] = acc[mt][nt][r];
    }
  }
}

// ---------------- fused FFN1 + bias + SwiGLU, 256x256 ring-4 pipeline -------
// Order-pinned per K-tile (round-3 lesson); FROZEN — verified 46.4 us.
__global__ __launch_bounds__(512, 2) void ffn1silu_k(
    const __bf16* __restrict__ A, const __bf16* __restrict__ W1t,
    const float* __restrict__ b1, __bf16* __restrict__ ffout) {
  __shared__ __bf16 sA[4][256 * 32];
  __shared__ __bf16 sB[4][256 * 32];
  const int tid = threadIdx.x, lane = tid & 63, w = tid >> 6;
  const int quad = lane >> 4, l16 = lane & 15;
  const int wm = w >> 2, wn = w & 3;          // 2 M-waves x 4 N-waves
  const int m0 = blockIdx.y * 256;            // M = 2048 -> 8
  const int n0p = blockIdx.x * 256;           // packed N = 8192 -> 32
  const int K = 1024, NKT = 32;
  const int rowS = tid >> 2;                  // 0..127
  const int kg = ((tid & 3) ^ ((rowS >> 1) & 3)) * 8;
  const __bf16* gA0 = A + (size_t)(m0 + rowS) * K + kg;
  const __bf16* gA1 = gA0 + (size_t)128 * K;
  const __bf16* gB0 = W1t + (size_t)(n0p + rowS) * K + kg;
  const __bf16* gB1 = gB0 + (size_t)128 * K;
  const int lo0 = tid * 8, lo1 = 4096 + tid * 8;

  f32x4 acc[8][4] = {};

  auto stageA = [&](int t) {
    __bf16* d = sA[t & 3];
    GLD16(gA0 + t * 32, d + lo0);
    GLD16(gA1 + t * 32, d + lo1);
  };
  auto stageB = [&](int t) {
    __bf16* d = sB[t & 3];
    GLD16(gB0 + t * 32, d + lo0);
    GLD16(gB1 + t * 32, d + lo1);
  };

  auto compute_half = [&](const __bf16* cA, const bf16x8* bfr, int half) {
    bf16x8 af[4];
    #pragma unroll
    for (int mt = 0; mt < 4; ++mt) {
      int r = wm * 128 + half * 64 + mt * 16 + l16;
      af[mt] = *(const bf16x8*)(cA + r * 32 + ((quad ^ ((r >> 1) & 3)) * 8));
    }
    __builtin_amdgcn_s_setprio(1);
    #pragma unroll
    for (int mt = 0; mt < 4; ++mt)
      #pragma unroll
      for (int nt = 0; nt < 4; ++nt)
        acc[half * 4 + mt][nt] = __builtin_amdgcn_mfma_f32_16x16x32_bf16(
            af[mt], bfr[nt], acc[half * 4 + mt][nt], 0, 0, 0);
    __builtin_amdgcn_s_setprio(0);
  };

  // prologue: prime tiles 0,1,2 (12 loads in flight)
  stageA(0); stageB(0);
  stageA(1); stageB(1);
  stageA(2); stageB(2);

  #pragma unroll 1
  for (int t = 0; t < NKT; ++t) {
    if (t < NKT - 2)
      asm volatile("s_waitcnt vmcnt(8)" ::: "memory");
    else if (t == NKT - 2)
      asm volatile("s_waitcnt vmcnt(4)" ::: "memory");
    else
      asm volatile("s_waitcnt vmcnt(0)" ::: "memory");
    __builtin_amdgcn_s_barrier();
    SCHED_FENCE();
    const __bf16* cA = sA[t & 3];
    const __bf16* cB = sB[t & 3];
    if (t + 3 < NKT) stageA(t + 3);
    SCHED_FENCE();
    bf16x8 bfr[4];
    #pragma unroll
    for (int nt = 0; nt < 4; ++nt) {
      int r = wn * 64 + nt * 16 + l16;
      bfr[nt] = *(const bf16x8*)(cB + r * 32 + ((quad ^ ((r >> 1) & 3)) * 8));
    }
    compute_half(cA, bfr, 0);
    SCHED_FENCE();
    if (t + 3 < NKT) stageB(t + 3);
    SCHED_FENCE();
    compute_half(cA, bfr, 1);
    SCHED_FENCE();
  }

  // epilogue: bias + SwiGLU, unpack interleaved xp/gate
  const int colbase = (blockIdx.x * 4 + wn) * 32;   // logical col base (0..4095)
  #pragma unroll
  for (int j = 0; j < 8; ++j) {
    int row = m0 + wm * 128 + (j >> 2) * 64 + (j & 3) * 16 + quad * 4;
    #pragma unroll
    for (int p = 0; p < 2; ++p) {
      int col = colbase + p * 16 + l16;
      float bxv = b1[col], bgv = b1[col + 4096];
      #pragma unroll
      for (int r = 0; r < 4; ++r) {
        float xp = acc[j][p][r] + bxv;
        float g  = acc[j][p + 2][r] + bgv;
        float val = xp * g / (1.f + __expf(-g));
        ffout[(size_t)(row + r) * 5120 + 1024 + col] = (__bf16)val;
      }
    }
  }
}

// ---------------- combine: out = Σ4 partials + (bo+b2) + lam*h --------------
__global__ __launch_bounds__(256) void combine_k(
    const float* __restrict__ P, const float* __restrict__ b2,
    const float* __restrict__ bo, const float* __restrict__ hs,
    const float* __restrict__ plam, float* __restrict__ out) {
  const size_t MN = (size_t)2048 * 1024;
  size_t i = ((size_t)blockIdx.x * 256 + threadIdx.x) * 4;
  int col = (int)(i & 1023);
  float4 a0 = *(const float4*)(P + i);
  float4 a1 = *(const float4*)(P + MN + i);
  float4 a2 = *(const float4*)(P + 2 * MN + i);
  float4 a3 = *(const float4*)(P + 3 * MN + i);
  float4 h  = *(const float4*)(hs + i);
  float4 v2 = *(const float4*)(b2 + col);
  float4 vo = *(const float4*)(bo + col);
  float lam = plam[0];
  float4 o;
  o.x = (a0.x + a1.x) + (a2.x + a3.x) + v2.x + vo.x + lam * h.x;
  o.y = (a0.y + a1.y) + (a2.y + a3.y) + v2.y + vo.y + lam * h.y;
  o.z = (a0.z + a1.z) + (a2.z + a3.z) + v2.z + vo.z + lam * h.z;
  o.w = (a0.w + a1.w) + (a2.w + a3.w) + v2.w + vo.w + lam * h.w;
  *(float4*)(out + i) = o;
}

// ---------------- sb row-sum via two-level cumsum ---------------------------
__global__ __launch_bounds__(256) void kbsum_k(const float* __restrict__ kb,
                                               float* __restrict__ tsum,
                                               float* __restrict__ tsum8) {
  int t = blockIdx.x, h = blockIdx.y;
  int d = threadIdx.x & 63, w = threadIdx.x >> 6;
  size_t base = (size_t)h * 64 + d;
  float s = 0.f;
  #pragma unroll
  for (int r = 0; r < 8; ++r)
    s += kb[(size_t)(t * 32 + w * 8 + r) * 1024 + base];
  tsum8[(size_t)((t * 4 + w) * 16 + h) * 64 + d] = s;
  __shared__ float ps[4][64];
  ps[w][d] = s;
  __syncthreads();
  if (w == 0)
    tsum[(size_t)(t * 16 + h) * 64 + d] = (ps[0][d] + ps[1][d]) + (ps[2][d] + ps[3][d]);
}

__global__ __launch_bounds__(256) void sbrow2_k(const float* __restrict__ qb,
                                                const float* __restrict__ kb,
                                                const float* __restrict__ tsum,
                                                const float* __restrict__ tsum8,
                                                float* __restrict__ sb) {
  int t = blockIdx.x, h = blockIdx.y;
  int d = threadIdx.x & 63, g = threadIdx.x >> 6;
  size_t base = (size_t)h * 64 + d;
  float run = 0.f;
  for (int tp = 0; tp < t; ++tp) run += tsum[(size_t)(tp * 16 + h) * 64 + d];
  for (int w = 0; w < g; ++w) run += tsum8[(size_t)((t * 4 + w) * 16 + h) * 64 + d];
  int r0 = t * 32 + g * 8;
  for (int s0 = 0; s0 < 8; s0 += 4) {
    float p[4];
    #pragma unroll
    for (int u = 0; u < 4; ++u) {
      size_t off = (size_t)(r0 + s0 + u) * 1024 + base;
      run += kb[off];
      p[u] = qb[off] * run;
    }
    #pragma unroll
    for (int o = 32; o > 0; o >>= 1) {
      #pragma unroll
      for (int u = 0; u < 4; ++u) p[u] += __shfl_xor(p[u], o);
    }
    if (d == 0) {
      #pragma unroll
      for (int u = 0; u < 4; ++u) sb[(r0 + s0 + u) * 16 + h] = 0.125f * p[u];
    }
  }
}

// ---------------- flash attention: split-KV x4, fixed-max softmax -----------
// q,k rows are L2-NORMALIZED -> scores = q.k in [-1,1] (Cauchy-Schwarz), so
// softmax can use a FIXED shift of 1 (shift-invariance): p = exp(s-1) in
// [e^-2, 1], no overflow possible. Kills the per-tile max shuffle-reduce,
// running-max bookkeeping, accO rescale, AND the per-tile sum reduce (l is
// accumulated lane-locally; one 16-lane reduce per phase). LDS ops per
// wave-tile drop ~110 -> ~34 (the 32 bpermutes from shfl are gone).
// attnmerge: partials now combine by plain addition (no m).
__global__ __launch_bounds__(256) void attn_k(const __bf16* __restrict__ qg,
    const __bf16* __restrict__ kg, const __bf16* __restrict__ vtg,
    float* __restrict__ o_part, float* __restrict__ l_part) {
  __shared__ __bf16 sK[2][64 * 64];
  __shared__ __bf16 sVt[2][64 * 64];
  __shared__ __bf16 sP[4][16 * 64];
  const int pair = blockIdx.x, j4 = blockIdx.y, hh = blockIdx.z;
  const int tid = threadIdx.x, lane = tid & 63, w = tid >> 6;
  const int quad = lane >> 4, l16 = lane & 15;
  const int srow = tid >> 3;
  const int sg = (tid & 7) ^ (srow & 7);
  __bf16* sPw = sP[w];

  auto stage = [&](int kt) {
    int b = kt & 1;
    const __bf16* gK = kg + (size_t)(kt * 64 + srow) * 1024 + hh * 64 + sg * 8;
    const __bf16* gV = vtg + (size_t)(hh * 64 + srow) * 2048 + kt * 64 + sg * 8;
    GLD16(gK, sK[b] + tid * 8);
    GLD16(gK + (size_t)32 * 1024, sK[b] + tid * 8 + 2048);
    GLD16(gV, sVt[b] + tid * 8);
    GLD16(gV + (size_t)32 * 2048, sVt[b] + tid * 8 + 2048);
  };

  for (int phase = 0; phase < 2; ++phase) {
    const int qt = phase ? 31 - pair : pair;
    const int q0 = qt * 64;
    const int n = qt + 1;
    const int kb = (j4 * n) >> 2, ke = ((j4 + 1) * n) >> 2;
    bf16x8 qf[2];
    #pragma unroll
    for (int kk = 0; kk < 2; ++kk)
      qf[kk] = *(const bf16x8*)(qg + (size_t)(q0 + w * 16 + l16) * 1024 + hh * 64 + kk * 32 + quad * 8);
    f32x4 accO[4] = {};
    float l_[4] = {0.f, 0.f, 0.f, 0.f};   // lane-local partial sums

    __syncthreads();                 // seal previous phase's buffer reads
    if (kb < ke) stage(kb);

    for (int kt = kb; kt < ke; ++kt) {
      __syncthreads();               // implicit vmcnt(0): buf[kt&1] ready;
                                     // seals buf[(kt+1)&1] (last read kt-1)
      SCHED_FENCE();
      if (kt + 1 < ke) stage(kt + 1);
      SCHED_FENCE();
      const __bf16* cK = sK[kt & 1];
      const __bf16* cV = sVt[kt & 1];

      f32x4 s4[4];
      #pragma unroll
      for (int nt = 0; nt < 4; ++nt) {
        int r = nt * 16 + l16;
        bf16x8 b0 = *(const bf16x8*)(cK + r * 64 + ((quad ^ (r & 7)) * 8));
        bf16x8 b1 = *(const bf16x8*)(cK + r * 64 + (((4 + quad) ^ (r & 7)) * 8));
        f32x4 sa = {0.f, 0.f, 0.f, 0.f};
        sa = __builtin_amdgcn_mfma_f32_16x16x32_bf16(qf[0], b0, sa, 0, 0, 0);
        sa = __builtin_amdgcn_mfma_f32_16x16x32_bf16(qf[1], b1, sa, 0, 0, 0);
        s4[nt] = sa;
      }
      if (kt == qt) {
        #pragma unroll
        for (int nt = 0; nt < 4; ++nt)
          #pragma unroll
          for (int r = 0; r < 4; ++r)
            if (nt * 16 + l16 > w * 16 + quad * 4 + r) s4[nt][r] = -INFINITY;
      }
      // fixed-max softmax: p = exp(s - 1); accumulate l lane-locally
      float p[4][4];
      #pragma unroll
      for (int nt = 0; nt < 4; ++nt)
        #pragma unroll
        for (int r = 0; r < 4; ++r)
          p[nt][r] = __expf(s4[nt][r] - 1.0f);
      #pragma unroll
      for (int r = 0; r < 4; ++r)
        l_[r] += (p[0][r] + p[1][r]) + (p[2][r] + p[3][r]);
      #pragma unroll
      for (int nt = 0; nt < 4; ++nt)
        #pragma unroll
        for (int r = 0; r < 4; ++r) {
          int row = quad * 4 + r, col = nt * 16 + l16;
          sPw[row * 64 + (col ^ ((row & 7) << 3))] = (__bf16)p[nt][r];
        }
      #pragma unroll
      for (int kk = 0; kk < 2; ++kk) {
        bf16x8 a = *(const bf16x8*)(sPw + l16 * 64 + (((kk * 4 + quad) ^ (l16 & 7)) * 8));
        #pragma unroll
        for (int nt = 0; nt < 4; ++nt) {
          int vr = nt * 16 + l16;
          bf16x8 bv = *(const bf16x8*)(cV + vr * 64 + (((kk * 4 + quad) ^ (vr & 7)) * 8));
          accO[nt] = __builtin_amdgcn_mfma_f32_16x16x32_bf16(a, bv, accO[nt], 0, 0, 0);
        }
      }
      // no trailing barrier: sP is wave-private; K/V buffers are ring-2 sealed
    }
    // one 16-lane reduce of l per phase (was per tile)
    #pragma unroll
    for (int o = 1; o < 16; o <<= 1)
      #pragma unroll
      for (int r = 0; r < 4; ++r) l_[r] += __shfl_xor(l_[r], o);
    #pragma unroll
    for (int r = 0; r < 4; ++r) {
      int grow = q0 + w * 16 + quad * 4 + r;
      if (l16 == 0)
        l_part[((size_t)j4 * 2048 + grow) * 16 + hh] = l_[r];
      #pragma unroll
      for (int nt = 0; nt < 4; ++nt)
        o_part[((size_t)j4 * 2048 + grow) * 1024 + hh * 64 + nt * 16 + l16] = accO[nt][r];
    }
  }
}

// ---------------- merge 4 KV-partials -> y into concat (stride 5120) --------
// Fixed-max softmax: partials share the same shift -> plain addition.
__global__ __launch_bounds__(256) void attnmerge_k(const float* __restrict__ o_part,
    const float* __restrict__ l_part, const float* __restrict__ sbr,
    const float* __restrict__ pl2s, __bf16* __restrict__ yo) {
  int idx = blockIdx.x * 256 + threadIdx.x;
  int s = idx >> 8, rem = idx & 255;
  int h = rem >> 4, dg = (rem & 15) * 4;
  float den = 0.f;
  float4 acc = {0.f, 0.f, 0.f, 0.f};
  #pragma unroll
  for (int j = 0; j < 4; ++j) {
    den += l_part[((size_t)j * 2048 + s) * 16 + h];
    float4 o = *(const float4*)(o_part + ((size_t)j * 2048 + s) * 1024 + h * 64 + dg);
    acc.x += o.x; acc.y += o.y; acc.z += o.z; acc.w += o.w;
  }
  float sc = pl2s[0] / den;
  float add = sbr[s * 16 + h];
  __bf16* yp = yo + (size_t)s * 5120 + h * 64 + dg;
  yp[0] = (__bf16)(sc * acc.x + add);
  yp[1] = (__bf16)(sc * acc.y + add);
  yp[2] = (__bf16)(sc * acc.z + add);
  yp[3] = (__bf16)(sc * acc.w + add);
}

extern "C" void kernel_launch(void* const* d_in, const int* in_sizes, int n_in,
                              void* d_out, int out_size, void* d_ws, size_t ws_size,
                              hipStream_t stream) {
  (void)in_sizes; (void)n_in; (void)out_size; (void)ws_size;
  const float* hs   = (const float*)d_in[0];
  const float* Wq   = (const float*)d_in[1];
  const float* Wk   = (const float*)d_in[2];
  const float* Wv   = (const float*)d_in[3];
  const float* Wqb  = (const float*)d_in[4];
  const float* Wkb  = (const float*)d_in[5];
  const float* Wo   = (const float*)d_in[6];
  const float* bo   = (const float*)d_in[7];
  const float* W1   = (const float*)d_in[8];
  const float* b1   = (const float*)d_in[9];
  const float* W2   = (const float*)d_in[10];
  const float* b2   = (const float*)d_in[11];
  const float* plam = (const float*)d_in[12];
  const float* pl2s = (const float*)d_in[13];
  float* out = (float*)d_out;
  char* ws = (char*)d_ws;

  size_t off = 0;
  auto alloc = [&](size_t bytes) { char* p = ws + off; off += (bytes + 255) & ~(size_t)255; return p; };
  __bf16* Wt5    = (__bf16*)alloc((size_t)5 * 1024 * 1024 * 2);
  __bf16* WoW2t  = (__bf16*)alloc((size_t)1024 * 5120 * 2);   // [n][k], k: Wo 0..1023, W2 1024..5119
  __bf16* W1t    = (__bf16*)alloc((size_t)8192 * 1024 * 2);   // packed xp/gate 32-col interleave
  __bf16* xbf    = (__bf16*)alloc((size_t)2048 * 1024 * 2);
  __bf16* concat = (__bf16*)alloc((size_t)2048 * 5120 * 2);   // [y | ffin] bf16
  float*  proj  = (float*)alloc((size_t)2048 * 5120 * 4);     // vproj / o_part / gpart scratch
  float*  qbf32 = (float*)alloc((size_t)2048 * 1024 * 4);
  float*  kbf32 = (float*)alloc((size_t)2048 * 1024 * 4);
  __bf16* qbf   = (__bf16*)alloc((size_t)2048 * 1024 * 2);
  __bf16* kbf   = (__bf16*)alloc((size_t)2048 * 1024 * 2);
  float*  vproj  = proj;                                      // 8 MB (v only)
  float*  o_part = proj;                                      // 4 x 8 MB (after tconv)
  float*  l_part = qbf32;                                     // 512 KB (after sbrow2)
  float*  gpart  = proj;                                      // 4 x 8 MB (after attnmerge)
  __bf16* vtbf  = (__bf16*)alloc((size_t)1024 * 2048 * 2);
  float*  sbrow = (float*)alloc((size_t)2048 * 16 * 4);
  float*  tsum  = (float*)alloc((size_t)64 * 16 * 64 * 4);
  float*  tsum8 = (float*)alloc((size_t)256 * 16 * 64 * 4);

  // merged weight repack (was 3 launches)
  repack_k<<<18432, 256, 0, stream>>>(Wq, Wk, Wv, Wqb, Wkb, Wo, W2, W1,
                                      Wt5, WoW2t, W1t);

  rmsnorm_k<<<2048, 256, 0, stream>>>(hs, xbf);
  // QKV-family GEMM with fused l2norm+RoPE epilogue (replaces gemm_bt + qkprep)
  gemm_qkv_k<<<dim3(40, 16), 256, 0, stream>>>(xbf, Wt5, qbf, kbf,
                                               qbf32, kbf32, vproj);
  tconv_k<<<dim3(32, 64), 256, 0, stream>>>(vproj, vtbf, 1024, 2048);
  kbsum_k<<<dim3(64, 16), 256, 0, stream>>>(kbf32, tsum, tsum8);
  sbrow2_k<<<dim3(64, 16), 256, 0, stream>>>(qbf32, kbf32, tsum, tsum8, sbrow);
  attn_k<<<dim3(16, 4, 16), 256, 0, stream>>>(qbf, kbf, vtbf, o_part, l_part);
  attnmerge_k<<<2048, 256, 0, stream>>>(o_part, l_part, sbrow, pl2s, concat);
  // fused FFN1 + bias + SwiGLU -> concat cols 1024..5119 (256x256 ring-4)
  ffn1silu_k<<<dim3(32, 8), 512, 0, stream>>>(xbf, W1t, b1, concat);
  // merged (Wo + FFN2): [y|ffin] @ [Wo;W2], K=5120, split-K x4 -> partials
  gemm_partk_k<<<dim3(8, 16, 4), 256, 0, stream>>>(concat, WoW2t, gpart, 1024, 5120);
  // out = Σ partials + (bo+b2) + lam*h
  combine_k<<<2048, 256, 0, stream>>>(gpart, b2, bo, hs, plam, out);
}

// Round 9
// 325.069 us; speedup vs baseline: 1.1905x; 1.0255x over previous
//
#include <hip/hip_runtime.h>
#include <hip/hip_bf16.h>
#include <math.h>

typedef __bf16 bf16x8 __attribute__((ext_vector_type(8)));
typedef __bf16 bf16x4 __attribute__((ext_vector_type(4)));
typedef float  f32x4  __attribute__((ext_vector_type(4)));

#define GLD16(g, l) __builtin_amdgcn_global_load_lds(                      \
    (const __attribute__((address_space(1))) void*)(g),                    \
    (__attribute__((address_space(3))) void*)(l), 16, 0, 0)

#define SCHED_FENCE() __builtin_amdgcn_sched_barrier(0)

// BK=32 LDS tiles (64 B rows): global k-group g of row r stored at slot
// g ^ ((r>>1)&3) -> all ds_read_b128 fragment reads are 2-way (free).

// ---------------- merged weight repack (was 3 kernels) ----------------------
__global__ __launch_bounds__(256) void repack_k(
    const float* __restrict__ Wq, const float* __restrict__ Wk,
    const float* __restrict__ Wv, const float* __restrict__ Wqb,
    const float* __restrict__ Wkb, const float* __restrict__ Wo,
    const float* __restrict__ W2, const float* __restrict__ W1,
    __bf16* __restrict__ Wt5, __bf16* __restrict__ WoW2t,
    __bf16* __restrict__ W1t) {
  int t = blockIdx.x;
  const float* in; __bf16* outp;
  int ldin, ldout, r0, c0, cin0, oofs;
  if (t < 5120) {
    int w = t >> 10, rem = t & 1023;
    const float* src[5] = {Wq, Wk, Wv, Wqb, Wkb};
    in = src[w]; ldin = 1024;
    r0 = (rem >> 5) << 5; c0 = (rem & 31) << 5; cin0 = c0;
    outp = Wt5 + (size_t)w * 1048576; ldout = 1024; oofs = 0;
  } else if (t < 6144) {
    int rem = t - 5120;
    in = Wo; ldin = 1024;
    r0 = (rem >> 5) << 5; c0 = (rem & 31) << 5; cin0 = c0;
    outp = WoW2t; ldout = 5120; oofs = 0;
  } else if (t < 10240) {
    int rem = t - 6144;
    in = W2; ldin = 1024;
    r0 = (rem >> 5) << 5; c0 = (rem & 31) << 5; cin0 = c0;
    outp = WoW2t; ldout = 5120; oofs = 1024;
  } else {
    int rem = t - 10240;
    in = W1; ldin = 8192;
    c0 = (rem & 255) << 5; r0 = (rem >> 8) << 5;
    cin0 = ((c0 >> 5) & 1) * 4096 + (c0 >> 6) * 32;
    outp = W1t; ldout = 1024; oofs = 0;
  }
  __shared__ float sh[32][33];
  int tid = threadIdx.x, tx = tid & 31, ty = tid >> 5;
  #pragma unroll
  for (int i = ty; i < 32; i += 8)
    sh[i][tx] = in[(size_t)(r0 + i) * ldin + cin0 + tx];
  __syncthreads();
  #pragma unroll
  for (int i = ty; i < 32; i += 8)
    outp[(size_t)(c0 + i) * ldout + oofs + r0 + tx] = (__bf16)sh[tx][i];
}

// ---------------- RMSNorm ---------------------------------------------------
__global__ __launch_bounds__(256) void rmsnorm_k(const float* __restrict__ hs,
                                                 __bf16* __restrict__ x) {
  int row = blockIdx.x, tid = threadIdx.x;
  const float4 v = ((const float4*)(hs + (size_t)row * 1024))[tid];
  float ss = v.x * v.x + v.y * v.y + v.z * v.z + v.w * v.w;
  #pragma unroll
  for (int o = 32; o > 0; o >>= 1) ss += __shfl_xor(ss, o);
  __shared__ float ps[4];
  if ((tid & 63) == 0) ps[tid >> 6] = ss;
  __syncthreads();
  float tot = ps[0] + ps[1] + ps[2] + ps[3];
  float r = rsqrtf(tot * (1.0f / 1024.0f) + 1.1920929e-7f);
  __bf16* xr = x + (size_t)row * 1024 + tid * 4;
  xr[0] = (__bf16)(v.x * r); xr[1] = (__bf16)(v.y * r);
  xr[2] = (__bf16)(v.z * r); xr[3] = (__bf16)(v.w * r);
}

// ---------------- GEMM 128x128 ring-3, 2-phase, fused l2norm/RoPE -----------
// 2-phase body (T3): ds_reads issue BEFORE the phase barrier, MFMA after —
// the barrier wait absorbs LDS latency and waves alternate roles on the
// MFMA pipe. vmcnt ladder unchanged (stage split A/B across phases keeps
// in-flight counts identical). V-quadrant epilogue writes V^T directly
// (bf16x4 8B stores, rows contiguous) — replaces vproj+tconv.
__global__ __launch_bounds__(256, 3) void gemm_qkv_k(
    const __bf16* __restrict__ A, const __bf16* __restrict__ Bt,
    __bf16* __restrict__ qbf, __bf16* __restrict__ kbf,
    float* __restrict__ qb32, float* __restrict__ kb32,
    __bf16* __restrict__ vtbf) {
  const int K = 1024;
  __shared__ __bf16 sA[3][128 * 32];
  __shared__ __bf16 sB[3][128 * 32];
  const int tid = threadIdx.x;
  const int lane = tid & 63;
  const int quad = lane >> 4, l16 = lane & 15;
  const int wave = tid >> 6;
  const int waveM = wave >> 1, waveN = wave & 1;
  const int m0 = blockIdx.y * 128, n0 = blockIdx.x * 128;
  const int nk = K >> 5;
  const int rowS = tid >> 2;
  const int kg = ((tid & 3) ^ ((rowS >> 1) & 3)) * 8;
  const __bf16* gA0 = A + (size_t)(m0 + rowS) * K + kg;
  const __bf16* gA1 = gA0 + (size_t)64 * K;
  const __bf16* gB0 = Bt + (size_t)(n0 + rowS) * K + kg;
  const __bf16* gB1 = gB0 + (size_t)64 * K;
  const int lo0 = tid * 8, lo1 = 2048 + tid * 8;

  auto stageA = [&](int t) {
    __bf16* dA = sA[t % 3];
    GLD16(gA0 + t * 32, dA + lo0);
    GLD16(gA1 + t * 32, dA + lo1);
  };
  auto stageB = [&](int t) {
    __bf16* dB = sB[t % 3];
    GLD16(gB0 + t * 32, dB + lo0);
    GLD16(gB1 + t * 32, dB + lo1);
  };
  stageA(0); stageB(0);
  stageA(1); stageB(1);

  f32x4 acc[4][4] = {};
  #pragma unroll 1
  for (int i = 0; i < nk; ++i) {
    if (i < nk - 1)
      asm volatile("s_waitcnt vmcnt(4)" ::: "memory");
    else
      asm volatile("s_waitcnt vmcnt(0)" ::: "memory");
    __builtin_amdgcn_s_barrier();
    SCHED_FENCE();
    const __bf16* cA = sA[i % 3];
    const __bf16* cB = sB[i % 3];
    // phase 0: reads (bfv + af0/1) || stage A-half of tile i+2
    bf16x8 af[4], bfv[4];
    #pragma unroll
    for (int nt = 0; nt < 4; ++nt) {
      int r = waveN * 64 + nt * 16 + l16;
      bfv[nt] = *(const bf16x8*)(cB + r * 32 + ((quad ^ ((r >> 1) & 3)) * 8));
    }
    #pragma unroll
    for (int mt = 0; mt < 2; ++mt) {
      int r = waveM * 64 + mt * 16 + l16;
      af[mt] = *(const bf16x8*)(cA + r * 32 + ((quad ^ ((r >> 1) & 3)) * 8));
    }
    if (i + 2 < nk) stageA(i + 2);
    SCHED_FENCE();
    __builtin_amdgcn_s_barrier();
    asm volatile("s_waitcnt lgkmcnt(0)" ::: "memory");
    SCHED_FENCE();
    __builtin_amdgcn_s_setprio(1);
    #pragma unroll
    for (int mt = 0; mt < 2; ++mt)
      #pragma unroll
      for (int nt = 0; nt < 4; ++nt)
        acc[mt][nt] = __builtin_amdgcn_mfma_f32_16x16x32_bf16(af[mt], bfv[nt], acc[mt][nt], 0, 0, 0);
    __builtin_amdgcn_s_setprio(0);
    SCHED_FENCE();
    // phase 1: reads (af2/3) || stage B-half of tile i+2
    #pragma unroll
    for (int mt = 2; mt < 4; ++mt) {
      int r = waveM * 64 + mt * 16 + l16;
      af[mt] = *(const bf16x8*)(cA + r * 32 + ((quad ^ ((r >> 1) & 3)) * 8));
    }
    if (i + 2 < nk) stageB(i + 2);
    SCHED_FENCE();
    __builtin_amdgcn_s_barrier();
    asm volatile("s_waitcnt lgkmcnt(0)" ::: "memory");
    SCHED_FENCE();
    __builtin_amdgcn_s_setprio(1);
    #pragma unroll
    for (int mt = 2; mt < 4; ++mt)
      #pragma unroll
      for (int nt = 0; nt < 4; ++nt)
        acc[mt][nt] = __builtin_amdgcn_mfma_f32_16x16x32_bf16(af[mt], bfv[nt], acc[mt][nt], 0, 0, 0);
    __builtin_amdgcn_s_setprio(0);
    SCHED_FENCE();
  }

  const int wid = n0 >> 10;                  // 0:q 1:k 2:v 3:qb 4:kb
  const int cw0 = (n0 & 1023) + waveN * 64;  // head-aligned col within weight
  if (wid == 2) {
    // direct V^T store: vtbf[d_global][seq], acc rows are contiguous seq
    #pragma unroll
    for (int mt = 0; mt < 4; ++mt) {
      int row = m0 + waveM * 64 + mt * 16 + quad * 4;
      #pragma unroll
      for (int nt = 0; nt < 4; ++nt) {
        int col = cw0 + nt * 16 + l16;
        bf16x4 v;
        v[0] = (__bf16)acc[mt][nt][0]; v[1] = (__bf16)acc[mt][nt][1];
        v[2] = (__bf16)acc[mt][nt][2]; v[3] = (__bf16)acc[mt][nt][3];
        *(bf16x4*)(vtbf + (size_t)col * 2048 + row) = v;
      }
    }
  } else {
    const float inv0 = exp2f(-0.31143076f * (float)l16);
    const float inv1 = exp2f(-0.31143076f * (float)(16 + l16));
    #pragma unroll
    for (int mt = 0; mt < 4; ++mt) {
      #pragma unroll
      for (int r = 0; r < 4; ++r) {
        int srow = m0 + waveM * 64 + mt * 16 + quad * 4 + r;
        float a0 = acc[mt][0][r], a1 = acc[mt][1][r];
        float a2 = acc[mt][2][r], a3 = acc[mt][3][r];
        float ss = a0 * a0 + a1 * a1 + a2 * a2 + a3 * a3;
        ss += __shfl_xor(ss, 1); ss += __shfl_xor(ss, 2);
        ss += __shfl_xor(ss, 4); ss += __shfl_xor(ss, 8);
        float yn = 1.0f / fmaxf(sqrtf(ss), 1e-12f);
        float ang0 = (float)srow * inv0;
        float cb0 = (float)(__bf16)__cosf(ang0);
        float sb0 = (float)(__bf16)__sinf(ang0);
        float ang1 = (float)srow * inv1;
        float cb1 = (float)(__bf16)__cosf(ang1);
        float sb1 = (float)(__bf16)__sinf(ang1);
        float y0 = a0 * yn, y1 = a1 * yn, y2 = a2 * yn, y3 = a3 * yn;
        float o0 =  y0 * cb0 + y2 * sb0;   // d = l16
        float o1 =  y1 * cb1 + y3 * sb1;   // d = 16+l16
        float o2 = -y0 * sb0 + y2 * cb0;   // d = 32+l16
        float o3 = -y1 * sb1 + y3 * cb1;   // d = 48+l16
        size_t base = (size_t)srow * 1024 + cw0 + l16;
        if (wid == 0) {
          qbf[base]      = (__bf16)o0; qbf[base + 16] = (__bf16)o1;
          qbf[base + 32] = (__bf16)o2; qbf[base + 48] = (__bf16)o3;
        } else if (wid == 1) {
          kbf[base]      = (__bf16)o0; kbf[base + 16] = (__bf16)o1;
          kbf[base + 32] = (__bf16)o2; kbf[base + 48] = (__bf16)o3;
        } else if (wid == 3) {
          qb32[base]      = o0; qb32[base + 16] = o1;
          qb32[base + 32] = o2; qb32[base + 48] = o3;
        } else {
          kb32[base]      = o0; kb32[base + 16] = o1;
          kb32[base + 32] = o2; kb32[base + 48] = o3;
        }
      }
    }
  }
}

// ---------------- GEMM 128x128 ring-3, 2-phase, split-K partials ------------
__global__ __launch_bounds__(256, 3) void gemm_partk_k(
    const __bf16* __restrict__ A, const __bf16* __restrict__ Bt,
    float* __restrict__ P, int N, int K) {
  __shared__ __bf16 sA[3][128 * 32];
  __shared__ __bf16 sB[3][128 * 32];
  const int tid = threadIdx.x;
  const int lane = tid & 63;
  const int quad = lane >> 4, l16 = lane & 15;
  const int wave = tid >> 6;
  const int waveM = wave >> 1, waveN = wave & 1;
  const int m0 = blockIdx.y * 128, n0 = blockIdx.x * 128;
  const int kz = blockIdx.z, nz = gridDim.z;
  const int kper = K / nz, kbeg = kz * kper;
  const int nk = kper >> 5;
  const size_t MN = (size_t)gridDim.y * 128 * N;
  float* C = P + (size_t)kz * MN;
  const int rowS = tid >> 2;
  const int kg = ((tid & 3) ^ ((rowS >> 1) & 3)) * 8;
  const __bf16* gA0 = A + (size_t)(m0 + rowS) * K + kbeg + kg;
  const __bf16* gA1 = gA0 + (size_t)64 * K;
  const __bf16* gB0 = Bt + (size_t)(n0 + rowS) * K + kbeg + kg;
  const __bf16* gB1 = gB0 + (size_t)64 * K;
  const int lo0 = tid * 8, lo1 = 2048 + tid * 8;

  auto stageA = [&](int t) {
    __bf16* dA = sA[t % 3];
    GLD16(gA0 + t * 32, dA + lo0);
    GLD16(gA1 + t * 32, dA + lo1);
  };
  auto stageB = [&](int t) {
    __bf16* dB = sB[t % 3];
    GLD16(gB0 + t * 32, dB + lo0);
    GLD16(gB1 + t * 32, dB + lo1);
  };
  stageA(0); stageB(0);
  stageA(1); stageB(1);

  f32x4 acc[4][4] = {};
  #pragma unroll 1
  for (int i = 0; i < nk; ++i) {
    if (i < nk - 1)
      asm volatile("s_waitcnt vmcnt(4)" ::: "memory");
    else
      asm volatile("s_waitcnt vmcnt(0)" ::: "memory");
    __builtin_amdgcn_s_barrier();
    SCHED_FENCE();
    const __bf16* cA = sA[i % 3];
    const __bf16* cB = sB[i % 3];
    bf16x8 af[4], bfv[4];
    #pragma unroll
    for (int nt = 0; nt < 4; ++nt) {
      int r = waveN * 64 + nt * 16 + l16;
      bfv[nt] = *(const bf16x8*)(cB + r * 32 + ((quad ^ ((r >> 1) & 3)) * 8));
    }
    #pragma unroll
    for (int mt = 0; mt < 2; ++mt) {
      int r = waveM * 64 + mt * 16 + l16;
      af[mt] = *(const bf16x8*)(cA + r * 32 + ((quad ^ ((r >> 1) & 3)) * 8));
    }
    if (i + 2 < nk) stageA(i + 2);
    SCHED_FENCE();
    __builtin_amdgcn_s_barrier();
    asm volatile("s_waitcnt lgkmcnt(0)" ::: "memory");
    SCHED_FENCE();
    __builtin_amdgcn_s_setprio(1);
    #pragma unroll
    for (int mt = 0; mt < 2; ++mt)
      #pragma unroll
      for (int nt = 0; nt < 4; ++nt)
        acc[mt][nt] = __builtin_amdgcn_mfma_f32_16x16x32_bf16(af[mt], bfv[nt], acc[mt][nt], 0, 0, 0);
    __builtin_amdgcn_s_setprio(0);
    SCHED_FENCE();
    #pragma unroll
    for (int mt = 2; mt < 4; ++mt) {
      int r = waveM * 64 + mt * 16 + l16;
      af[mt] = *(const bf16x8*)(cA + r * 32 + ((quad ^ ((r >> 1) & 3)) * 8));
    }
    if (i + 2 < nk) stageB(i + 2);
    SCHED_FENCE();
    __builtin_amdgcn_s_barrier();
    asm volatile("s_waitcnt lgkmcnt(0)" ::: "memory");
    SCHED_FENCE();
    __builtin_amdgcn_s_setprio(1);
    #pragma unroll
    for (int mt = 2; mt < 4; ++mt)
      #pragma unroll
      for (int nt = 0; nt < 4; ++nt)
        acc[mt][nt] = __builtin_amdgcn_mfma_f32_16x16x32_bf16(af[mt], bfv[nt], acc[mt][nt], 0, 0, 0);
    __builtin_amdgcn_s_setprio(0);
    SCHED_FENCE();
  }
  #pragma unroll
  for (int mt = 0; mt < 4; ++mt) {
    int row = m0 + waveM * 64 + mt * 16 + quad * 4;
    #pragma unroll
    for (int nt = 0; nt < 4; ++nt) {
      int col = n0 + waveN * 64 + nt * 16 + l16;
      #pragma unroll
      for (int r = 0; r < 4; ++r)
        C[(size_t)(row + r) * N + col] = acc[mt][nt][r];
    }
  }
}

// ---------------- fused FFN1 + bias + SwiGLU, 256x256 ring-4, 2-phase -------
// Phase split (T3): reads issue pre-barrier, MFMA post-barrier; barrier wait
// absorbs ds_read latency, waves role-split on the MFMA pipe. vmcnt ladder
// identical to the verified ring-4 (stage split A/B preserved).
__global__ __launch_bounds__(512, 2) void ffn1silu_k(
    const __bf16* __restrict__ A, const __bf16* __restrict__ W1t,
    const float* __restrict__ b1, __bf16* __restrict__ ffout) {
  __shared__ __bf16 sA[4][256 * 32];
  __shared__ __bf16 sB[4][256 * 32];
  const int tid = threadIdx.x, lane = tid & 63, w = tid >> 6;
  const int quad = lane >> 4, l16 = lane & 15;
  const int wm = w >> 2, wn = w & 3;          // 2 M-waves x 4 N-waves
  const int m0 = blockIdx.y * 256;            // M = 2048 -> 8
  const int n0p = blockIdx.x * 256;           // packed N = 8192 -> 32
  const int K = 1024, NKT = 32;
  const int rowS = tid >> 2;                  // 0..127
  const int kg = ((tid & 3) ^ ((rowS >> 1) & 3)) * 8;
  const __bf16* gA0 = A + (size_t)(m0 + rowS) * K + kg;
  const __bf16* gA1 = gA0 + (size_t)128 * K;
  const __bf16* gB0 = W1t + (size_t)(n0p + rowS) * K + kg;
  const __bf16* gB1 = gB0 + (size_t)128 * K;
  const int lo0 = tid * 8, lo1 = 4096 + tid * 8;

  f32x4 acc[8][4] = {};

  auto stageA = [&](int t) {
    __bf16* d = sA[t & 3];
    GLD16(gA0 + t * 32, d + lo0);
    GLD16(gA1 + t * 32, d + lo1);
  };
  auto stageB = [&](int t) {
    __bf16* d = sB[t & 3];
    GLD16(gB0 + t * 32, d + lo0);
    GLD16(gB1 + t * 32, d + lo1);
  };

  // prologue: prime tiles 0,1,2 (12 loads in flight)
  stageA(0); stageB(0);
  stageA(1); stageB(1);
  stageA(2); stageB(2);

  #pragma unroll 1
  for (int t = 0; t < NKT; ++t) {
    if (t < NKT - 2)
      asm volatile("s_waitcnt vmcnt(8)" ::: "memory");
    else if (t == NKT - 2)
      asm volatile("s_waitcnt vmcnt(4)" ::: "memory");
    else
      asm volatile("s_waitcnt vmcnt(0)" ::: "memory");
    __builtin_amdgcn_s_barrier();
    SCHED_FENCE();
    const __bf16* cA = sA[t & 3];
    const __bf16* cB = sB[t & 3];
    // phase 0: reads (bfr + af half0) || stageA(t+3)
    bf16x8 bfr[4], af[4];
    #pragma unroll
    for (int nt = 0; nt < 4; ++nt) {
      int r = wn * 64 + nt * 16 + l16;
      bfr[nt] = *(const bf16x8*)(cB + r * 32 + ((quad ^ ((r >> 1) & 3)) * 8));
    }
    #pragma unroll
    for (int mt = 0; mt < 4; ++mt) {
      int r = wm * 128 + mt * 16 + l16;
      af[mt] = *(const bf16x8*)(cA + r * 32 + ((quad ^ ((r >> 1) & 3)) * 8));
    }
    if (t + 3 < NKT) stageA(t + 3);
    SCHED_FENCE();
    __builtin_amdgcn_s_barrier();
    asm volatile("s_waitcnt lgkmcnt(0)" ::: "memory");
    SCHED_FENCE();
    __builtin_amdgcn_s_setprio(1);
    #pragma unroll
    for (int mt = 0; mt < 4; ++mt)
      #pragma unroll
      for (int nt = 0; nt < 4; ++nt)
        acc[mt][nt] = __builtin_amdgcn_mfma_f32_16x16x32_bf16(af[mt], bfr[nt], acc[mt][nt], 0, 0, 0);
    __builtin_amdgcn_s_setprio(0);
    SCHED_FENCE();
    // phase 1: reads (af half1) || stageB(t+3)
    bf16x8 af1[4];
    #pragma unroll
    for (int mt = 0; mt < 4; ++mt) {
      int r = wm * 128 + 64 + mt * 16 + l16;
      af1[mt] = *(const bf16x8*)(cA + r * 32 + ((quad ^ ((r >> 1) & 3)) * 8));
    }
    if (t + 3 < NKT) stageB(t + 3);
    SCHED_FENCE();
    __builtin_amdgcn_s_barrier();
    asm volatile("s_waitcnt lgkmcnt(0)" ::: "memory");
    SCHED_FENCE();
    __builtin_amdgcn_s_setprio(1);
    #pragma unroll
    for (int mt = 0; mt < 4; ++mt)
      #pragma unroll
      for (int nt = 0; nt < 4; ++nt)
        acc[4 + mt][nt] = __builtin_amdgcn_mfma_f32_16x16x32_bf16(af1[mt], bfr[nt], acc[4 + mt][nt], 0, 0, 0);
    __builtin_amdgcn_s_setprio(0);
    SCHED_FENCE();
  }

  // epilogue: bias + SwiGLU, unpack interleaved xp/gate
  const int colbase = (blockIdx.x * 4 + wn) * 32;   // logical col base (0..4095)
  #pragma unroll
  for (int j = 0; j < 8; ++j) {
    int row = m0 + wm * 128 + (j >> 2) * 64 + (j & 3) * 16 + quad * 4;
    #pragma unroll
    for (int p = 0; p < 2; ++p) {
      int col = colbase + p * 16 + l16;
      float bxv = b1[col], bgv = b1[col + 4096];
      #pragma unroll
      for (int r = 0; r < 4; ++r) {
        float xp = acc[j][p][r] + bxv;
        float g  = acc[j][p + 2][r] + bgv;
        float val = xp * g / (1.f + __expf(-g));
        ffout[(size_t)(row + r) * 5120 + 1024 + col] = (__bf16)val;
      }
    }
  }
}

// ---------------- combine: out = Σ4 partials + (bo+b2) + lam*h --------------
__global__ __launch_bounds__(256) void combine_k(
    const float* __restrict__ P, const float* __restrict__ b2,
    const float* __restrict__ bo, const float* __restrict__ hs,
    const float* __restrict__ plam, float* __restrict__ out) {
  const size_t MN = (size_t)2048 * 1024;
  size_t i = ((size_t)blockIdx.x * 256 + threadIdx.x) * 4;
  int col = (int)(i & 1023);
  float4 a0 = *(const float4*)(P + i);
  float4 a1 = *(const float4*)(P + MN + i);
  float4 a2 = *(const float4*)(P + 2 * MN + i);
  float4 a3 = *(const float4*)(P + 3 * MN + i);
  float4 h  = *(const float4*)(hs + i);
  float4 v2 = *(const float4*)(b2 + col);
  float4 vo = *(const float4*)(bo + col);
  float lam = plam[0];
  float4 o;
  o.x = (a0.x + a1.x) + (a2.x + a3.x) + v2.x + vo.x + lam * h.x;
  o.y = (a0.y + a1.y) + (a2.y + a3.y) + v2.y + vo.y + lam * h.y;
  o.z = (a0.z + a1.z) + (a2.z + a3.z) + v2.z + vo.z + lam * h.z;
  o.w = (a0.w + a1.w) + (a2.w + a3.w) + v2.w + vo.w + lam * h.w;
  *(float4*)(out + i) = o;
}

// ---------------- sb row-sum via two-level cumsum ---------------------------
__global__ __launch_bounds__(256) void kbsum_k(const float* __restrict__ kb,
                                               float* __restrict__ tsum,
                                               float* __restrict__ tsum8) {
  int t = blockIdx.x, h = blockIdx.y;
  int d = threadIdx.x & 63, w = threadIdx.x >> 6;
  size_t base = (size_t)h * 64 + d;
  float s = 0.f;
  #pragma unroll
  for (int r = 0; r < 8; ++r)
    s += kb[(size_t)(t * 32 + w * 8 + r) * 1024 + base];
  tsum8[(size_t)((t * 4 + w) * 16 + h) * 64 + d] = s;
  __shared__ float ps[4][64];
  ps[w][d] = s;
  __syncthreads();
  if (w == 0)
    tsum[(size_t)(t * 16 + h) * 64 + d] = (ps[0][d] + ps[1][d]) + (ps[2][d] + ps[3][d]);
}

__global__ __launch_bounds__(256) void sbrow2_k(const float* __restrict__ qb,
                                                const float* __restrict__ kb,
                                                const float* __restrict__ tsum,
                                                const float* __restrict__ tsum8,
                                                float* __restrict__ sb) {
  int t = blockIdx.x, h = blockIdx.y;
  int d = threadIdx.x & 63, g = threadIdx.x >> 6;
  size_t base = (size_t)h * 64 + d;
  float run = 0.f;
  for (int tp = 0; tp < t; ++tp) run += tsum[(size_t)(tp * 16 + h) * 64 + d];
  for (int w = 0; w < g; ++w) run += tsum8[(size_t)((t * 4 + w) * 16 + h) * 64 + d];
  int r0 = t * 32 + g * 8;
  for (int s0 = 0; s0 < 8; s0 += 4) {
    float p[4];
    #pragma unroll
    for (int u = 0; u < 4; ++u) {
      size_t off = (size_t)(r0 + s0 + u) * 1024 + base;
      run += kb[off];
      p[u] = qb[off] * run;
    }
    #pragma unroll
    for (int o = 32; o > 0; o >>= 1) {
      #pragma unroll
      for (int u = 0; u < 4; ++u) p[u] += __shfl_xor(p[u], o);
    }
    if (d == 0) {
      #pragma unroll
      for (int u = 0; u < 4; ++u) sb[(r0 + s0 + u) * 16 + h] = 0.125f * p[u];
    }
  }
}

// ---------------- flash attention: split-KV x4, fixed-max softmax -----------
__global__ __launch_bounds__(256) void attn_k(const __bf16* __restrict__ qg,
    const __bf16* __restrict__ kg, const __bf16* __restrict__ vtg,
    float* __restrict__ o_part, float* __restrict__ l_part) {
  __shared__ __bf16 sK[2][64 * 64];
  __shared__ __bf16 sVt[2][64 * 64];
  __shared__ __bf16 sP[4][16 * 64];
  const int pair = blockIdx.x, j4 = blockIdx.y, hh = blockIdx.z;
  const int tid = threadIdx.x, lane = tid & 63, w = tid >> 6;
  const int quad = lane >> 4, l16 = lane & 15;
  const int srow = tid >> 3;
  const int sg = (tid & 7) ^ (srow & 7);
  __bf16* sPw = sP[w];

  auto stage = [&](int kt) {
    int b = kt & 1;
    const __bf16* gK = kg + (size_t)(kt * 64 + srow) * 1024 + hh * 64 + sg * 8;
    const __bf16* gV = vtg + (size_t)(hh * 64 + srow) * 2048 + kt * 64 + sg * 8;
    GLD16(gK, sK[b] + tid * 8);
    GLD16(gK + (size_t)32 * 1024, sK[b] + tid * 8 + 2048);
    GLD16(gV, sVt[b] + tid * 8);
    GLD16(gV + (size_t)32 * 2048, sVt[b] + tid * 8 + 2048);
  };

  for (int phase = 0; phase < 2; ++phase) {
    const int qt = phase ? 31 - pair : pair;
    const int q0 = qt * 64;
    const int n = qt + 1;
    const int kb = (j4 * n) >> 2, ke = ((j4 + 1) * n) >> 2;
    bf16x8 qf[2];
    #pragma unroll
    for (int kk = 0; kk < 2; ++kk)
      qf[kk] = *(const bf16x8*)(qg + (size_t)(q0 + w * 16 + l16) * 1024 + hh * 64 + kk * 32 + quad * 8);
    f32x4 accO[4] = {};
    float l_[4] = {0.f, 0.f, 0.f, 0.f};   // lane-local partial sums

    __syncthreads();                 // seal previous phase's buffer reads
    if (kb < ke) stage(kb);

    for (int kt = kb; kt < ke; ++kt) {
      __syncthreads();               // implicit vmcnt(0): buf[kt&1] ready;
                                     // seals buf[(kt+1)&1] (last read kt-1)
      SCHED_FENCE();
      if (kt + 1 < ke) stage(kt + 1);
      SCHED_FENCE();
      const __bf16* cK = sK[kt & 1];
      const __bf16* cV = sVt[kt & 1];

      f32x4 s4[4];
      #pragma unroll
      for (int nt = 0; nt < 4; ++nt) {
        int r = nt * 16 + l16;
        bf16x8 b0 = *(const bf16x8*)(cK + r * 64 + ((quad ^ (r & 7)) * 8));
        bf16x8 b1 = *(const bf16x8*)(cK + r * 64 + (((4 + quad) ^ (r & 7)) * 8));
        f32x4 sa = {0.f, 0.f, 0.f, 0.f};
        sa = __builtin_amdgcn_mfma_f32_16x16x32_bf16(qf[0], b0, sa, 0, 0, 0);
        sa = __builtin_amdgcn_mfma_f32_16x16x32_bf16(qf[1], b1, sa, 0, 0, 0);
        s4[nt] = sa;
      }
      if (kt == qt) {
        #pragma unroll
        for (int nt = 0; nt < 4; ++nt)
          #pragma unroll
          for (int r = 0; r < 4; ++r)
            if (nt * 16 + l16 > w * 16 + quad * 4 + r) s4[nt][r] = -INFINITY;
      }
      // fixed-max softmax: p = exp(s - 1); accumulate l lane-locally
      float p[4][4];
      #pragma unroll
      for (int nt = 0; nt < 4; ++nt)
        #pragma unroll
        for (int r = 0; r < 4; ++r)
          p[nt][r] = __expf(s4[nt][r] - 1.0f);
      #pragma unroll
      for (int r = 0; r < 4; ++r)
        l_[r] += (p[0][r] + p[1][r]) + (p[2][r] + p[3][r]);
      #pragma unroll
      for (int nt = 0; nt < 4; ++nt)
        #pragma unroll
        for (int r = 0; r < 4; ++r) {
          int row = quad * 4 + r, col = nt * 16 + l16;
          sPw[row * 64 + (col ^ ((row & 7) << 3))] = (__bf16)p[nt][r];
        }
      #pragma unroll
      for (int kk = 0; kk < 2; ++kk) {
        bf16x8 a = *(const bf16x8*)(sPw + l16 * 64 + (((kk * 4 + quad) ^ (l16 & 7)) * 8));
        #pragma unroll
        for (int nt = 0; nt < 4; ++nt) {
          int vr = nt * 16 + l16;
          bf16x8 bv = *(const bf16x8*)(cV + vr * 64 + (((kk * 4 + quad) ^ (vr & 7)) * 8));
          accO[nt] = __builtin_amdgcn_mfma_f32_16x16x32_bf16(a, bv, accO[nt], 0, 0, 0);
        }
      }
      // no trailing barrier: sP is wave-private; K/V buffers are ring-2 sealed
    }
    // one 16-lane reduce of l per phase (was per tile)
    #pragma unroll
    for (int o = 1; o < 16; o <<= 1)
      #pragma unroll
      for (int r = 0; r < 4; ++r) l_[r] += __shfl_xor(l_[r], o);
    #pragma unroll
    for (int r = 0; r < 4; ++r) {
      int grow = q0 + w * 16 + quad * 4 + r;
      if (l16 == 0)
        l_part[((size_t)j4 * 2048 + grow) * 16 + hh] = l_[r];
      #pragma unroll
      for (int nt = 0; nt < 4; ++nt)
        o_part[((size_t)j4 * 2048 + grow) * 1024 + hh * 64 + nt * 16 + l16] = accO[nt][r];
    }
  }
}

// ---------------- merge 4 KV-partials -> y into concat (stride 5120) --------
__global__ __launch_bounds__(256) void attnmerge_k(const float* __restrict__ o_part,
    const float* __restrict__ l_part, const float* __restrict__ sbr,
    const float* __restrict__ pl2s, __bf16* __restrict__ yo) {
  int idx = blockIdx.x * 256 + threadIdx.x;
  int s = idx >> 8, rem = idx & 255;
  int h = rem >> 4, dg = (rem & 15) * 4;
  float den = 0.f;
  float4 acc = {0.f, 0.f, 0.f, 0.f};
  #pragma unroll
  for (int j = 0; j < 4; ++j) {
    den += l_part[((size_t)j * 2048 + s) * 16 + h];
    float4 o = *(const float4*)(o_part + ((size_t)j * 2048 + s) * 1024 + h * 64 + dg);
    acc.x += o.x; acc.y += o.y; acc.z += o.z; acc.w += o.w;
  }
  float sc = pl2s[0] / den;
  float add = sbr[s * 16 + h];
  __bf16* yp = yo + (size_t)s * 5120 + h * 64 + dg;
  yp[0] = (__bf16)(sc * acc.x + add);
  yp[1] = (__bf16)(sc * acc.y + add);
  yp[2] = (__bf16)(sc * acc.z + add);
  yp[3] = (__bf16)(sc * acc.w + add);
}

extern "C" void kernel_launch(void* const* d_in, const int* in_sizes, int n_in,
                              void* d_out, int out_size, void* d_ws, size_t ws_size,
                              hipStream_t stream) {
  (void)in_sizes; (void)n_in; (void)out_size; (void)ws_size;
  const float* hs   = (const float*)d_in[0];
  const float* Wq   = (const float*)d_in[1];
  const float* Wk   = (const float*)d_in[2];
  const float* Wv   = (const float*)d_in[3];
  const float* Wqb  = (const float*)d_in[4];
  const float* Wkb  = (const float*)d_in[5];
  const float* Wo   = (const float*)d_in[6];
  const float* bo   = (const float*)d_in[7];
  const float* W1   = (const float*)d_in[8];
  const float* b1   = (const float*)d_in[9];
  const float* W2   = (const float*)d_in[10];
  const float* b2   = (const float*)d_in[11];
  const float* plam = (const float*)d_in[12];
  const float* pl2s = (const float*)d_in[13];
  float* out = (float*)d_out;
  char* ws = (char*)d_ws;

  size_t off = 0;
  auto alloc = [&](size_t bytes) { char* p = ws + off; off += (bytes + 255) & ~(size_t)255; return p; };
  __bf16* Wt5    = (__bf16*)alloc((size_t)5 * 1024 * 1024 * 2);
  __bf16* WoW2t  = (__bf16*)alloc((size_t)1024 * 5120 * 2);   // [n][k], k: Wo 0..1023, W2 1024..5119
  __bf16* W1t    = (__bf16*)alloc((size_t)8192 * 1024 * 2);   // packed xp/gate 32-col interleave
  __bf16* xbf    = (__bf16*)alloc((size_t)2048 * 1024 * 2);
  __bf16* concat = (__bf16*)alloc((size_t)2048 * 5120 * 2);   // [y | ffin] bf16
  float*  proj  = (float*)alloc((size_t)2048 * 5120 * 4);     // o_part / gpart scratch
  float*  qbf32 = (float*)alloc((size_t)2048 * 1024 * 4);
  float*  kbf32 = (float*)alloc((size_t)2048 * 1024 * 4);
  __bf16* qbf   = (__bf16*)alloc((size_t)2048 * 1024 * 2);
  __bf16* kbf   = (__bf16*)alloc((size_t)2048 * 1024 * 2);
  float*  o_part = proj;                                      // 4 x 8 MB
  float*  l_part = qbf32;                                     // 512 KB (after sbrow2)
  float*  gpart  = proj;                                      // 4 x 8 MB (after attnmerge)
  __bf16* vtbf  = (__bf16*)alloc((size_t)1024 * 2048 * 2);
  float*  sbrow = (float*)alloc((size_t)2048 * 16 * 4);
  float*  tsum  = (float*)alloc((size_t)64 * 16 * 64 * 4);
  float*  tsum8 = (float*)alloc((size_t)256 * 16 * 64 * 4);

  // merged weight repack
  repack_k<<<18432, 256, 0, stream>>>(Wq, Wk, Wv, Wqb, Wkb, Wo, W2, W1,
                                      Wt5, WoW2t, W1t);

  rmsnorm_k<<<2048, 256, 0, stream>>>(hs, xbf);
  // QKV GEMM: fused l2norm+RoPE epilogue + direct V^T store (tconv gone)
  gemm_qkv_k<<<dim3(40, 16), 256, 0, stream>>>(xbf, Wt5, qbf, kbf,
                                               qbf32, kbf32, vtbf);
  kbsum_k<<<dim3(64, 16), 256, 0, stream>>>(kbf32, tsum, tsum8);
  sbrow2_k<<<dim3(64, 16), 256, 0, stream>>>(qbf32, kbf32, tsum, tsum8, sbrow);
  attn_k<<<dim3(16, 4, 16), 256, 0, stream>>>(qbf, kbf, vtbf, o_part, l_part);
  attnmerge_k<<<2048, 256, 0, stream>>>(o_part, l_part, sbrow, pl2s, concat);
  // fused FFN1 + bias + SwiGLU -> concat cols 1024..5119 (256x256 ring-4, 2-phase)
  ffn1silu_k<<<dim3(32, 8), 512, 0, stream>>>(xbf, W1t, b1, concat);
  // merged (Wo + FFN2): [y|ffin] @ [Wo;W2], K=5120, split-K x4 -> partials
  gemm_partk_k<<<dim3(8, 16, 4), 256, 0, stream>>>(concat, WoW2t, gpart, 1024, 5120);
  // out = Σ partials + (bo+b2) + lam*h
  combine_k<<<2048, 256, 0, stream>>>(gpart, b2, bo, hs, plam, out);
}